// Round 1
// baseline (1108.453 us; speedup 1.0000x reference)
//
#include <hip/hip_runtime.h>

// ---------------------------------------------------------------------------
// Problem constants (B=32 grids of 30x30, D=256, NH=4 heads (hd=64), L=8, P=12)
// ---------------------------------------------------------------------------
constexpr int kB = 32, kT = 900, kD = 256, kHD = 64, kL = 8, kP = 12;

// Workspace layout (float offsets). Total = 9,195,008 floats = 36.8 MB.
constexpr size_t OFF_POSQ  = 0;                               // 900x256
constexpr size_t OFF_POSK  = OFF_POSQ  + 900*256;             // 900x256
constexpr size_t OFF_POSV  = OFF_POSK  + 900*256;             // 900x256
constexpr size_t OFF_EMBQ  = OFF_POSV  + 900*256;             // 10x256
constexpr size_t OFF_EMBK  = OFF_EMBQ  + 10*256;
constexpr size_t OFF_EMBV  = OFF_EMBK  + 10*256;
constexpr size_t OFF_WOK   = OFF_EMBV  + 10*256;              // 256x256 (wo@wk)
constexpr size_t OFF_WOV   = OFF_WOK   + 256*256;             // 256x256 (wo@wv)
constexpr size_t OFF_WOOUT = OFF_WOV   + 256*256;             // 256x12  (wo@w_out)
constexpr size_t OFF_Q2    = OFF_WOOUT + 256*12;              // 8x256   (step_q@wq)
constexpr size_t OFF_ATTN  = OFF_Q2    + 8*256;               // 32x900x256 self-attn out (pre-wo)
constexpr size_t OFF_SC2   = OFF_ATTN  + (size_t)32*900*256;  // 32x4x8x900 cross scores
constexpr size_t OFF_CROSS = OFF_SC2   + (size_t)32*4*8*900;  // 32x8x256 cross-attn out

// ---------------------------------------------------------------------------
// Small precompute GEMMs: C[MxN] = A[Mx256] @ W[256xN], one thread per output.
// jobs: embQ/K/V, woK, woV, woOut, q2, posQ/K/V
// ---------------------------------------------------------------------------
__global__ void k_precompute(const float* __restrict__ embed,
                             const float* __restrict__ pos_emb,
                             const float* __restrict__ wq,
                             const float* __restrict__ wk,
                             const float* __restrict__ wv,
                             const float* __restrict__ wo,
                             const float* __restrict__ step_q,
                             const float* __restrict__ w_out,
                             float* __restrict__ ws) {
  const int job = blockIdx.y;
  const float* A; const float* Wm; float* C; int M; int N;
  switch (job) {
    case 0: A=embed;  Wm=wq;    C=ws+OFF_EMBQ;  M=10;  N=256; break;
    case 1: A=embed;  Wm=wk;    C=ws+OFF_EMBK;  M=10;  N=256; break;
    case 2: A=embed;  Wm=wv;    C=ws+OFF_EMBV;  M=10;  N=256; break;
    case 3: A=wo;     Wm=wk;    C=ws+OFF_WOK;   M=256; N=256; break;
    case 4: A=wo;     Wm=wv;    C=ws+OFF_WOV;   M=256; N=256; break;
    case 5: A=wo;     Wm=w_out; C=ws+OFF_WOOUT; M=256; N=12;  break;
    case 6: A=step_q; Wm=wq;    C=ws+OFF_Q2;    M=8;   N=256; break;
    case 7: A=pos_emb;Wm=wq;    C=ws+OFF_POSQ;  M=900; N=256; break;
    case 8: A=pos_emb;Wm=wk;    C=ws+OFF_POSK;  M=900; N=256; break;
    default:A=pos_emb;Wm=wv;    C=ws+OFF_POSV;  M=900; N=256; break;
  }
  int idx = blockIdx.x * 256 + threadIdx.x;
  if (idx >= M * N) return;
  int m = idx / N, n = idx - m * N;
  const float* a = A + (size_t)m * 256;
  float acc = 0.f;
  #pragma unroll 8
  for (int k = 0; k < 256; ++k) acc = fmaf(a[k], Wm[(size_t)k * N + n], acc);
  C[idx] = acc;
}

// ---------------------------------------------------------------------------
// Self-attention (flash style, f32). One block = (qtile of 64, head, batch).
// Q/K/V tiles built on the fly from embX[grid]+posX (projection-free).
// Thread micro-tile: 4x4. qg=tid/16 (4 query rows), kg=tid%16 (4 cols).
// Writes attnOut[b][t][h*64+d] (pre-@wo MHA output).
// ---------------------------------------------------------------------------
__global__ __launch_bounds__(256) void k_self_attn(const int* __restrict__ grid_in,
                                                   const float* __restrict__ ws,
                                                   float* __restrict__ attnOut) {
  const float* posQ = ws + OFF_POSQ;
  const float* posK = ws + OFF_POSK;
  const float* posV = ws + OFF_POSV;
  const float* embQ = ws + OFF_EMBQ;
  const float* embK = ws + OFF_EMBK;
  const float* embV = ws + OFF_EMBV;

  const int qt = blockIdx.x, h = blockIdx.y, b = blockIdx.z;
  const int t0 = qt * 64, hc = h * 64;
  const int tid = threadIdx.x;

  __shared__ float Qs[64][68];
  __shared__ float Ks[64][68];   // doubles as P after scores are consumed
  __shared__ float Vs[64][68];

  // Load Q tile (gather + pos add), coalesced over d.
  for (int idx = tid; idx < 64 * 64; idx += 256) {
    int i = idx >> 6, d = idx & 63;
    int t = t0 + i; if (t > 899) t = 899;
    int g = grid_in[b * 900 + t];
    Qs[i][d] = embQ[g * 256 + hc + d] + posQ[(size_t)t * 256 + hc + d];
  }

  const int qg = tid >> 4, kg = tid & 15;
  float m_[4], l_[4], O[4][4];
  #pragma unroll
  for (int i = 0; i < 4; ++i) {
    m_[i] = -1e30f; l_[i] = 0.f;
    #pragma unroll
    for (int j = 0; j < 4; ++j) O[i][j] = 0.f;
  }

  for (int kt = 0; kt < 15; ++kt) {
    const int k0 = kt * 64;
    __syncthreads();  // prev-iter P/V reads done; Q visible on first iter
    for (int idx = tid; idx < 64 * 64; idx += 256) {
      int j = idx >> 6, d = idx & 63;
      int t = k0 + j; if (t > 899) t = 899;
      int g = grid_in[b * 900 + t];
      Ks[j][d] = embK[g * 256 + hc + d] + posK[(size_t)t * 256 + hc + d];
      Vs[j][d] = embV[g * 256 + hc + d] + posV[(size_t)t * 256 + hc + d];
    }
    __syncthreads();

    // S = Q K^T (4x4 per thread)
    float s[4][4] = {};
    #pragma unroll 4
    for (int dq = 0; dq < 16; ++dq) {
      float4 qv[4], kv[4];
      #pragma unroll
      for (int i = 0; i < 4; ++i) qv[i] = *(const float4*)&Qs[4 * qg + i][4 * dq];
      #pragma unroll
      for (int j = 0; j < 4; ++j) kv[j] = *(const float4*)&Ks[4 * kg + j][4 * dq];
      #pragma unroll
      for (int i = 0; i < 4; ++i)
        #pragma unroll
        for (int j = 0; j < 4; ++j)
          s[i][j] += qv[i].x * kv[j].x + qv[i].y * kv[j].y +
                     qv[i].z * kv[j].z + qv[i].w * kv[j].w;
    }

    // Online softmax update (row stats across the 16 lanes sharing qg).
    float p[4][4];
    #pragma unroll
    for (int i = 0; i < 4; ++i) {
      float tmax = -1e30f;
      #pragma unroll
      for (int j = 0; j < 4; ++j) {
        s[i][j] *= 0.125f;                       // 1/sqrt(64)
        if (k0 + 4 * kg + j >= 900) s[i][j] = -1e30f;
        tmax = fmaxf(tmax, s[i][j]);
      }
      for (int mk = 1; mk < 16; mk <<= 1) tmax = fmaxf(tmax, __shfl_xor(tmax, mk));
      float mn = fmaxf(m_[i], tmax);
      float sc = __expf(m_[i] - mn);
      float rs = 0.f;
      #pragma unroll
      for (int j = 0; j < 4; ++j) { p[i][j] = __expf(s[i][j] - mn); rs += p[i][j]; }
      for (int mk = 1; mk < 16; mk <<= 1) rs += __shfl_xor(rs, mk);
      l_[i] = l_[i] * sc + rs;
      m_[i] = mn;
      #pragma unroll
      for (int j = 0; j < 4; ++j) O[i][j] *= sc;
    }

    __syncthreads();  // all S reads of Ks done before overwriting with P
    #pragma unroll
    for (int i = 0; i < 4; ++i)
      #pragma unroll
      for (int j = 0; j < 4; ++j) Ks[4 * qg + i][4 * kg + j] = p[i][j];
    __syncthreads();

    // O += P V  (thread owns rows 4qg+i, output cols 4kg+jj)
    #pragma unroll 4
    for (int kq = 0; kq < 16; ++kq) {
      float4 pr[4], vr[4];
      #pragma unroll
      for (int i = 0; i < 4; ++i) pr[i] = *(const float4*)&Ks[4 * qg + i][4 * kq];
      #pragma unroll
      for (int j = 0; j < 4; ++j) vr[j] = *(const float4*)&Vs[4 * kq + j][4 * kg];
      #pragma unroll
      for (int i = 0; i < 4; ++i) {
        O[i][0] += pr[i].x * vr[0].x + pr[i].y * vr[1].x + pr[i].z * vr[2].x + pr[i].w * vr[3].x;
        O[i][1] += pr[i].x * vr[0].y + pr[i].y * vr[1].y + pr[i].z * vr[2].y + pr[i].w * vr[3].y;
        O[i][2] += pr[i].x * vr[0].z + pr[i].y * vr[1].z + pr[i].z * vr[2].z + pr[i].w * vr[3].z;
        O[i][3] += pr[i].x * vr[0].w + pr[i].y * vr[1].w + pr[i].z * vr[2].w + pr[i].w * vr[3].w;
      }
    }
  }

  // Epilogue: normalize and store.
  #pragma unroll
  for (int i = 0; i < 4; ++i) {
    int t = t0 + 4 * qg + i;
    if (t < 900) {
      float inv = 1.f / l_[i];
      float4 o4 = make_float4(O[i][0] * inv, O[i][1] * inv, O[i][2] * inv, O[i][3] * inv);
      *(float4*)&attnOut[((size_t)(b * 900 + t)) * 256 + hc + 4 * kg] = o4;
    }
  }
}

// ---------------------------------------------------------------------------
// Cross-attention scores: per (ktile, head, batch) block, build
// k2[64x64] = gather(embK,posK) + attnOut_tile @ woK[:,h-slice], then
// scores2[b,h,l,t] = q2[l]·k2[t] / 8.
// ---------------------------------------------------------------------------
__global__ __launch_bounds__(256) void k_cross_scores(const int* __restrict__ grid_in,
                                                      const float* __restrict__ ws,
                                                      float* __restrict__ scores2) {
  const float* posK = ws + OFF_POSK;
  const float* embK = ws + OFF_EMBK;
  const float* woK  = ws + OFF_WOK;
  const float* q2   = ws + OFF_Q2;
  const float* attnOut = ws + OFF_ATTN;

  const int kt = blockIdx.x, h = blockIdx.y, b = blockIdx.z;
  const int k0 = kt * 64, hc = h * 64;
  const int tid = threadIdx.x;

  __shared__ float As[64][36];
  __shared__ float Wcs[32][68];
  __shared__ float k2s[64][68];
  __shared__ float q2s[8][64];

  for (int idx = tid; idx < 8 * 64; idx += 256) {
    int l = idx >> 6, d = idx & 63;
    q2s[l][d] = q2[l * 256 + hc + d];
  }

  const int jg = tid >> 4, dg = tid & 15;
  float acc[4][4] = {};
  for (int kc = 0; kc < 8; ++kc) {
    __syncthreads();
    for (int idx = tid; idx < 64 * 32; idx += 256) {
      int j = idx >> 5, cc = idx & 31;
      int t = k0 + j; if (t > 899) t = 899;
      As[j][cc] = attnOut[((size_t)(b * 900 + t)) * 256 + kc * 32 + cc];
    }
    for (int idx = tid; idx < 32 * 64; idx += 256) {
      int cc = idx >> 6, d = idx & 63;
      Wcs[cc][d] = woK[((size_t)(kc * 32 + cc)) * 256 + hc + d];
    }
    __syncthreads();
    for (int cc = 0; cc < 32; ++cc) {
      float a0 = As[4*jg+0][cc], a1 = As[4*jg+1][cc];
      float a2 = As[4*jg+2][cc], a3 = As[4*jg+3][cc];
      float4 wv = *(const float4*)&Wcs[cc][4 * dg];
      acc[0][0]+=a0*wv.x; acc[0][1]+=a0*wv.y; acc[0][2]+=a0*wv.z; acc[0][3]+=a0*wv.w;
      acc[1][0]+=a1*wv.x; acc[1][1]+=a1*wv.y; acc[1][2]+=a1*wv.z; acc[1][3]+=a1*wv.w;
      acc[2][0]+=a2*wv.x; acc[2][1]+=a2*wv.y; acc[2][2]+=a2*wv.z; acc[2][3]+=a2*wv.w;
      acc[3][0]+=a3*wv.x; acc[3][1]+=a3*wv.y; acc[3][2]+=a3*wv.z; acc[3][3]+=a3*wv.w;
    }
  }

  // gather-add and stage k2 tile
  #pragma unroll
  for (int i = 0; i < 4; ++i) {
    int t = k0 + 4 * jg + i; int tc = t > 899 ? 899 : t;
    int g = grid_in[b * 900 + tc];
    #pragma unroll
    for (int jj = 0; jj < 4; ++jj) {
      int d = 4 * dg + jj;
      k2s[4 * jg + i][d] = acc[i][jj] + embK[g * 256 + hc + d] + posK[(size_t)tc * 256 + hc + d];
    }
  }
  __syncthreads();

  const int kj = tid & 63, l2 = tid >> 6;
  if (k0 + kj < 900) {
    #pragma unroll
    for (int li = 0; li < 2; ++li) {
      int l = l2 + 4 * li;
      float sacc = 0.f;
      for (int d = 0; d < 64; ++d) sacc += q2s[l][d] * k2s[kj][d];
      scores2[(((size_t)b * 4 + h) * 8 + l) * 900 + k0 + kj] = sacc * 0.125f;
    }
  }
}

// One wave per (b,h,l) row of 900: softmax in place.
__global__ void k_cross_softmax(float* __restrict__ scores2) {
  const int row = blockIdx.x;
  const int lane = threadIdx.x;
  float* r = scores2 + (size_t)row * 900;
  float v[15];
  float mx = -1e30f;
  #pragma unroll
  for (int k = 0; k < 15; ++k) {
    int t = lane + 64 * k;
    v[k] = (t < 900) ? r[t] : -1e30f;
    mx = fmaxf(mx, v[k]);
  }
  for (int mk = 1; mk < 64; mk <<= 1) mx = fmaxf(mx, __shfl_xor(mx, mk));
  float sm = 0.f;
  #pragma unroll
  for (int k = 0; k < 15; ++k) { v[k] = __expf(v[k] - mx); sm += v[k]; }
  for (int mk = 1; mk < 64; mk <<= 1) sm += __shfl_xor(sm, mk);
  float inv = 1.f / sm;
  #pragma unroll
  for (int k = 0; k < 15; ++k) {
    int t = lane + 64 * k;
    if (t < 900) r[t] = v[k] * inv;
  }
}

__global__ void k_zero_cross(float* __restrict__ ws) {
  ws[OFF_CROSS + blockIdx.x * 256 + threadIdx.x] = 0.f;
}

// ---------------------------------------------------------------------------
// Cross-attention PV: per (head, batch, ksplit) block, rebuild v2 tiles
// (gather + attnOut@woV) and accumulate out2[l,d] += p[l,t] v2[t,d].
// ---------------------------------------------------------------------------
__global__ __launch_bounds__(256) void k_cross_pv(const int* __restrict__ grid_in,
                                                  const float* __restrict__ ws,
                                                  float* __restrict__ crossOut) {
  const float* posV = ws + OFF_POSV;
  const float* embV = ws + OFF_EMBV;
  const float* woV  = ws + OFF_WOV;
  const float* attnOut = ws + OFF_ATTN;
  const float* sc2 = ws + OFF_SC2;

  const int h = blockIdx.x, b = blockIdx.y, z = blockIdx.z;
  const int hc = h * 64;
  const int tid = threadIdx.x;
  const int jg = tid >> 4, dg = tid & 15;
  const int dcol = tid & 63, l2 = tid >> 6;

  __shared__ float As[64][36];
  __shared__ float Wcs[32][68];
  __shared__ float v2s[64][68];
  __shared__ float ps[8][64];

  float o2[2] = {0.f, 0.f};

  for (int kk = 0; kk < 3; ++kk) {
    const int kt = z * 3 + kk;
    const int k0 = kt * 64;
    float acc[4][4] = {};
    for (int kc = 0; kc < 8; ++kc) {
      __syncthreads();
      for (int idx = tid; idx < 64 * 32; idx += 256) {
        int j = idx >> 5, cc = idx & 31;
        int t = k0 + j; if (t > 899) t = 899;
        As[j][cc] = attnOut[((size_t)(b * 900 + t)) * 256 + kc * 32 + cc];
      }
      for (int idx = tid; idx < 32 * 64; idx += 256) {
        int cc = idx >> 6, d = idx & 63;
        Wcs[cc][d] = woV[((size_t)(kc * 32 + cc)) * 256 + hc + d];
      }
      __syncthreads();
      for (int cc = 0; cc < 32; ++cc) {
        float a0 = As[4*jg+0][cc], a1 = As[4*jg+1][cc];
        float a2 = As[4*jg+2][cc], a3 = As[4*jg+3][cc];
        float4 wv = *(const float4*)&Wcs[cc][4 * dg];
        acc[0][0]+=a0*wv.x; acc[0][1]+=a0*wv.y; acc[0][2]+=a0*wv.z; acc[0][3]+=a0*wv.w;
        acc[1][0]+=a1*wv.x; acc[1][1]+=a1*wv.y; acc[1][2]+=a1*wv.z; acc[1][3]+=a1*wv.w;
        acc[2][0]+=a2*wv.x; acc[2][1]+=a2*wv.y; acc[2][2]+=a2*wv.z; acc[2][3]+=a2*wv.w;
        acc[3][0]+=a3*wv.x; acc[3][1]+=a3*wv.y; acc[3][2]+=a3*wv.z; acc[3][3]+=a3*wv.w;
      }
    }
    // stage softmax-probabilities and v2 tile
    for (int idx = tid; idx < 512; idx += 256) {
      int l = idx >> 6, j = idx & 63;
      int t = k0 + j;
      ps[l][j] = (t < 900) ? sc2[(((size_t)b * 4 + h) * 8 + l) * 900 + t] : 0.f;
    }
    #pragma unroll
    for (int i = 0; i < 4; ++i) {
      int t = k0 + 4 * jg + i; int tc = t > 899 ? 899 : t;
      int g = grid_in[b * 900 + tc];
      #pragma unroll
      for (int jj = 0; jj < 4; ++jj) {
        int d = 4 * dg + jj;
        v2s[4 * jg + i][d] = acc[i][jj] + embV[g * 256 + hc + d] + posV[(size_t)tc * 256 + hc + d];
      }
    }
    __syncthreads();
    #pragma unroll
    for (int li = 0; li < 2; ++li) {
      int l = l2 + 4 * li;
      float a = 0.f;
      for (int j = 0; j < 64; ++j) a += ps[l][j] * v2s[j][dcol];
      o2[li] += a;
    }
  }
  #pragma unroll
  for (int li = 0; li < 2; ++li) {
    int l = l2 + 4 * li;
    atomicAdd(&crossOut[((size_t)b * 8 + l) * 256 + hc + dcol], o2[li]);
  }
}

// logits[b,l,p] = crossOut[b,l,:] @ woOut[:,p] + b_out[p]
__global__ void k_logits(const float* __restrict__ ws,
                         const float* __restrict__ b_out,
                         float* __restrict__ out) {
  const float* crossOut = ws + OFF_CROSS;
  const float* woOut = ws + OFF_WOOUT;
  int idx = blockIdx.x * 256 + threadIdx.x;
  if (idx >= 32 * 8 * 12) return;
  int p = idx % 12;
  int bl = idx / 12;
  float acc = b_out[p];
  for (int d = 0; d < 256; ++d) acc = fmaf(crossOut[(size_t)bl * 256 + d], woOut[d * 12 + p], acc);
  out[idx] = acc;
}

// ---------------------------------------------------------------------------
// Program executor: flood fill (4-connected, row bitmasks, wave-parallel),
// rotate 90 CW about anchor, paint color 3. One 64-thread block per batch.
// ---------------------------------------------------------------------------
__global__ void k_execute(const int* __restrict__ grid_in,
                          const int* __restrict__ anchor,
                          float* __restrict__ outg) {
  const int b = blockIdx.x;
  const int lane = threadIdx.x;
  const int* g = grid_in + b * 900;
  int ar = anchor[2 * b], ac = anchor[2 * b + 1];
  ar = min(max(ar, 0), 29); ac = min(max(ac, 0), 29);
  const int seed = g[ar * 30 + ac];

  unsigned same = 0u;
  if (lane < 30)
    for (int c = 0; c < 30; ++c) same |= (unsigned)(g[lane * 30 + c] == seed) << c;

  unsigned cur = (lane == ar) ? (1u << ac) : 0u;
  bool changed = true;
  while (changed) {
    unsigned up = __shfl(cur, (lane + 63) & 63);
    unsigned dn = __shfl(cur, (lane + 1) & 63);
    if (lane == 0) up = 0u;
    unsigned nm = (cur | (cur << 1) | (cur >> 1) | up | dn) & same;
    changed = __any(nm != cur);
    cur = nm;
  }

  __shared__ unsigned msh[32];
  if (lane < 32) msh[lane] = (lane < 30) ? cur : 0u;
  __syncthreads();

  if (lane < 30) {
    // dest row nr=lane corresponds to source column cc = nr-ar+ac;
    // dest col nc corresponds to source row rr = ar+ac-nc.
    unsigned rot = 0u;
    int cc = lane - ar + ac;
    if (cc >= 0 && cc < 30) {
      for (int nc = 0; nc < 30; ++nc) {
        int rr = ar + ac - nc;
        if (rr >= 0 && rr < 30) rot |= ((msh[rr] >> cc) & 1u) << nc;
      }
    }
    for (int c = 0; c < 30; ++c) {
      int v = ((rot >> c) & 1u) ? 3 : g[lane * 30 + c];
      outg[b * 900 + lane * 30 + c] = (float)v;
    }
  }
}

// ---------------------------------------------------------------------------
extern "C" void kernel_launch(void* const* d_in, const int* in_sizes, int n_in,
                              void* d_out, int out_size, void* d_ws, size_t ws_size,
                              hipStream_t stream) {
  const int*   grid_in = (const int*)d_in[0];
  const int*   anchor  = (const int*)d_in[1];
  const float* embed   = (const float*)d_in[2];
  const float* pos_emb = (const float*)d_in[3];
  const float* wq      = (const float*)d_in[4];
  const float* wk      = (const float*)d_in[5];
  const float* wv      = (const float*)d_in[6];
  const float* wo      = (const float*)d_in[7];
  const float* step_q  = (const float*)d_in[8];
  const float* w_out   = (const float*)d_in[9];
  const float* b_out   = (const float*)d_in[10];
  float* out = (float*)d_out;
  float* ws  = (float*)d_ws;

  k_precompute<<<dim3(900, 10), dim3(256), 0, stream>>>(embed, pos_emb, wq, wk, wv,
                                                        wo, step_q, w_out, ws);
  k_self_attn<<<dim3(15, 4, 32), dim3(256), 0, stream>>>(grid_in, ws, ws + OFF_ATTN);
  k_cross_scores<<<dim3(15, 4, 32), dim3(256), 0, stream>>>(grid_in, ws, ws + OFF_SC2);
  k_cross_softmax<<<dim3(32 * 4 * 8), dim3(64), 0, stream>>>(ws + OFF_SC2);
  k_zero_cross<<<dim3(256), dim3(256), 0, stream>>>(ws);
  k_cross_pv<<<dim3(4, 32, 5), dim3(256), 0, stream>>>(grid_in, ws, ws + OFF_CROSS);
  k_logits<<<dim3(12), dim3(256), 0, stream>>>(ws, b_out, out);
  k_execute<<<dim3(32), dim3(64), 0, stream>>>(grid_in, anchor, out + 32 * 8 * 12);
}

// Round 2
// 648.283 us; speedup vs baseline: 1.7098x; 1.7098x over previous
//
#include <hip/hip_runtime.h>

// ===========================================================================
// ARPS forward, restructured:
//   tok = embed[grid]+pos  =>  all projections distribute over the gather:
//   q = embQ[g]+posQ, k = embK[g]+posK, v = embV[g]+posV   (tiny precomputes)
//   tok2 (residual) never materialized: k2 = (embK[g]+posK) + attnOut@(wo@wk)
//   Heavy parts (self-attn QK^T/PV, delta GEMM) run on bf16 MFMA.
// ===========================================================================

typedef __attribute__((ext_vector_type(8))) short bf16x8;   // 8 bf16 (4 VGPR)
typedef __attribute__((ext_vector_type(4))) float f32x4;    // MFMA acc

__device__ __forceinline__ short f2bf(float f) {
  union { float f; unsigned u; } v; v.f = f;
  unsigned r = v.u + 0x7fffu + ((v.u >> 16) & 1u);   // RNE
  return (short)(r >> 16);
}
__device__ __forceinline__ float bf2f(short s) {
  union { unsigned u; float f; } v; v.u = ((unsigned)(unsigned short)s) << 16;
  return v.f;
}
// XOR-swizzled index into a [rows][64] bf16 LDS tile (row stride 128B).
// 16B chunk id XORed with row&7 -> conflict-reduced ds_read_b128 (T2).
__device__ __forceinline__ int swz(int row, int col) {
  return row * 64 + ((((col >> 3) ^ row) & 7) << 3) + (col & 7);
}

// ---------------- workspace layout ----------------
// float region
constexpr size_t OFF_POSQ  = 0;                 // 900x256
constexpr size_t OFF_POSK  = 230400;
constexpr size_t OFF_POSV  = 460800;
constexpr size_t OFF_EMBQ  = 691200;            // 10x256 each
constexpr size_t OFF_EMBK  = 693760;
constexpr size_t OFF_EMBV  = 696320;
constexpr size_t OFF_WOOUT = 698880;            // 256x12
constexpr size_t OFF_Q2    = 701952;            // 8x256
constexpr size_t OFF_CROSS = 704000;            // 32x8x256
constexpr size_t OFF_F32_END = 769536;
// short (bf16) region, offsets in shorts from (short*)(ws+OFF_F32_END)
constexpr size_t SOFF_WOKVT = 0;                // [512][256]  (wo@wk | wo@wv)^T
constexpr size_t SOFF_ATTN  = 131072;           // [32*900][256] self-attn out
constexpr size_t SOFF_K2    = 7503872;          // [32][4][900][64]
constexpr size_t SOFF_V2    = 14876672;         // [32][4][900][64]

// ---------------------------------------------------------------------------
// Precompute GEMMs (f32, tiny). Jobs 3/4 store bf16 TRANSPOSED ([n][k]) so the
// delta-GEMM can stage B-fragments with contiguous 16B reads.
// ---------------------------------------------------------------------------
__global__ void k_precompute(const float* __restrict__ embed,
                             const float* __restrict__ pos_emb,
                             const float* __restrict__ wq,
                             const float* __restrict__ wk,
                             const float* __restrict__ wv,
                             const float* __restrict__ wo,
                             const float* __restrict__ step_q,
                             const float* __restrict__ w_out,
                             float* __restrict__ ws) {
  const int job = blockIdx.y;
  const float* A; const float* Wm; float* C = nullptr; int M; int N; int tr = 0;
  switch (job) {
    case 0: A=embed;  Wm=wq;    C=ws+OFF_EMBQ;  M=10;  N=256; break;
    case 1: A=embed;  Wm=wk;    C=ws+OFF_EMBK;  M=10;  N=256; break;
    case 2: A=embed;  Wm=wv;    C=ws+OFF_EMBV;  M=10;  N=256; break;
    case 3: A=wo;     Wm=wk;    M=256; N=256; tr=1; break;
    case 4: A=wo;     Wm=wv;    M=256; N=256; tr=2; break;
    case 5: A=wo;     Wm=w_out; C=ws+OFF_WOOUT; M=256; N=12;  break;
    case 6: A=step_q; Wm=wq;    C=ws+OFF_Q2;    M=8;   N=256; break;
    case 7: A=pos_emb;Wm=wq;    C=ws+OFF_POSQ;  M=900; N=256; break;
    case 8: A=pos_emb;Wm=wk;    C=ws+OFF_POSK;  M=900; N=256; break;
    default:A=pos_emb;Wm=wv;    C=ws+OFF_POSV;  M=900; N=256; break;
  }
  int idx = blockIdx.x * 256 + threadIdx.x;
  if (idx >= M * N) return;
  int m = idx / N, n = idx - m * N;
  const float* a = A + (size_t)m * 256;
  float acc = 0.f;
  #pragma unroll 8
  for (int k = 0; k < 256; ++k) acc = fmaf(a[k], Wm[(size_t)k * N + n], acc);
  if (tr) {
    short* wsS = (short*)(ws + OFF_F32_END);
    wsS[SOFF_WOKVT + (size_t)(n + (tr == 2 ? 256 : 0)) * 256 + m] = f2bf(acc);
  } else {
    C[idx] = acc;
  }
}

// ---------------------------------------------------------------------------
// Self-attention, bf16 MFMA flash. Block = (qtile 64, head, batch), 4 waves.
// Wave w owns q rows [16w,16w+16). Per 64-k tile: 8 MFMA QK^T + 8 MFMA PV.
// LDS: Q,K row-major [64][64] bf16; V transposed [d][t]; P per-wave [16][64].
// All fragment reads are swizzled ds_read_b128.
// ---------------------------------------------------------------------------
__global__ __launch_bounds__(256) void k_attn(const int* __restrict__ grid_in,
                                              const float* __restrict__ ws,
                                              short* __restrict__ attnOut) {
  const float* posQ = ws + OFF_POSQ;
  const float* posK = ws + OFF_POSK;
  const float* posV = ws + OFF_POSV;
  const float* embQ = ws + OFF_EMBQ;
  const float* embK = ws + OFF_EMBK;
  const float* embV = ws + OFF_EMBV;

  const int qt = blockIdx.x, h = blockIdx.y, b = blockIdx.z;
  const int t0 = qt * 64, hc = h * 64;
  const int tid = threadIdx.x, w = tid >> 6, lane = tid & 63;
  const int g = lane >> 4, c16 = lane & 15;

  __shared__ __align__(16) short Qs[4096];
  __shared__ __align__(16) short Ks[4096];
  __shared__ __align__(16) short Vs[4096];   // V^T: row=d, col=t
  __shared__ __align__(16) short Ps[4096];   // per-wave 16x64 regions

  // ---- stage Q (gather + pos, x0.125 softmax scale folded in) ----
  for (int idx = tid; idx < 512; idx += 256) {
    int row = idx >> 3, ch = idx & 7;
    int t = t0 + row; if (t > 899) t = 899;
    int gc = grid_in[b * 900 + t];
    const float* pp = posQ + (size_t)t * 256 + hc + ch * 8;
    const float* ee = embQ + (size_t)gc * 256 + hc + ch * 8;
    float4 p0 = *(const float4*)pp, p1 = *(const float4*)(pp + 4);
    float4 e0 = *(const float4*)ee, e1 = *(const float4*)(ee + 4);
    union { short s[8]; bf16x8 v; } u;
    u.s[0] = f2bf((p0.x + e0.x) * 0.125f); u.s[1] = f2bf((p0.y + e0.y) * 0.125f);
    u.s[2] = f2bf((p0.z + e0.z) * 0.125f); u.s[3] = f2bf((p0.w + e0.w) * 0.125f);
    u.s[4] = f2bf((p1.x + e1.x) * 0.125f); u.s[5] = f2bf((p1.y + e1.y) * 0.125f);
    u.s[6] = f2bf((p1.z + e1.z) * 0.125f); u.s[7] = f2bf((p1.w + e1.w) * 0.125f);
    *(bf16x8*)&Qs[swz(row, ch * 8)] = u.v;
  }
  __syncthreads();
  bf16x8 aQ0 = *(bf16x8*)&Qs[swz(w * 16 + c16, g * 8)];
  bf16x8 aQ1 = *(bf16x8*)&Qs[swz(w * 16 + c16, 32 + g * 8)];

  float m_[4], l_[4];
  f32x4 O[4];
  #pragma unroll
  for (int r = 0; r < 4; ++r) { m_[r] = -1e30f; l_[r] = 0.f; }
  #pragma unroll
  for (int dt = 0; dt < 4; ++dt) { f32x4 z = {0.f, 0.f, 0.f, 0.f}; O[dt] = z; }

  for (int kt = 0; kt < 15; ++kt) {
    const int k0 = kt * 64;
    __syncthreads();   // previous tile's K/V reads complete
    // stage K rows
    for (int idx = tid; idx < 512; idx += 256) {
      int row = idx >> 3, ch = idx & 7;
      int t = k0 + row; if (t > 899) t = 899;
      int gc = grid_in[b * 900 + t];
      const float* pp = posK + (size_t)t * 256 + hc + ch * 8;
      const float* ee = embK + (size_t)gc * 256 + hc + ch * 8;
      float4 p0 = *(const float4*)pp, p1 = *(const float4*)(pp + 4);
      float4 e0 = *(const float4*)ee, e1 = *(const float4*)(ee + 4);
      union { short s[8]; bf16x8 v; } u;
      u.s[0] = f2bf(p0.x + e0.x); u.s[1] = f2bf(p0.y + e0.y);
      u.s[2] = f2bf(p0.z + e0.z); u.s[3] = f2bf(p0.w + e0.w);
      u.s[4] = f2bf(p1.x + e1.x); u.s[5] = f2bf(p1.y + e1.y);
      u.s[6] = f2bf(p1.z + e1.z); u.s[7] = f2bf(p1.w + e1.w);
      *(bf16x8*)&Ks[swz(row, ch * 8)] = u.v;
    }
    // stage V transposed: Vs[d][t]
    for (int idx = tid; idx < 512; idx += 256) {
      int d = idx >> 3, tc = (idx & 7) * 8;
      union { short s[8]; bf16x8 v; } u;
      #pragma unroll
      for (int i = 0; i < 8; ++i) {
        int t = k0 + tc + i; if (t > 899) t = 899;
        int gc = grid_in[b * 900 + t];
        u.s[i] = f2bf(posV[(size_t)t * 256 + hc + d] + embV[(size_t)gc * 256 + hc + d]);
      }
      *(bf16x8*)&Vs[swz(d, tc)] = u.v;
    }
    __syncthreads();

    // ---- S = Q K^T ----
    f32x4 sacc[4];
    #pragma unroll
    for (int ct = 0; ct < 4; ++ct) {
      f32x4 z = {0.f, 0.f, 0.f, 0.f};
      bf16x8 bK0 = *(bf16x8*)&Ks[swz(ct * 16 + c16, g * 8)];
      bf16x8 bK1 = *(bf16x8*)&Ks[swz(ct * 16 + c16, 32 + g * 8)];
      z = __builtin_amdgcn_mfma_f32_16x16x32_bf16(aQ0, bK0, z, 0, 0, 0);
      z = __builtin_amdgcn_mfma_f32_16x16x32_bf16(aQ1, bK1, z, 0, 0, 0);
      if (k0 + ct * 16 + c16 >= 900) {
        z[0] = -1e30f; z[1] = -1e30f; z[2] = -1e30f; z[3] = -1e30f;
      }
      sacc[ct] = z;
    }

    // ---- online softmax (D-layout: row = 4g+r, col = c16) ----
    float pp_[4][4];
    #pragma unroll
    for (int r = 0; r < 4; ++r) {
      float rm = fmaxf(fmaxf(sacc[0][r], sacc[1][r]), fmaxf(sacc[2][r], sacc[3][r]));
      rm = fmaxf(rm, __shfl_xor(rm, 1));
      rm = fmaxf(rm, __shfl_xor(rm, 2));
      rm = fmaxf(rm, __shfl_xor(rm, 4));
      rm = fmaxf(rm, __shfl_xor(rm, 8));
      float mn = fmaxf(m_[r], rm);
      float sc = __expf(m_[r] - mn);
      float rs = 0.f;
      #pragma unroll
      for (int ct = 0; ct < 4; ++ct) { pp_[r][ct] = __expf(sacc[ct][r] - mn); rs += pp_[r][ct]; }
      rs += __shfl_xor(rs, 1);
      rs += __shfl_xor(rs, 2);
      rs += __shfl_xor(rs, 4);
      rs += __shfl_xor(rs, 8);
      l_[r] = l_[r] * sc + rs;
      m_[r] = mn;
      #pragma unroll
      for (int dt = 0; dt < 4; ++dt) O[dt][r] = O[dt][r] * sc;
    }
    // ---- write P into this wave's region (row = 4g+r, col = ct*16+c16) ----
    #pragma unroll
    for (int ct = 0; ct < 4; ++ct)
      #pragma unroll
      for (int r = 0; r < 4; ++r)
        Ps[swz(w * 16 + 4 * g + r, ct * 16 + c16)] = f2bf(pp_[r][ct]);

    // ---- O += P V ----
    #pragma unroll
    for (int c = 0; c < 2; ++c) {
      bf16x8 aP = *(bf16x8*)&Ps[swz(w * 16 + c16, c * 32 + g * 8)];
      #pragma unroll
      for (int dt = 0; dt < 4; ++dt) {
        bf16x8 bV = *(bf16x8*)&Vs[swz(dt * 16 + c16, c * 32 + g * 8)];
        O[dt] = __builtin_amdgcn_mfma_f32_16x16x32_bf16(aP, bV, O[dt], 0, 0, 0);
      }
    }
  }

  // ---- epilogue: normalize, store bf16 ----
  #pragma unroll
  for (int r = 0; r < 4; ++r) {
    int t = t0 + w * 16 + 4 * g + r;
    if (t < 900) {
      float inv = 1.f / l_[r];
      #pragma unroll
      for (int dt = 0; dt < 4; ++dt)
        attnOut[((size_t)(b * 900 + t)) * 256 + hc + dt * 16 + c16] = f2bf(O[dt][r] * inv);
    }
  }
}

// ---------------------------------------------------------------------------
// Delta GEMM: C[28800x512] = attnOut(bf16) @ [woK|woV], epilogue adds the
// gather (embK/posK or embV/posV) and stores k2/v2 bf16 as [b][h][t][64].
// Block tile 128x64, 4 waves (wave: 2 row-tiles x 4 col-tiles), BK=64.
// ---------------------------------------------------------------------------
__global__ __launch_bounds__(256) void k_delta(const int* __restrict__ grid_in,
                                               const float* __restrict__ ws,
                                               const short* __restrict__ attnOut,
                                               const short* __restrict__ wokvT,
                                               short* __restrict__ k2,
                                               short* __restrict__ v2) {
  const int m0 = blockIdx.x * 128, n0 = blockIdx.y * 64;
  const int tid = threadIdx.x, w = tid >> 6, lane = tid & 63;
  const int g = lane >> 4, c16 = lane & 15;
  __shared__ __align__(16) short As[8192];
  __shared__ __align__(16) short Bs[4096];
  f32x4 acc[2][4];
  #pragma unroll
  for (int rt = 0; rt < 2; ++rt)
    #pragma unroll
    for (int ct = 0; ct < 4; ++ct) { f32x4 z = {0.f, 0.f, 0.f, 0.f}; acc[rt][ct] = z; }

  for (int kk = 0; kk < 4; ++kk) {
    __syncthreads();
    for (int idx = tid; idx < 1024; idx += 256) {
      int row = idx >> 3, ch = idx & 7;
      *(bf16x8*)&As[swz(row, ch * 8)] =
          *(const bf16x8*)&attnOut[(size_t)(m0 + row) * 256 + kk * 64 + ch * 8];
    }
    for (int idx = tid; idx < 512; idx += 256) {
      int row = idx >> 3, ch = idx & 7;
      *(bf16x8*)&Bs[swz(row, ch * 8)] =
          *(const bf16x8*)&wokvT[(size_t)(n0 + row) * 256 + kk * 64 + ch * 8];
    }
    __syncthreads();
    #pragma unroll
    for (int ks = 0; ks < 2; ++ks) {
      bf16x8 aA0 = *(bf16x8*)&As[swz(w * 32 + c16, ks * 32 + g * 8)];
      bf16x8 aA1 = *(bf16x8*)&As[swz(w * 32 + 16 + c16, ks * 32 + g * 8)];
      #pragma unroll
      for (int ct = 0; ct < 4; ++ct) {
        bf16x8 bB = *(bf16x8*)&Bs[swz(ct * 16 + c16, ks * 32 + g * 8)];
        acc[0][ct] = __builtin_amdgcn_mfma_f32_16x16x32_bf16(aA0, bB, acc[0][ct], 0, 0, 0);
        acc[1][ct] = __builtin_amdgcn_mfma_f32_16x16x32_bf16(aA1, bB, acc[1][ct], 0, 0, 0);
      }
    }
  }

  const float* embK = ws + OFF_EMBK;
  const float* posK = ws + OFF_POSK;
  const float* embV = ws + OFF_EMBV;
  const float* posV = ws + OFF_POSV;
  #pragma unroll
  for (int rt = 0; rt < 2; ++rt) {
    #pragma unroll
    for (int r = 0; r < 4; ++r) {
      int m = m0 + w * 32 + rt * 16 + 4 * g + r;
      int bb = m / 900, tok = m - bb * 900;
      int gc = grid_in[m];
      #pragma unroll
      for (int ct = 0; ct < 4; ++ct) {
        int n = n0 + ct * 16 + c16;
        float a = acc[rt][ct][r];
        if (n < 256) {
          float val = a + embK[(size_t)gc * 256 + n] + posK[(size_t)tok * 256 + n];
          k2[(((size_t)bb * 4 + (n >> 6)) * 900 + tok) * 64 + (n & 63)] = f2bf(val);
        } else {
          int d = n - 256;
          float val = a + embV[(size_t)gc * 256 + d] + posV[(size_t)tok * 256 + d];
          v2[(((size_t)bb * 4 + (d >> 6)) * 900 + tok) * 64 + (d & 63)] = f2bf(val);
        }
      }
    }
  }
}

// ---------------------------------------------------------------------------
// Fused cross-attention per (head, batch): scores -> softmax -> PV.
// P (8x900) lives in LDS; no global score buffer, no atomics.
// ---------------------------------------------------------------------------
__global__ __launch_bounds__(256) void k_cross(const float* __restrict__ ws,
                                               const short* __restrict__ k2,
                                               const short* __restrict__ v2,
                                               float* __restrict__ crossOut) {
  const int h = blockIdx.x, b = blockIdx.y;
  const int hc = h * 64, tid = threadIdx.x;
  __shared__ float Pl[8][900];
  __shared__ float q2s[8][64];
  const float* q2 = ws + OFF_Q2;
  for (int idx = tid; idx < 512; idx += 256)
    q2s[idx >> 6][idx & 63] = q2[(size_t)(idx >> 6) * 256 + hc + (idx & 63)];
  __syncthreads();

  // scores
  for (int tt = tid; tt < 900; tt += 256) {
    const short* kr = k2 + ((size_t)(b * 4 + h) * 900 + tt) * 64;
    float accs[8] = {0.f, 0.f, 0.f, 0.f, 0.f, 0.f, 0.f, 0.f};
    #pragma unroll
    for (int ch = 0; ch < 8; ++ch) {
      bf16x8 kv = *(const bf16x8*)&kr[ch * 8];
      float kf[8];
      #pragma unroll
      for (int i = 0; i < 8; ++i) kf[i] = bf2f(kv[i]);
      #pragma unroll
      for (int l = 0; l < 8; ++l) {
        const float* qq = &q2s[l][ch * 8];
        accs[l] += kf[0]*qq[0] + kf[1]*qq[1] + kf[2]*qq[2] + kf[3]*qq[3] +
                   kf[4]*qq[4] + kf[5]*qq[5] + kf[6]*qq[6] + kf[7]*qq[7];
      }
    }
    #pragma unroll
    for (int l = 0; l < 8; ++l) Pl[l][tt] = accs[l] * 0.125f;
  }
  __syncthreads();

  // softmax: wave w handles rows w and w+4
  const int w = tid >> 6, lane = tid & 63;
  for (int rr = w; rr < 8; rr += 4) {
    float v[15]; float mx = -1e30f;
    #pragma unroll
    for (int k = 0; k < 15; ++k) {
      int t = lane + 64 * k;
      v[k] = (t < 900) ? Pl[rr][t] : -1e30f;
      mx = fmaxf(mx, v[k]);
    }
    for (int mk = 1; mk < 64; mk <<= 1) mx = fmaxf(mx, __shfl_xor(mx, mk));
    float sm = 0.f;
    #pragma unroll
    for (int k = 0; k < 15; ++k) { v[k] = __expf(v[k] - mx); sm += v[k]; }
    for (int mk = 1; mk < 64; mk <<= 1) sm += __shfl_xor(sm, mk);
    float inv = 1.f / sm;
    #pragma unroll
    for (int k = 0; k < 15; ++k) {
      int t = lane + 64 * k;
      if (t < 900) Pl[rr][t] = v[k] * inv;
    }
  }
  __syncthreads();

  // PV: thread = (l, d-pair)
  const int l = tid >> 5, dp = (tid & 31) * 2;
  const short* vb = v2 + ((size_t)(b * 4 + h) * 900) * 64 + dp;
  float a0 = 0.f, a1 = 0.f;
  #pragma unroll 4
  for (int t = 0; t < 900; ++t) {
    float p = Pl[l][t];
    short2 vv = *(const short2*)(vb + (size_t)t * 64);
    a0 += p * bf2f(vv.x);
    a1 += p * bf2f(vv.y);
  }
  float* o = crossOut + ((size_t)b * 8 + l) * 256 + hc + dp;
  o[0] = a0; o[1] = a1;
}

// logits[b,l,p] = crossOut[b,l,:] @ woOut[:,p] + b_out[p]
__global__ void k_logits(const float* __restrict__ ws,
                         const float* __restrict__ b_out,
                         float* __restrict__ out) {
  const float* crossOut = ws + OFF_CROSS;
  const float* woOut = ws + OFF_WOOUT;
  int idx = blockIdx.x * 256 + threadIdx.x;
  if (idx >= 32 * 8 * 12) return;
  int p = idx % 12;
  int bl = idx / 12;
  float acc = b_out[p];
  for (int d = 0; d < 256; ++d)
    acc = fmaf(crossOut[(size_t)bl * 256 + d], woOut[d * 12 + p], acc);
  out[idx] = acc;
}

// ---------------------------------------------------------------------------
// Program executor (verified r1): flood fill via row bitmasks, rotate 90 CW
// about anchor, paint color 3. One 64-thread block per batch element.
// ---------------------------------------------------------------------------
__global__ void k_execute(const int* __restrict__ grid_in,
                          const int* __restrict__ anchor,
                          float* __restrict__ outg) {
  const int b = blockIdx.x;
  const int lane = threadIdx.x;
  const int* g = grid_in + b * 900;
  int ar = anchor[2 * b], ac = anchor[2 * b + 1];
  ar = min(max(ar, 0), 29); ac = min(max(ac, 0), 29);
  const int seed = g[ar * 30 + ac];

  unsigned same = 0u;
  if (lane < 30)
    for (int c = 0; c < 30; ++c) same |= (unsigned)(g[lane * 30 + c] == seed) << c;

  unsigned cur = (lane == ar) ? (1u << ac) : 0u;
  bool changed = true;
  while (changed) {
    unsigned up = __shfl(cur, (lane + 63) & 63);
    unsigned dn = __shfl(cur, (lane + 1) & 63);
    if (lane == 0) up = 0u;
    unsigned nm = (cur | (cur << 1) | (cur >> 1) | up | dn) & same;
    changed = __any(nm != cur);
    cur = nm;
  }

  __shared__ unsigned msh[32];
  if (lane < 32) msh[lane] = (lane < 30) ? cur : 0u;
  __syncthreads();

  if (lane < 30) {
    unsigned rot = 0u;
    int cc = lane - ar + ac;
    if (cc >= 0 && cc < 30) {
      for (int nc = 0; nc < 30; ++nc) {
        int rr = ar + ac - nc;
        if (rr >= 0 && rr < 30) rot |= ((msh[rr] >> cc) & 1u) << nc;
      }
    }
    for (int c = 0; c < 30; ++c) {
      int v = ((rot >> c) & 1u) ? 3 : g[lane * 30 + c];
      outg[b * 900 + lane * 30 + c] = (float)v;
    }
  }
}

// ---------------------------------------------------------------------------
extern "C" void kernel_launch(void* const* d_in, const int* in_sizes, int n_in,
                              void* d_out, int out_size, void* d_ws, size_t ws_size,
                              hipStream_t stream) {
  const int*   grid_in = (const int*)d_in[0];
  const int*   anchor  = (const int*)d_in[1];
  const float* embed   = (const float*)d_in[2];
  const float* pos_emb = (const float*)d_in[3];
  const float* wq      = (const float*)d_in[4];
  const float* wk      = (const float*)d_in[5];
  const float* wv      = (const float*)d_in[6];
  const float* wo      = (const float*)d_in[7];
  const float* step_q  = (const float*)d_in[8];
  const float* w_out   = (const float*)d_in[9];
  const float* b_out   = (const float*)d_in[10];
  float* out = (float*)d_out;
  float* ws  = (float*)d_ws;
  short* wsS = (short*)(ws + OFF_F32_END);

  k_precompute<<<dim3(900, 10), dim3(256), 0, stream>>>(embed, pos_emb, wq, wk, wv,
                                                        wo, step_q, w_out, ws);
  k_attn<<<dim3(15, 4, 32), dim3(256), 0, stream>>>(grid_in, ws, wsS + SOFF_ATTN);
  k_delta<<<dim3(225, 8), dim3(256), 0, stream>>>(grid_in, ws, wsS + SOFF_ATTN,
                                                  wsS + SOFF_WOKVT,
                                                  wsS + SOFF_K2, wsS + SOFF_V2);
  k_cross<<<dim3(4, 32), dim3(256), 0, stream>>>(ws, wsS + SOFF_K2, wsS + SOFF_V2,
                                                 ws + OFF_CROSS);
  k_logits<<<dim3(12), dim3(256), 0, stream>>>(ws, b_out, out);
  k_execute<<<dim3(32), dim3(64), 0, stream>>>(grid_in, anchor, out + 32 * 8 * 12);
}

// Round 3
// 406.253 us; speedup vs baseline: 2.7285x; 1.5958x over previous
//
#include <hip/hip_runtime.h>

// ===========================================================================
// ARPS forward. Structure:
//   tok = embed[grid]+pos  =>  projections distribute over the gather.
//   k_precompute: tiny f32 GEMMs (embQ/K/V, posQ/K/V, wo@wk|wv (bf16,T),
//                 wo@w_out, step_q@wq)
//   k_kv:        materialize K bf16 [b][t][256] and V^T bf16 tiles
//                [bh][kt][64d][64t] (one gather+convert pass, LDS transpose)
//   k_attn:      flash self-attn, bf16 MFMA, 128 q-rows/block, dbuf
//                global_load_lds staging w/ source-swizzle, XCD-aware grid
//   k_delta:     [28800x512] = attnOut @ [woK|woV] MFMA GEMM, epilogue adds
//                gather -> k2/v2 (alias dead Kb/VT)
//   k_cross:     fused 8-query cross-attn per (b,h)
//   k_logits, k_execute (flood fill / rotate / paint)
// ===========================================================================

typedef __attribute__((ext_vector_type(8))) short bf16x8;   // 8 bf16 (4 VGPR)
typedef __attribute__((ext_vector_type(4))) float f32x4;    // MFMA acc

__device__ __forceinline__ short f2bf(float f) {
  union { float f; unsigned u; } v; v.f = f;
  unsigned r = v.u + 0x7fffu + ((v.u >> 16) & 1u);   // RNE
  return (short)(r >> 16);
}
__device__ __forceinline__ float bf2f(short s) {
  union { unsigned u; float f; } v; v.u = ((unsigned)(unsigned short)s) << 16;
  return v.f;
}
// XOR-swizzled index into a [rows][64] bf16 LDS tile (row stride 128B).
__device__ __forceinline__ int swz(int row, int col) {
  return row * 64 + ((((col >> 3) ^ row) & 7) << 3) + (col & 7);
}
// async global->LDS 16B copy; LDS dest is wave-uniform base + lane*16.
__device__ __forceinline__ void gload16(const short* gsrc, short* lds) {
  __builtin_amdgcn_global_load_lds(
      (const __attribute__((address_space(1))) unsigned int*)gsrc,
      (__attribute__((address_space(3))) unsigned int*)lds, 16, 0, 0);
}

// ---------------- workspace layout ----------------
// float region
constexpr size_t OFF_POSQ  = 0;                 // 900x256
constexpr size_t OFF_POSK  = 230400;
constexpr size_t OFF_POSV  = 460800;
constexpr size_t OFF_EMBQ  = 691200;            // 10x256 each
constexpr size_t OFF_EMBK  = 693760;
constexpr size_t OFF_EMBV  = 696320;
constexpr size_t OFF_WOOUT = 698880;            // 256x12
constexpr size_t OFF_Q2    = 701952;            // 8x256
constexpr size_t OFF_CROSS = 704000;            // 32x8x256
constexpr size_t OFF_F32_END = 769536;
// short (bf16) region, offsets in shorts from (short*)(ws+OFF_F32_END)
constexpr size_t SOFF_WOKVT = 0;                // [512][256]  (wo@wk | wo@wv)^T
constexpr size_t SOFF_ATTN  = 131072;           // [28800][256]
constexpr size_t SOFF_KB    = 7503872;          // [28800][256] K bf16; k2 aliases after attn
constexpr size_t SOFF_VT    = 14876672;         // [128 bh][15 kt][64d][64t]; v2 aliases
// end = 22740992 shorts (45.5 MB) + 3.1 MB f32

// ---------------------------------------------------------------------------
// Precompute GEMMs (f32, tiny). Jobs 3/4 store bf16 TRANSPOSED ([n][k]).
// ---------------------------------------------------------------------------
__global__ void k_precompute(const float* __restrict__ embed,
                             const float* __restrict__ pos_emb,
                             const float* __restrict__ wq,
                             const float* __restrict__ wk,
                             const float* __restrict__ wv,
                             const float* __restrict__ wo,
                             const float* __restrict__ step_q,
                             const float* __restrict__ w_out,
                             float* __restrict__ ws) {
  const int job = blockIdx.y;
  const float* A; const float* Wm; float* C = nullptr; int M; int N; int tr = 0;
  switch (job) {
    case 0: A=embed;  Wm=wq;    C=ws+OFF_EMBQ;  M=10;  N=256; break;
    case 1: A=embed;  Wm=wk;    C=ws+OFF_EMBK;  M=10;  N=256; break;
    case 2: A=embed;  Wm=wv;    C=ws+OFF_EMBV;  M=10;  N=256; break;
    case 3: A=wo;     Wm=wk;    M=256; N=256; tr=1; break;
    case 4: A=wo;     Wm=wv;    M=256; N=256; tr=2; break;
    case 5: A=wo;     Wm=w_out; C=ws+OFF_WOOUT; M=256; N=12;  break;
    case 6: A=step_q; Wm=wq;    C=ws+OFF_Q2;    M=8;   N=256; break;
    case 7: A=pos_emb;Wm=wq;    C=ws+OFF_POSQ;  M=900; N=256; break;
    case 8: A=pos_emb;Wm=wk;    C=ws+OFF_POSK;  M=900; N=256; break;
    default:A=pos_emb;Wm=wv;    C=ws+OFF_POSV;  M=900; N=256; break;
  }
  int idx = blockIdx.x * 256 + threadIdx.x;
  if (idx >= M * N) return;
  int m = idx / N, n = idx - m * N;
  const float* a = A + (size_t)m * 256;
  float acc = 0.f;
  #pragma unroll 8
  for (int k = 0; k < 256; ++k) acc = fmaf(a[k], Wm[(size_t)k * N + n], acc);
  if (tr) {
    short* wsS = (short*)(ws + OFF_F32_END);
    wsS[SOFF_WOKVT + (size_t)(n + (tr == 2 ? 256 : 0)) * 256 + m] = f2bf(acc);
  } else {
    C[idx] = acc;
  }
}

// ---------------------------------------------------------------------------
// Materialize K (row-major bf16) and V^T (tiled bf16) once.
// Block = (kt 0..14, b). V transpose via padded-65 f32 LDS (conflict-free).
// ---------------------------------------------------------------------------
__global__ __launch_bounds__(256) void k_kv(const int* __restrict__ grid_in,
                                            const float* __restrict__ ws,
                                            short* __restrict__ Kb,
                                            short* __restrict__ VT) {
  const int kt = blockIdx.x, b = blockIdx.y;
  const int t0 = kt * 64, tid = threadIdx.x;
  const float* posK = ws + OFF_POSK;
  const float* embK = ws + OFF_EMBK;
  const float* posV = ws + OFF_POSV;
  const float* embV = ws + OFF_EMBV;

  // K rows: 64 rows x 32 chunks of 8
  for (int i = tid; i < 2048; i += 256) {
    int row = i >> 5, ch = i & 31;
    int t = t0 + row;
    if (t > 899) continue;
    int g = grid_in[b * 900 + t];
    const float* pk = posK + (size_t)t * 256 + ch * 8;
    const float* ek = embK + (size_t)g * 256 + ch * 8;
    float4 p0 = *(const float4*)pk, p1 = *(const float4*)(pk + 4);
    float4 e0 = *(const float4*)ek, e1 = *(const float4*)(ek + 4);
    union { short s[8]; bf16x8 v; } u;
    u.s[0] = f2bf(p0.x + e0.x); u.s[1] = f2bf(p0.y + e0.y);
    u.s[2] = f2bf(p0.z + e0.z); u.s[3] = f2bf(p0.w + e0.w);
    u.s[4] = f2bf(p1.x + e1.x); u.s[5] = f2bf(p1.y + e1.y);
    u.s[6] = f2bf(p1.z + e1.z); u.s[7] = f2bf(p1.w + e1.w);
    *(bf16x8*)&Kb[((size_t)(b * 900 + t)) * 256 + ch * 8] = u.v;
  }

  // V^T tiles per head
  __shared__ float Lf[64 * 65];
  const int tt = tid & 63, dq = tid >> 6;
  for (int h = 0; h < 4; ++h) {
    __syncthreads();
    for (int i = tid; i < 512; i += 256) {
      int row = i >> 3, ch = i & 7;
      int t = t0 + row; if (t > 899) t = 899;
      int g = grid_in[b * 900 + t];
      const float* pv = posV + (size_t)t * 256 + h * 64 + ch * 8;
      const float* ev = embV + (size_t)g * 256 + h * 64 + ch * 8;
      float4 p0 = *(const float4*)pv, p1 = *(const float4*)(pv + 4);
      float4 e0 = *(const float4*)ev, e1 = *(const float4*)(ev + 4);
      float* L = &Lf[row * 65 + ch * 8];
      L[0] = p0.x + e0.x; L[1] = p0.y + e0.y; L[2] = p0.z + e0.z; L[3] = p0.w + e0.w;
      L[4] = p1.x + e1.x; L[5] = p1.y + e1.y; L[6] = p1.z + e1.z; L[7] = p1.w + e1.w;
    }
    __syncthreads();
    short* tile = VT + ((size_t)((b * 4 + h) * 15 + kt)) * 4096;
    #pragma unroll
    for (int dd = 0; dd < 16; ++dd) {
      int d = dq * 16 + dd;
      tile[d * 64 + tt] = f2bf(Lf[tt * 65 + d]);   // coalesced along tt
    }
  }
}

// ---------------------------------------------------------------------------
// Self-attention, bf16 MFMA flash. Block = 128 q-rows x (head, batch).
// 4 waves; wave w owns q rows {t0+w*16..+16} and {t0+64+w*16..+16}.
// K/V^T double-buffered via global_load_lds (source-swizzled, LDS linear).
// One __syncthreads per k-tile; stage issued before compute (overlap).
// ---------------------------------------------------------------------------
__global__ __launch_bounds__(256) void k_attn(const int* __restrict__ grid_in,
                                              const float* __restrict__ ws,
                                              const short* __restrict__ Kb,
                                              const short* __restrict__ VT,
                                              short* __restrict__ attnOut) {
  const int bidx = blockIdx.x;                  // XCD-aware encoding
  const int bh = ((bidx >> 6) << 3) | (bidx & 7);   // same bh -> same idx%8
  const int qt = (bidx >> 3) & 7;
  const int h = bh & 3, b = bh >> 2;
  const int t0 = qt * 128, hc = h * 64;
  const int tid = threadIdx.x, w = tid >> 6, lane = tid & 63;
  const int g = lane >> 4, c16 = lane & 15;
  const size_t tileBase = (size_t)(bh * 15) * 4096;

  __shared__ __align__(16) short Ks[2][4096];
  __shared__ __align__(16) short Vs[2][4096];
  __shared__ __align__(16) short Ps[4096];

  const float* posQ = ws + OFF_POSQ;
  const float* embQ = ws + OFF_EMBQ;

  // Q fragments direct to registers (once), 0.125 scale folded.
  bf16x8 aQ[2][2];
  #pragma unroll
  for (int s = 0; s < 2; ++s) {
    int t = t0 + s * 64 + w * 16 + c16; if (t > 899) t = 899;
    int gq = grid_in[b * 900 + t];
    #pragma unroll
    for (int kc = 0; kc < 2; ++kc) {
      union { short s8[8]; bf16x8 v; } u;
      #pragma unroll
      for (int j = 0; j < 8; ++j) {
        int d = hc + kc * 32 + g * 8 + j;
        u.s8[j] = f2bf(0.125f * (embQ[gq * 256 + d] + posQ[(size_t)t * 256 + d]));
      }
      aQ[s][kc] = u.v;
    }
  }

#define STAGE(BUF, KT)                                                        \
  do {                                                                        \
    int kk0_ = (KT) * 64;                                                     \
    _Pragma("unroll")                                                         \
    for (int j_ = 0; j_ < 2; ++j_) {                                          \
      int c_ = j_ * 256 + w * 64 + lane;                                      \
      int row_ = c_ >> 3, ch_ = c_ & 7;                                       \
      int t_ = kk0_ + row_; if (t_ > 899) t_ = 899;                           \
      int sw_ = ((ch_ ^ row_) & 7) << 3;                                      \
      gload16(Kb + ((size_t)(b * 900 + t_)) * 256 + hc + sw_,                 \
              &Ks[BUF][(j_ * 256 + w * 64) << 3]);                            \
      gload16(VT + tileBase + (size_t)(KT) * 4096 + (row_ << 6) + sw_,        \
              &Vs[BUF][(j_ * 256 + w * 64) << 3]);                            \
    }                                                                         \
  } while (0)

  float m_[2][4], l_[2][4];
  f32x4 O[2][4];
  #pragma unroll
  for (int s = 0; s < 2; ++s)
    #pragma unroll
    for (int r = 0; r < 4; ++r) { m_[s][r] = -1e30f; l_[s][r] = 0.f; }
  #pragma unroll
  for (int s = 0; s < 2; ++s)
    #pragma unroll
    for (int dt = 0; dt < 4; ++dt) { f32x4 z = {0.f,0.f,0.f,0.f}; O[s][dt] = z; }

  STAGE(0, 0);
  __syncthreads();

  int cur = 0;
  for (int kt = 0; kt < 15; ++kt) {
    if (kt + 1 < 15) STAGE(cur ^ 1, kt + 1);   // issue-early: flies under compute
    const int k0 = kt * 64;

    // ---- S = Q K^T (both q-subtiles) ----
    f32x4 sacc[2][4];
    #pragma unroll
    for (int ct = 0; ct < 4; ++ct) {
      bf16x8 bK0 = *(bf16x8*)&Ks[cur][swz(ct * 16 + c16, g * 8)];
      bf16x8 bK1 = *(bf16x8*)&Ks[cur][swz(ct * 16 + c16, 32 + g * 8)];
      #pragma unroll
      for (int s = 0; s < 2; ++s) {
        f32x4 z = {0.f, 0.f, 0.f, 0.f};
        z = __builtin_amdgcn_mfma_f32_16x16x32_bf16(aQ[s][0], bK0, z, 0, 0, 0);
        z = __builtin_amdgcn_mfma_f32_16x16x32_bf16(aQ[s][1], bK1, z, 0, 0, 0);
        if (k0 + ct * 16 + c16 >= 900) { z[0] = -1e30f; z[1] = -1e30f; z[2] = -1e30f; z[3] = -1e30f; }
        sacc[s][ct] = z;
      }
    }

    // ---- per-subtile: online softmax -> P -> PV ----
    #pragma unroll
    for (int s = 0; s < 2; ++s) {
      #pragma unroll
      for (int r = 0; r < 4; ++r) {
        float rm = fmaxf(fmaxf(sacc[s][0][r], sacc[s][1][r]),
                         fmaxf(sacc[s][2][r], sacc[s][3][r]));
        rm = fmaxf(rm, __shfl_xor(rm, 1));
        rm = fmaxf(rm, __shfl_xor(rm, 2));
        rm = fmaxf(rm, __shfl_xor(rm, 4));
        rm = fmaxf(rm, __shfl_xor(rm, 8));
        float mn = fmaxf(m_[s][r], rm);
        float sc = __expf(m_[s][r] - mn);
        float rs = 0.f;
        #pragma unroll
        for (int ct = 0; ct < 4; ++ct) {
          float p = __expf(sacc[s][ct][r] - mn);
          sacc[s][ct][r] = p; rs += p;
        }
        rs += __shfl_xor(rs, 1);
        rs += __shfl_xor(rs, 2);
        rs += __shfl_xor(rs, 4);
        rs += __shfl_xor(rs, 8);
        l_[s][r] = l_[s][r] * sc + rs;
        m_[s][r] = mn;
        #pragma unroll
        for (int dt = 0; dt < 4; ++dt) O[s][dt][r] *= sc;
      }
      #pragma unroll
      for (int ct = 0; ct < 4; ++ct)
        #pragma unroll
        for (int r = 0; r < 4; ++r)
          Ps[swz(w * 16 + 4 * g + r, ct * 16 + c16)] = f2bf(sacc[s][ct][r]);
      #pragma unroll
      for (int c = 0; c < 2; ++c) {
        bf16x8 aP = *(bf16x8*)&Ps[swz(w * 16 + c16, c * 32 + g * 8)];
        #pragma unroll
        for (int dt = 0; dt < 4; ++dt) {
          bf16x8 bV = *(bf16x8*)&Vs[cur][swz(dt * 16 + c16, c * 32 + g * 8)];
          O[s][dt] = __builtin_amdgcn_mfma_f32_16x16x32_bf16(aP, bV, O[s][dt], 0, 0, 0);
        }
      }
    }

    __syncthreads();   // drains staged loads (vmcnt 0) + orders LDS reuse
    cur ^= 1;
  }
#undef STAGE

  // ---- epilogue ----
  #pragma unroll
  for (int s = 0; s < 2; ++s)
    #pragma unroll
    for (int r = 0; r < 4; ++r) {
      int t = t0 + s * 64 + w * 16 + 4 * g + r;
      if (t < 900) {
        float inv = 1.f / l_[s][r];
        #pragma unroll
        for (int dt = 0; dt < 4; ++dt)
          attnOut[((size_t)(b * 900 + t)) * 256 + hc + dt * 16 + c16] =
              f2bf(O[s][dt][r] * inv);
      }
    }
}

// ---------------------------------------------------------------------------
// Delta GEMM: C[28800x512] = attnOut(bf16) @ [woK|woV]; epilogue adds gather
// and stores k2/v2 bf16 [b][h][900][64]. Tile 128x128, BK=64, gload_lds.
// ---------------------------------------------------------------------------
__global__ __launch_bounds__(256) void k_delta(const int* __restrict__ grid_in,
                                               const float* __restrict__ ws,
                                               const short* __restrict__ attnOut,
                                               const short* __restrict__ wokvT,
                                               short* __restrict__ k2,
                                               short* __restrict__ v2) {
  const int m0 = blockIdx.x * 128, n0 = blockIdx.y * 128;
  const int tid = threadIdx.x, w = tid >> 6, lane = tid & 63;
  const int g = lane >> 4, c16 = lane & 15;
  __shared__ __align__(16) short As[8192];
  __shared__ __align__(16) short Bs[8192];
  f32x4 acc[2][8];
  #pragma unroll
  for (int rt = 0; rt < 2; ++rt)
    #pragma unroll
    for (int ct = 0; ct < 8; ++ct) { f32x4 z = {0.f,0.f,0.f,0.f}; acc[rt][ct] = z; }

  for (int kk = 0; kk < 4; ++kk) {
    if (kk) __syncthreads();
    #pragma unroll
    for (int j = 0; j < 4; ++j) {
      int c = j * 256 + w * 64 + lane;
      int row = c >> 3, ch = c & 7;
      int sw = ((ch ^ row) & 7) << 3;
      gload16(attnOut + ((size_t)(m0 + row)) * 256 + kk * 64 + sw,
              &As[(j * 256 + w * 64) << 3]);
      gload16(wokvT + ((size_t)(n0 + row)) * 256 + kk * 64 + sw,
              &Bs[(j * 256 + w * 64) << 3]);
    }
    __syncthreads();
    #pragma unroll
    for (int ks = 0; ks < 2; ++ks) {
      bf16x8 aA0 = *(bf16x8*)&As[swz(w * 32 + c16, ks * 32 + g * 8)];
      bf16x8 aA1 = *(bf16x8*)&As[swz(w * 32 + 16 + c16, ks * 32 + g * 8)];
      #pragma unroll
      for (int ct = 0; ct < 8; ++ct) {
        bf16x8 bB = *(bf16x8*)&Bs[swz(ct * 16 + c16, ks * 32 + g * 8)];
        acc[0][ct] = __builtin_amdgcn_mfma_f32_16x16x32_bf16(aA0, bB, acc[0][ct], 0, 0, 0);
        acc[1][ct] = __builtin_amdgcn_mfma_f32_16x16x32_bf16(aA1, bB, acc[1][ct], 0, 0, 0);
      }
    }
  }

  const float* embK = ws + OFF_EMBK;
  const float* posK = ws + OFF_POSK;
  const float* embV = ws + OFF_EMBV;
  const float* posV = ws + OFF_POSV;
  #pragma unroll
  for (int rt = 0; rt < 2; ++rt) {
    #pragma unroll
    for (int r = 0; r < 4; ++r) {
      int m = m0 + w * 32 + rt * 16 + 4 * g + r;
      int bb = m / 900, tok = m - bb * 900;
      int gc = grid_in[m];
      #pragma unroll
      for (int ct = 0; ct < 8; ++ct) {
        int n = n0 + ct * 16 + c16;
        float a = acc[rt][ct][r];
        if (n < 256) {
          float val = a + embK[(size_t)gc * 256 + n] + posK[(size_t)tok * 256 + n];
          k2[(((size_t)bb * 4 + (n >> 6)) * 900 + tok) * 64 + (n & 63)] = f2bf(val);
        } else {
          int d = n - 256;
          float val = a + embV[(size_t)gc * 256 + d] + posV[(size_t)tok * 256 + d];
          v2[(((size_t)bb * 4 + (d >> 6)) * 900 + tok) * 64 + (d & 63)] = f2bf(val);
        }
      }
    }
  }
}

// ---------------------------------------------------------------------------
// Fused cross-attention per (head, batch): scores -> softmax -> PV.
// ---------------------------------------------------------------------------
__global__ __launch_bounds__(256) void k_cross(const float* __restrict__ ws,
                                               const short* __restrict__ k2,
                                               const short* __restrict__ v2,
                                               float* __restrict__ crossOut) {
  const int h = blockIdx.x, b = blockIdx.y;
  const int hc = h * 64, tid = threadIdx.x;
  __shared__ float Pl[8][900];
  __shared__ float q2s[8][64];
  const float* q2 = ws + OFF_Q2;
  for (int idx = tid; idx < 512; idx += 256)
    q2s[idx >> 6][idx & 63] = q2[(size_t)(idx >> 6) * 256 + hc + (idx & 63)];
  __syncthreads();

  for (int tt = tid; tt < 900; tt += 256) {
    const short* kr = k2 + ((size_t)(b * 4 + h) * 900 + tt) * 64;
    float accs[8] = {0.f, 0.f, 0.f, 0.f, 0.f, 0.f, 0.f, 0.f};
    #pragma unroll
    for (int ch = 0; ch < 8; ++ch) {
      bf16x8 kv = *(const bf16x8*)&kr[ch * 8];
      float kf[8];
      #pragma unroll
      for (int i = 0; i < 8; ++i) kf[i] = bf2f(kv[i]);
      #pragma unroll
      for (int l = 0; l < 8; ++l) {
        const float* qq = &q2s[l][ch * 8];
        accs[l] += kf[0]*qq[0] + kf[1]*qq[1] + kf[2]*qq[2] + kf[3]*qq[3] +
                   kf[4]*qq[4] + kf[5]*qq[5] + kf[6]*qq[6] + kf[7]*qq[7];
      }
    }
    #pragma unroll
    for (int l = 0; l < 8; ++l) Pl[l][tt] = accs[l] * 0.125f;
  }
  __syncthreads();

  const int w = tid >> 6, lane = tid & 63;
  for (int rr = w; rr < 8; rr += 4) {
    float v[15]; float mx = -1e30f;
    #pragma unroll
    for (int k = 0; k < 15; ++k) {
      int t = lane + 64 * k;
      v[k] = (t < 900) ? Pl[rr][t] : -1e30f;
      mx = fmaxf(mx, v[k]);
    }
    for (int mk = 1; mk < 64; mk <<= 1) mx = fmaxf(mx, __shfl_xor(mx, mk));
    float sm = 0.f;
    #pragma unroll
    for (int k = 0; k < 15; ++k) { v[k] = __expf(v[k] - mx); sm += v[k]; }
    for (int mk = 1; mk < 64; mk <<= 1) sm += __shfl_xor(sm, mk);
    float inv = 1.f / sm;
    #pragma unroll
    for (int k = 0; k < 15; ++k) {
      int t = lane + 64 * k;
      if (t < 900) Pl[rr][t] = v[k] * inv;
    }
  }
  __syncthreads();

  const int l = tid >> 5, dp = (tid & 31) * 2;
  const short* vb = v2 + ((size_t)(b * 4 + h) * 900) * 64 + dp;
  float a0 = 0.f, a1 = 0.f;
  #pragma unroll 4
  for (int t = 0; t < 900; ++t) {
    float p = Pl[l][t];
    short2 vv = *(const short2*)(vb + (size_t)t * 64);
    a0 += p * bf2f(vv.x);
    a1 += p * bf2f(vv.y);
  }
  float* o = crossOut + ((size_t)b * 8 + l) * 256 + hc + dp;
  o[0] = a0; o[1] = a1;
}

// logits[b,l,p] = crossOut[b,l,:] @ woOut[:,p] + b_out[p]
__global__ void k_logits(const float* __restrict__ ws,
                         const float* __restrict__ b_out,
                         float* __restrict__ out) {
  const float* crossOut = ws + OFF_CROSS;
  const float* woOut = ws + OFF_WOOUT;
  int idx = blockIdx.x * 256 + threadIdx.x;
  if (idx >= 32 * 8 * 12) return;
  int p = idx % 12;
  int bl = idx / 12;
  float acc = b_out[p];
  for (int d = 0; d < 256; ++d)
    acc = fmaf(crossOut[(size_t)bl * 256 + d], woOut[d * 12 + p], acc);
  out[idx] = acc;
}

// ---------------------------------------------------------------------------
// Program executor (verified): flood fill, rotate 90 CW about anchor, paint.
// ---------------------------------------------------------------------------
__global__ void k_execute(const int* __restrict__ grid_in,
                          const int* __restrict__ anchor,
                          float* __restrict__ outg) {
  const int b = blockIdx.x;
  const int lane = threadIdx.x;
  const int* g = grid_in + b * 900;
  int ar = anchor[2 * b], ac = anchor[2 * b + 1];
  ar = min(max(ar, 0), 29); ac = min(max(ac, 0), 29);
  const int seed = g[ar * 30 + ac];

  unsigned same = 0u;
  if (lane < 30)
    for (int c = 0; c < 30; ++c) same |= (unsigned)(g[lane * 30 + c] == seed) << c;

  unsigned cur = (lane == ar) ? (1u << ac) : 0u;
  bool changed = true;
  while (changed) {
    unsigned up = __shfl(cur, (lane + 63) & 63);
    unsigned dn = __shfl(cur, (lane + 1) & 63);
    if (lane == 0) up = 0u;
    unsigned nm = (cur | (cur << 1) | (cur >> 1) | up | dn) & same;
    changed = __any(nm != cur);
    cur = nm;
  }

  __shared__ unsigned msh[32];
  if (lane < 32) msh[lane] = (lane < 30) ? cur : 0u;
  __syncthreads();

  if (lane < 30) {
    unsigned rot = 0u;
    int cc = lane - ar + ac;
    if (cc >= 0 && cc < 30) {
      for (int nc = 0; nc < 30; ++nc) {
        int rr = ar + ac - nc;
        if (rr >= 0 && rr < 30) rot |= ((msh[rr] >> cc) & 1u) << nc;
      }
    }
    for (int c = 0; c < 30; ++c) {
      int v = ((rot >> c) & 1u) ? 3 : g[lane * 30 + c];
      outg[b * 900 + lane * 30 + c] = (float)v;
    }
  }
}

// ---------------------------------------------------------------------------
extern "C" void kernel_launch(void* const* d_in, const int* in_sizes, int n_in,
                              void* d_out, int out_size, void* d_ws, size_t ws_size,
                              hipStream_t stream) {
  const int*   grid_in = (const int*)d_in[0];
  const int*   anchor  = (const int*)d_in[1];
  const float* embed   = (const float*)d_in[2];
  const float* pos_emb = (const float*)d_in[3];
  const float* wq      = (const float*)d_in[4];
  const float* wk      = (const float*)d_in[5];
  const float* wv      = (const float*)d_in[6];
  const float* wo      = (const float*)d_in[7];
  const float* step_q  = (const float*)d_in[8];
  const float* w_out   = (const float*)d_in[9];
  const float* b_out   = (const float*)d_in[10];
  float* out = (float*)d_out;
  float* ws  = (float*)d_ws;
  short* wsS = (short*)(ws + OFF_F32_END);

  k_precompute<<<dim3(900, 10), dim3(256), 0, stream>>>(embed, pos_emb, wq, wk, wv,
                                                        wo, step_q, w_out, ws);
  k_kv<<<dim3(15, 32), dim3(256), 0, stream>>>(grid_in, ws,
                                               wsS + SOFF_KB, wsS + SOFF_VT);
  k_attn<<<dim3(1024), dim3(256), 0, stream>>>(grid_in, ws, wsS + SOFF_KB,
                                               wsS + SOFF_VT, wsS + SOFF_ATTN);
  k_delta<<<dim3(225, 4), dim3(256), 0, stream>>>(grid_in, ws, wsS + SOFF_ATTN,
                                                  wsS + SOFF_WOKVT,
                                                  wsS + SOFF_KB, wsS + SOFF_VT);
  k_cross<<<dim3(4, 32), dim3(256), 0, stream>>>(ws, wsS + SOFF_KB, wsS + SOFF_VT,
                                                 ws + OFF_CROSS);
  k_logits<<<dim3(12), dim3(256), 0, stream>>>(ws, b_out, out);
  k_execute<<<dim3(32), dim3(64), 0, stream>>>(grid_in, anchor, out + 32 * 8 * 12);
}

// Round 4
// 336.798 us; speedup vs baseline: 3.2912x; 1.2062x over previous
//
#include <hip/hip_runtime.h>

// ===========================================================================
// ARPS forward. tok = embed[grid]+pos => projections distribute over gather.
//   k_small:    tiny f32 GEMMs (embQ/K/V, wo@wk|wv (bf16,T), wo@w_out, q2)
//   k_pos_gemm: tiled f32 GEMM posQ/K/V = pos_emb @ [wq|wk|wv]
//   k_kv:       materialize K bf16 rows + V^T bf16 tiles (one gather pass)
//   k_attn:     flash self-attn, swapped-QK^T S^T layout, m=0 softmax,
//               bf16 MFMA, dbuf global_load_lds staging, XCD-aware grid
//   k_delta:    [28800x512] attnOut @ [woK|woV] MFMA GEMM -> k2/v2
//   k_cross:    fused 8-query cross-attn per (b,h)
//   k_logits, k_execute (flood fill / rotate / paint)
// ===========================================================================

typedef __attribute__((ext_vector_type(8))) short bf16x8;   // 8 bf16 (4 VGPR)
typedef __attribute__((ext_vector_type(4))) float f32x4;    // MFMA acc

__device__ __forceinline__ short f2bf(float f) {
  union { float f; unsigned u; } v; v.f = f;
  unsigned r = v.u + 0x7fffu + ((v.u >> 16) & 1u);   // RNE
  return (short)(r >> 16);
}
__device__ __forceinline__ float bf2f(short s) {
  union { unsigned u; float f; } v; v.u = ((unsigned)(unsigned short)s) << 16;
  return v.f;
}
// pack 2 f32 -> 2 bf16 (RNE), gfx950 single instruction (no builtin, T12)
__device__ __forceinline__ unsigned cvt_pk_bf16(float lo, float hi) {
  unsigned r;
  asm("v_cvt_pk_bf16_f32 %0, %1, %2" : "=v"(r) : "v"(lo), "v"(hi));
  return r;
}
// XOR-swizzled index into a [rows][64] bf16 LDS tile (row stride 128B).
__device__ __forceinline__ int swz(int row, int col) {
  return row * 64 + ((((col >> 3) ^ row) & 7) << 3) + (col & 7);
}
// async global->LDS 16B copy; LDS dest is wave-uniform base + lane*16.
__device__ __forceinline__ void gload16(const short* gsrc, short* lds) {
  __builtin_amdgcn_global_load_lds(
      (const __attribute__((address_space(1))) unsigned int*)gsrc,
      (__attribute__((address_space(3))) unsigned int*)lds, 16, 0, 0);
}

// ---------------- workspace layout ----------------
// float region
constexpr size_t OFF_POSQ  = 0;                 // 900x256
constexpr size_t OFF_POSK  = 230400;
constexpr size_t OFF_POSV  = 460800;
constexpr size_t OFF_EMBQ  = 691200;            // 10x256 each
constexpr size_t OFF_EMBK  = 693760;
constexpr size_t OFF_EMBV  = 696320;
constexpr size_t OFF_WOOUT = 698880;            // 256x12
constexpr size_t OFF_Q2    = 701952;            // 8x256
constexpr size_t OFF_CROSS = 704000;            // 32x8x256
constexpr size_t OFF_F32_END = 769536;
// short (bf16) region, offsets in shorts from (short*)(ws+OFF_F32_END)
constexpr size_t SOFF_WOKVT = 0;                // [512][256]  (wo@wk | wo@wv)^T
constexpr size_t SOFF_ATTN  = 131072;           // [28800][256]
constexpr size_t SOFF_KB    = 7503872;          // [28800][256] K bf16; k2 aliases
constexpr size_t SOFF_VT    = 14876672;         // [128 bh][15 kt][64d][64t]; v2 aliases

// ---------------------------------------------------------------------------
// Small precompute GEMMs, exact-sized grid (562 blocks).
// ---------------------------------------------------------------------------
__global__ void k_small(const float* __restrict__ embed,
                        const float* __restrict__ wq,
                        const float* __restrict__ wk,
                        const float* __restrict__ wv,
                        const float* __restrict__ wo,
                        const float* __restrict__ step_q,
                        const float* __restrict__ w_out,
                        float* __restrict__ ws) {
  const int blk = blockIdx.x;
  int job, base;
  if      (blk < 10)  { job = 0; base = blk; }
  else if (blk < 20)  { job = 1; base = blk - 10; }
  else if (blk < 30)  { job = 2; base = blk - 20; }
  else if (blk < 286) { job = 3; base = blk - 30; }
  else if (blk < 542) { job = 4; base = blk - 286; }
  else if (blk < 554) { job = 5; base = blk - 542; }
  else                { job = 6; base = blk - 554; }
  const float* A; const float* Wm; float* C = nullptr; int M; int N; int tr = 0;
  switch (job) {
    case 0: A=embed;  Wm=wq;    C=ws+OFF_EMBQ;  M=10;  N=256; break;
    case 1: A=embed;  Wm=wk;    C=ws+OFF_EMBK;  M=10;  N=256; break;
    case 2: A=embed;  Wm=wv;    C=ws+OFF_EMBV;  M=10;  N=256; break;
    case 3: A=wo;     Wm=wk;    M=256; N=256; tr=1; break;
    case 4: A=wo;     Wm=wv;    M=256; N=256; tr=2; break;
    case 5: A=wo;     Wm=w_out; C=ws+OFF_WOOUT; M=256; N=12;  break;
    default:A=step_q; Wm=wq;    C=ws+OFF_Q2;    M=8;   N=256; break;
  }
  int idx = base * 256 + threadIdx.x;
  if (idx >= M * N) return;
  int m = idx / N, n = idx - m * N;
  const float* a = A + (size_t)m * 256;
  float acc = 0.f;
  #pragma unroll 8
  for (int k = 0; k < 256; ++k) acc = fmaf(a[k], Wm[(size_t)k * N + n], acc);
  if (tr) {
    short* wsS = (short*)(ws + OFF_F32_END);
    wsS[SOFF_WOKVT + (size_t)(n + (tr == 2 ? 256 : 0)) * 256 + m] = f2bf(acc);
  } else {
    C[idx] = acc;
  }
}

// ---------------------------------------------------------------------------
// Tiled f32 GEMM: [posQ|posK|posV](900x768) = pos_emb(900x256) @ [wq|wk|wv].
// Block: 64x64 tile, 256 threads, 4x4 micro-tiles. Grid (15, 12).
// ---------------------------------------------------------------------------
__global__ __launch_bounds__(256) void k_pos_gemm(const float* __restrict__ pos_emb,
                                                  const float* __restrict__ wq,
                                                  const float* __restrict__ wk,
                                                  const float* __restrict__ wv,
                                                  float* __restrict__ ws) {
  const int mt = blockIdx.x, nt = blockIdx.y;
  const float* W = nt < 4 ? wq : (nt < 8 ? wk : wv);
  float* C = ws + (nt < 4 ? OFF_POSQ : (nt < 8 ? OFF_POSK : OFF_POSV));
  const int n0 = (nt & 3) * 64, m0 = mt * 64;
  const int tid = threadIdx.x, tr = tid >> 4, tc = tid & 15;
  __shared__ float As[64][68];
  __shared__ float Bs[64][68];
  float acc[4][4] = {};
  for (int kc = 0; kc < 4; ++kc) {
    __syncthreads();
    for (int i = tid; i < 1024; i += 256) {
      int row = i >> 4, c4 = (i & 15) * 4;
      int m = m0 + row; if (m > 899) m = 899;
      *(float4*)&As[row][c4] = *(const float4*)&pos_emb[(size_t)m * 256 + kc * 64 + c4];
      *(float4*)&Bs[row][c4] = *(const float4*)&W[(size_t)(kc * 64 + row) * 256 + n0 + c4];
    }
    __syncthreads();
    #pragma unroll 8
    for (int kk = 0; kk < 64; ++kk) {
      float a0 = As[4*tr+0][kk], a1 = As[4*tr+1][kk];
      float a2 = As[4*tr+2][kk], a3 = As[4*tr+3][kk];
      float4 b4 = *(const float4*)&Bs[kk][4*tc];
      acc[0][0]+=a0*b4.x; acc[0][1]+=a0*b4.y; acc[0][2]+=a0*b4.z; acc[0][3]+=a0*b4.w;
      acc[1][0]+=a1*b4.x; acc[1][1]+=a1*b4.y; acc[1][2]+=a1*b4.z; acc[1][3]+=a1*b4.w;
      acc[2][0]+=a2*b4.x; acc[2][1]+=a2*b4.y; acc[2][2]+=a2*b4.z; acc[2][3]+=a2*b4.w;
      acc[3][0]+=a3*b4.x; acc[3][1]+=a3*b4.y; acc[3][2]+=a3*b4.z; acc[3][3]+=a3*b4.w;
    }
  }
  #pragma unroll
  for (int i = 0; i < 4; ++i) {
    int m = m0 + 4 * tr + i;
    if (m < 900)
      *(float4*)&C[(size_t)m * 256 + n0 + 4 * tc] =
          make_float4(acc[i][0], acc[i][1], acc[i][2], acc[i][3]);
  }
}

// ---------------------------------------------------------------------------
// Materialize K (row-major bf16) and V^T (tiled bf16) once.
// ---------------------------------------------------------------------------
__global__ __launch_bounds__(256) void k_kv(const int* __restrict__ grid_in,
                                            const float* __restrict__ ws,
                                            short* __restrict__ Kb,
                                            short* __restrict__ VT) {
  const int kt = blockIdx.x, b = blockIdx.y;
  const int t0 = kt * 64, tid = threadIdx.x;
  const float* posK = ws + OFF_POSK;
  const float* embK = ws + OFF_EMBK;
  const float* posV = ws + OFF_POSV;
  const float* embV = ws + OFF_EMBV;

  for (int i = tid; i < 2048; i += 256) {
    int row = i >> 5, ch = i & 31;
    int t = t0 + row;
    if (t > 899) continue;
    int g = grid_in[b * 900 + t];
    const float* pk = posK + (size_t)t * 256 + ch * 8;
    const float* ek = embK + (size_t)g * 256 + ch * 8;
    float4 p0 = *(const float4*)pk, p1 = *(const float4*)(pk + 4);
    float4 e0 = *(const float4*)ek, e1 = *(const float4*)(ek + 4);
    union { short s[8]; bf16x8 v; } u;
    u.s[0] = f2bf(p0.x + e0.x); u.s[1] = f2bf(p0.y + e0.y);
    u.s[2] = f2bf(p0.z + e0.z); u.s[3] = f2bf(p0.w + e0.w);
    u.s[4] = f2bf(p1.x + e1.x); u.s[5] = f2bf(p1.y + e1.y);
    u.s[6] = f2bf(p1.z + e1.z); u.s[7] = f2bf(p1.w + e1.w);
    *(bf16x8*)&Kb[((size_t)(b * 900 + t)) * 256 + ch * 8] = u.v;
  }

  __shared__ float Lf[64 * 65];
  const int tt = tid & 63, dq = tid >> 6;
  for (int h = 0; h < 4; ++h) {
    __syncthreads();
    for (int i = tid; i < 512; i += 256) {
      int row = i >> 3, ch = i & 7;
      int t = t0 + row; if (t > 899) t = 899;
      int g = grid_in[b * 900 + t];
      const float* pv = posV + (size_t)t * 256 + h * 64 + ch * 8;
      const float* ev = embV + (size_t)g * 256 + h * 64 + ch * 8;
      float4 p0 = *(const float4*)pv, p1 = *(const float4*)(pv + 4);
      float4 e0 = *(const float4*)ev, e1 = *(const float4*)(ev + 4);
      float* L = &Lf[row * 65 + ch * 8];
      L[0] = p0.x + e0.x; L[1] = p0.y + e0.y; L[2] = p0.z + e0.z; L[3] = p0.w + e0.w;
      L[4] = p1.x + e1.x; L[5] = p1.y + e1.y; L[6] = p1.z + e1.z; L[7] = p1.w + e1.w;
    }
    __syncthreads();
    short* tile = VT + ((size_t)((b * 4 + h) * 15 + kt)) * 4096;
    #pragma unroll
    for (int dd = 0; dd < 16; ++dd) {
      int d = dq * 16 + dd;
      tile[d * 64 + tt] = f2bf(Lf[tt * 65 + d]);
    }
  }
}

// ---------------------------------------------------------------------------
// Self-attention, swapped-QK^T (S^T: lane owns one q-column), m=0 softmax.
// Block = 128 q-rows x (head, batch), 4 waves. K/V^T dbuf global_load_lds.
// ---------------------------------------------------------------------------
__global__ __launch_bounds__(256) void k_attn(const int* __restrict__ grid_in,
                                              const float* __restrict__ ws,
                                              const short* __restrict__ Kb,
                                              const short* __restrict__ VT,
                                              short* __restrict__ attnOut) {
  const int bidx = blockIdx.x;                      // XCD-aware encoding
  const int bh = ((bidx >> 6) << 3) | (bidx & 7);
  const int qt = (bidx >> 3) & 7;
  const int h = bh & 3, b = bh >> 2;
  const int t0 = qt * 128, hc = h * 64;
  const int tid = threadIdx.x, w = tid >> 6, lane = tid & 63;
  const int g = lane >> 4, c16 = lane & 15;
  const size_t tileBase = (size_t)(bh * 15) * 4096;

  __shared__ __align__(16) short Ks[2][4096];
  __shared__ __align__(16) short Vs[2][4096];
  __shared__ __align__(16) short Ps[4096];

  const float* posQ = ws + OFF_POSQ;
  const float* embQ = ws + OFF_EMBQ;

  // Q fragments direct to registers (0.125 scale folded).
  bf16x8 aQ[2][2];
  #pragma unroll
  for (int s = 0; s < 2; ++s) {
    int t = t0 + s * 64 + w * 16 + c16; if (t > 899) t = 899;
    int gq = grid_in[b * 900 + t];
    #pragma unroll
    for (int kc = 0; kc < 2; ++kc) {
      union { short s8[8]; bf16x8 v; } u;
      #pragma unroll
      for (int j = 0; j < 8; ++j) {
        int d = hc + kc * 32 + g * 8 + j;
        u.s8[j] = f2bf(0.125f * (embQ[gq * 256 + d] + posQ[(size_t)t * 256 + d]));
      }
      aQ[s][kc] = u.v;
    }
  }

#define STAGE(BUF, KT)                                                        \
  do {                                                                        \
    int kk0_ = (KT) * 64;                                                     \
    _Pragma("unroll")                                                         \
    for (int j_ = 0; j_ < 2; ++j_) {                                          \
      int c_ = j_ * 256 + w * 64 + lane;                                      \
      int row_ = c_ >> 3, ch_ = c_ & 7;                                       \
      int t_ = kk0_ + row_; if (t_ > 899) t_ = 899;                           \
      int sw_ = ((ch_ ^ row_) & 7) << 3;                                      \
      gload16(Kb + ((size_t)(b * 900 + t_)) * 256 + hc + sw_,                 \
              &Ks[BUF][(j_ * 256 + w * 64) << 3]);                            \
      gload16(VT + tileBase + (size_t)(KT) * 4096 + (row_ << 6) + sw_,        \
              &Vs[BUF][(j_ * 256 + w * 64) << 3]);                            \
    }                                                                         \
  } while (0)

  float l_[2] = {0.f, 0.f};          // per-lane: sum for q-column c16
  f32x4 O[2][4];
  #pragma unroll
  for (int s = 0; s < 2; ++s)
    #pragma unroll
    for (int dt = 0; dt < 4; ++dt) { f32x4 z = {0.f,0.f,0.f,0.f}; O[s][dt] = z; }

  STAGE(0, 0);
  __syncthreads();

  int cur = 0;
  for (int kt = 0; kt < 15; ++kt) {
    if (kt + 1 < 15) STAGE(cur ^ 1, kt + 1);

    if (kt < 14) {
      // ---- S^T = K Q^T : sacc[s][ct] rows k=ct*16+4g+r, col q=c16 ----
      f32x4 sacc[2][4];
      #pragma unroll
      for (int ct = 0; ct < 4; ++ct) {
        bf16x8 aK0 = *(bf16x8*)&Ks[cur][swz(ct * 16 + c16, g * 8)];
        bf16x8 aK1 = *(bf16x8*)&Ks[cur][swz(ct * 16 + c16, 32 + g * 8)];
        #pragma unroll
        for (int s = 0; s < 2; ++s) {
          f32x4 z = {0.f, 0.f, 0.f, 0.f};
          z = __builtin_amdgcn_mfma_f32_16x16x32_bf16(aK0, aQ[s][0], z, 0, 0, 0);
          z = __builtin_amdgcn_mfma_f32_16x16x32_bf16(aK1, aQ[s][1], z, 0, 0, 0);
          sacc[s][ct] = z;
        }
      }
      #pragma unroll
      for (int s = 0; s < 2; ++s) {
        // ---- p = exp(s), column-sum (fixed m=0; scores are tiny) ----
        float rs = 0.f;
        unsigned pk[4][2];
        #pragma unroll
        for (int ct = 0; ct < 4; ++ct) {
          float p0 = __expf(sacc[s][ct][0]);
          float p1 = __expf(sacc[s][ct][1]);
          float p2 = __expf(sacc[s][ct][2]);
          float p3 = __expf(sacc[s][ct][3]);
          rs += (p0 + p1) + (p2 + p3);
          pk[ct][0] = cvt_pk_bf16(p0, p1);
          pk[ct][1] = cvt_pk_bf16(p2, p3);
        }
        rs += __shfl_xor(rs, 16);
        rs += __shfl_xor(rs, 32);
        l_[s] += rs;
        // ---- write P[q][k] (row q=c16, contiguous k) as b64 ----
        #pragma unroll
        for (int ct = 0; ct < 4; ++ct)
          *(uint2*)&Ps[swz(w * 16 + c16, ct * 16 + 4 * g)] =
              make_uint2(pk[ct][0], pk[ct][1]);
        // ---- O[s] += P V ----
        #pragma unroll
        for (int c = 0; c < 2; ++c) {
          bf16x8 aP = *(bf16x8*)&Ps[swz(w * 16 + c16, c * 32 + g * 8)];
          #pragma unroll
          for (int dt = 0; dt < 4; ++dt) {
            bf16x8 bV = *(bf16x8*)&Vs[cur][swz(dt * 16 + c16, c * 32 + g * 8)];
            O[s][dt] = __builtin_amdgcn_mfma_f32_16x16x32_bf16(aP, bV, O[s][dt], 0, 0, 0);
          }
        }
      }
    } else {
      // ---- tile 14: only k=896..899 valid (ct=0, g==0) ----
      bf16x8 aK0 = *(bf16x8*)&Ks[cur][swz(c16, g * 8)];
      bf16x8 aK1 = *(bf16x8*)&Ks[cur][swz(c16, 32 + g * 8)];
      #pragma unroll
      for (int s = 0; s < 2; ++s) {
        f32x4 z = {0.f, 0.f, 0.f, 0.f};
        z = __builtin_amdgcn_mfma_f32_16x16x32_bf16(aK0, aQ[s][0], z, 0, 0, 0);
        z = __builtin_amdgcn_mfma_f32_16x16x32_bf16(aK1, aQ[s][1], z, 0, 0, 0);
        float p0 = 0.f, p1 = 0.f, p2 = 0.f, p3 = 0.f;
        if (g == 0) {
          p0 = __expf(z[0]); p1 = __expf(z[1]);
          p2 = __expf(z[2]); p3 = __expf(z[3]);
        }
        float rs = (p0 + p1) + (p2 + p3);
        rs += __shfl_xor(rs, 16);
        rs += __shfl_xor(rs, 32);
        l_[s] += rs;
        *(uint2*)&Ps[swz(w * 16 + c16, 4 * g)] =
            make_uint2(cvt_pk_bf16(p0, p1), cvt_pk_bf16(p2, p3));
        *(uint2*)&Ps[swz(w * 16 + c16, 16 + 4 * g)] = make_uint2(0u, 0u);
        bf16x8 aP = *(bf16x8*)&Ps[swz(w * 16 + c16, g * 8)];
        #pragma unroll
        for (int dt = 0; dt < 4; ++dt) {
          bf16x8 bV = *(bf16x8*)&Vs[cur][swz(dt * 16 + c16, g * 8)];
          O[s][dt] = __builtin_amdgcn_mfma_f32_16x16x32_bf16(aP, bV, O[s][dt], 0, 0, 0);
        }
      }
    }

    __syncthreads();   // drains staged loads + orders LDS reuse
    cur ^= 1;
  }
#undef STAGE

  // ---- epilogue: fetch per-row sums via shfl, normalize, store bf16 ----
  #pragma unroll
  for (int s = 0; s < 2; ++s) {
    #pragma unroll
    for (int r = 0; r < 4; ++r) {
      float lq = __shfl(l_[s], (g << 4) | (4 * g + r));
      int t = t0 + s * 64 + w * 16 + 4 * g + r;
      if (t < 900) {
        float inv = 1.f / lq;
        #pragma unroll
        for (int dt = 0; dt < 4; ++dt)
          attnOut[((size_t)(b * 900 + t)) * 256 + hc + dt * 16 + c16] =
              f2bf(O[s][dt][r] * inv);
      }
    }
  }
}

// ---------------------------------------------------------------------------
// Delta GEMM: C[28800x512] = attnOut(bf16) @ [woK|woV]; epilogue adds gather
// and stores k2/v2 bf16 [b][h][900][64]. Tile 128x128, BK=64, gload_lds.
// ---------------------------------------------------------------------------
__global__ __launch_bounds__(256) void k_delta(const int* __restrict__ grid_in,
                                               const float* __restrict__ ws,
                                               const short* __restrict__ attnOut,
                                               const short* __restrict__ wokvT,
                                               short* __restrict__ k2,
                                               short* __restrict__ v2) {
  const int m0 = blockIdx.x * 128, n0 = blockIdx.y * 128;
  const int tid = threadIdx.x, w = tid >> 6, lane = tid & 63;
  const int g = lane >> 4, c16 = lane & 15;
  __shared__ __align__(16) short As[8192];
  __shared__ __align__(16) short Bs[8192];
  f32x4 acc[2][8];
  #pragma unroll
  for (int rt = 0; rt < 2; ++rt)
    #pragma unroll
    for (int ct = 0; ct < 8; ++ct) { f32x4 z = {0.f,0.f,0.f,0.f}; acc[rt][ct] = z; }

  for (int kk = 0; kk < 4; ++kk) {
    if (kk) __syncthreads();
    #pragma unroll
    for (int j = 0; j < 4; ++j) {
      int c = j * 256 + w * 64 + lane;
      int row = c >> 3, ch = c & 7;
      int sw = ((ch ^ row) & 7) << 3;
      gload16(attnOut + ((size_t)(m0 + row)) * 256 + kk * 64 + sw,
              &As[(j * 256 + w * 64) << 3]);
      gload16(wokvT + ((size_t)(n0 + row)) * 256 + kk * 64 + sw,
              &Bs[(j * 256 + w * 64) << 3]);
    }
    __syncthreads();
    #pragma unroll
    for (int ks = 0; ks < 2; ++ks) {
      bf16x8 aA0 = *(bf16x8*)&As[swz(w * 32 + c16, ks * 32 + g * 8)];
      bf16x8 aA1 = *(bf16x8*)&As[swz(w * 32 + 16 + c16, ks * 32 + g * 8)];
      #pragma unroll
      for (int ct = 0; ct < 8; ++ct) {
        bf16x8 bB = *(bf16x8*)&Bs[swz(ct * 16 + c16, ks * 32 + g * 8)];
        acc[0][ct] = __builtin_amdgcn_mfma_f32_16x16x32_bf16(aA0, bB, acc[0][ct], 0, 0, 0);
        acc[1][ct] = __builtin_amdgcn_mfma_f32_16x16x32_bf16(aA1, bB, acc[1][ct], 0, 0, 0);
      }
    }
  }

  const float* embK = ws + OFF_EMBK;
  const float* posK = ws + OFF_POSK;
  const float* embV = ws + OFF_EMBV;
  const float* posV = ws + OFF_POSV;
  #pragma unroll
  for (int rt = 0; rt < 2; ++rt) {
    #pragma unroll
    for (int r = 0; r < 4; ++r) {
      int m = m0 + w * 32 + rt * 16 + 4 * g + r;
      int bb = m / 900, tok = m - bb * 900;
      int gc = grid_in[m];
      #pragma unroll
      for (int ct = 0; ct < 8; ++ct) {
        int n = n0 + ct * 16 + c16;
        float a = acc[rt][ct][r];
        if (n < 256) {
          float val = a + embK[(size_t)gc * 256 + n] + posK[(size_t)tok * 256 + n];
          k2[(((size_t)bb * 4 + (n >> 6)) * 900 + tok) * 64 + (n & 63)] = f2bf(val);
        } else {
          int d = n - 256;
          float val = a + embV[(size_t)gc * 256 + d] + posV[(size_t)tok * 256 + d];
          v2[(((size_t)bb * 4 + (d >> 6)) * 900 + tok) * 64 + (d & 63)] = f2bf(val);
        }
      }
    }
  }
}

// ---------------------------------------------------------------------------
// Fused cross-attention per (head, batch): scores -> softmax -> PV.
// ---------------------------------------------------------------------------
__global__ __launch_bounds__(256) void k_cross(const float* __restrict__ ws,
                                               const short* __restrict__ k2,
                                               const short* __restrict__ v2,
                                               float* __restrict__ crossOut) {
  const int h = blockIdx.x, b = blockIdx.y;
  const int hc = h * 64, tid = threadIdx.x;
  __shared__ float Pl[8][900];
  __shared__ float q2s[8][64];
  const float* q2 = ws + OFF_Q2;
  for (int idx = tid; idx < 512; idx += 256)
    q2s[idx >> 6][idx & 63] = q2[(size_t)(idx >> 6) * 256 + hc + (idx & 63)];
  __syncthreads();

  for (int tt = tid; tt < 900; tt += 256) {
    const short* kr = k2 + ((size_t)(b * 4 + h) * 900 + tt) * 64;
    float accs[8] = {0.f, 0.f, 0.f, 0.f, 0.f, 0.f, 0.f, 0.f};
    #pragma unroll
    for (int ch = 0; ch < 8; ++ch) {
      bf16x8 kv = *(const bf16x8*)&kr[ch * 8];
      float kf[8];
      #pragma unroll
      for (int i = 0; i < 8; ++i) kf[i] = bf2f(kv[i]);
      #pragma unroll
      for (int l = 0; l < 8; ++l) {
        const float* qq = &q2s[l][ch * 8];
        accs[l] += kf[0]*qq[0] + kf[1]*qq[1] + kf[2]*qq[2] + kf[3]*qq[3] +
                   kf[4]*qq[4] + kf[5]*qq[5] + kf[6]*qq[6] + kf[7]*qq[7];
      }
    }
    #pragma unroll
    for (int l = 0; l < 8; ++l) Pl[l][tt] = accs[l] * 0.125f;
  }
  __syncthreads();

  const int w = tid >> 6, lane = tid & 63;
  for (int rr = w; rr < 8; rr += 4) {
    float v[15]; float mx = -1e30f;
    #pragma unroll
    for (int k = 0; k < 15; ++k) {
      int t = lane + 64 * k;
      v[k] = (t < 900) ? Pl[rr][t] : -1e30f;
      mx = fmaxf(mx, v[k]);
    }
    for (int mk = 1; mk < 64; mk <<= 1) mx = fmaxf(mx, __shfl_xor(mx, mk));
    float sm = 0.f;
    #pragma unroll
    for (int k = 0; k < 15; ++k) { v[k] = __expf(v[k] - mx); sm += v[k]; }
    for (int mk = 1; mk < 64; mk <<= 1) sm += __shfl_xor(sm, mk);
    float inv = 1.f / sm;
    #pragma unroll
    for (int k = 0; k < 15; ++k) {
      int t = lane + 64 * k;
      if (t < 900) Pl[rr][t] = v[k] * inv;
    }
  }
  __syncthreads();

  const int l = tid >> 5, dp = (tid & 31) * 2;
  const short* vb = v2 + ((size_t)(b * 4 + h) * 900) * 64 + dp;
  float a0 = 0.f, a1 = 0.f;
  #pragma unroll 4
  for (int t = 0; t < 900; ++t) {
    float p = Pl[l][t];
    short2 vv = *(const short2*)(vb + (size_t)t * 64);
    a0 += p * bf2f(vv.x);
    a1 += p * bf2f(vv.y);
  }
  float* o = crossOut + ((size_t)b * 8 + l) * 256 + hc + dp;
  o[0] = a0; o[1] = a1;
}

// logits[b,l,p] = crossOut[b,l,:] @ woOut[:,p] + b_out[p]
__global__ void k_logits(const float* __restrict__ ws,
                         const float* __restrict__ b_out,
                         float* __restrict__ out) {
  const float* crossOut = ws + OFF_CROSS;
  const float* woOut = ws + OFF_WOOUT;
  int idx = blockIdx.x * 256 + threadIdx.x;
  if (idx >= 32 * 8 * 12) return;
  int p = idx % 12;
  int bl = idx / 12;
  float acc = b_out[p];
  for (int d = 0; d < 256; ++d)
    acc = fmaf(crossOut[(size_t)bl * 256 + d], woOut[d * 12 + p], acc);
  out[idx] = acc;
}

// ---------------------------------------------------------------------------
// Program executor (verified): flood fill, rotate 90 CW about anchor, paint.
// ---------------------------------------------------------------------------
__global__ void k_execute(const int* __restrict__ grid_in,
                          const int* __restrict__ anchor,
                          float* __restrict__ outg) {
  const int b = blockIdx.x;
  const int lane = threadIdx.x;
  const int* g = grid_in + b * 900;
  int ar = anchor[2 * b], ac = anchor[2 * b + 1];
  ar = min(max(ar, 0), 29); ac = min(max(ac, 0), 29);
  const int seed = g[ar * 30 + ac];

  unsigned same = 0u;
  if (lane < 30)
    for (int c = 0; c < 30; ++c) same |= (unsigned)(g[lane * 30 + c] == seed) << c;

  unsigned cur = (lane == ar) ? (1u << ac) : 0u;
  bool changed = true;
  while (changed) {
    unsigned up = __shfl(cur, (lane + 63) & 63);
    unsigned dn = __shfl(cur, (lane + 1) & 63);
    if (lane == 0) up = 0u;
    unsigned nm = (cur | (cur << 1) | (cur >> 1) | up | dn) & same;
    changed = __any(nm != cur);
    cur = nm;
  }

  __shared__ unsigned msh[32];
  if (lane < 32) msh[lane] = (lane < 30) ? cur : 0u;
  __syncthreads();

  if (lane < 30) {
    unsigned rot = 0u;
    int cc = lane - ar + ac;
    if (cc >= 0 && cc < 30) {
      for (int nc = 0; nc < 30; ++nc) {
        int rr = ar + ac - nc;
        if (rr >= 0 && rr < 30) rot |= ((msh[rr] >> cc) & 1u) << nc;
      }
    }
    for (int c = 0; c < 30; ++c) {
      int v = ((rot >> c) & 1u) ? 3 : g[lane * 30 + c];
      outg[b * 900 + lane * 30 + c] = (float)v;
    }
  }
}

// ---------------------------------------------------------------------------
extern "C" void kernel_launch(void* const* d_in, const int* in_sizes, int n_in,
                              void* d_out, int out_size, void* d_ws, size_t ws_size,
                              hipStream_t stream) {
  const int*   grid_in = (const int*)d_in[0];
  const int*   anchor  = (const int*)d_in[1];
  const float* embed   = (const float*)d_in[2];
  const float* pos_emb = (const float*)d_in[3];
  const float* wq      = (const float*)d_in[4];
  const float* wk      = (const float*)d_in[5];
  const float* wv      = (const float*)d_in[6];
  const float* wo      = (const float*)d_in[7];
  const float* step_q  = (const float*)d_in[8];
  const float* w_out   = (const float*)d_in[9];
  const float* b_out   = (const float*)d_in[10];
  float* out = (float*)d_out;
  float* ws  = (float*)d_ws;
  short* wsS = (short*)(ws + OFF_F32_END);

  k_small<<<dim3(562), dim3(256), 0, stream>>>(embed, wq, wk, wv, wo, step_q, w_out, ws);
  k_pos_gemm<<<dim3(15, 12), dim3(256), 0, stream>>>(pos_emb, wq, wk, wv, ws);
  k_kv<<<dim3(15, 32), dim3(256), 0, stream>>>(grid_in, ws,
                                               wsS + SOFF_KB, wsS + SOFF_VT);
  k_attn<<<dim3(1024), dim3(256), 0, stream>>>(grid_in, ws, wsS + SOFF_KB,
                                               wsS + SOFF_VT, wsS + SOFF_ATTN);
  k_delta<<<dim3(225, 4), dim3(256), 0, stream>>>(grid_in, ws, wsS + SOFF_ATTN,
                                                  wsS + SOFF_WOKVT,
                                                  wsS + SOFF_KB, wsS + SOFF_VT);
  k_cross<<<dim3(4, 32), dim3(256), 0, stream>>>(ws, wsS + SOFF_KB, wsS + SOFF_VT,
                                                 ws + OFF_CROSS);
  k_logits<<<dim3(12), dim3(256), 0, stream>>>(ws, b_out, out);
  k_execute<<<dim3(32), dim3(64), 0, stream>>>(grid_in, anchor, out + 32 * 8 * 12);
}

// Round 6
// 286.409 us; speedup vs baseline: 3.8702x; 1.1759x over previous
//
#include <hip/hip_runtime.h>

// ===========================================================================
// ARPS forward. tok = embed[grid]+pos => projections distribute over gather.
//   k_small:    tiny f32 GEMMs (embQ/K/V, wo@w_out, q2) + crossOut zeroing
//   k_gemm_all: tiled f32 GEMM posQ/K/V = pos_emb @ [wq|wk|wv]; also
//               woK/woV = wo @ [wk|wv] stored bf16 transposed
//   k_kv:       materialize K bf16 rows + V^T bf16 tiles (one gather pass)
//   k_attn:     flash self-attn, swapped-QK^T S^T layout, m=0 softmax,
//               bf16 MFMA, dbuf global_load_lds staging, XCD-aware grid
//   k_delta:    [28800x512] attnOut @ [woK|woV] MFMA GEMM -> k2/v2
//   k_crossA:   E = exp(scores/8) per 64-tile + partial sums Sp (1920 blks)
//   k_crossB:   crossOut += (E/S) @ v2, t-split atomics (640 blks)
//   k_logits, k_execute (flood fill / rotate / paint)
// Aliasing map (stream-ordered, verified sizes):
//   E  (921,600 f32 = 1,843,200 shorts) -> SOFF_ATTN region (7,372,800 shorts,
//       dead after k_delta)
//   Sp (15,360 f32 = 30,720 shorts)     -> SOFF_WOKVT region (131,072 shorts,
//       dead after k_delta)
//   k2/v2 -> SOFF_KB / SOFF_VT (Kb/VT dead after k_attn)
// ===========================================================================

typedef __attribute__((ext_vector_type(8))) short bf16x8;   // 8 bf16 (4 VGPR)
typedef __attribute__((ext_vector_type(4))) float f32x4;    // MFMA acc

__device__ __forceinline__ short f2bf(float f) {
  union { float f; unsigned u; } v; v.f = f;
  unsigned r = v.u + 0x7fffu + ((v.u >> 16) & 1u);   // RNE
  return (short)(r >> 16);
}
__device__ __forceinline__ float bf2f(short s) {
  union { unsigned u; float f; } v; v.u = ((unsigned)(unsigned short)s) << 16;
  return v.f;
}
// pack 2 f32 -> 2 bf16 (RNE), gfx950 single instruction
__device__ __forceinline__ unsigned cvt_pk_bf16(float lo, float hi) {
  unsigned r;
  asm("v_cvt_pk_bf16_f32 %0, %1, %2" : "=v"(r) : "v"(lo), "v"(hi));
  return r;
}
// XOR-swizzled index into a [rows][64] bf16 LDS tile (row stride 128B).
__device__ __forceinline__ int swz(int row, int col) {
  return row * 64 + ((((col >> 3) ^ row) & 7) << 3) + (col & 7);
}
// async global->LDS 16B copy; LDS dest is wave-uniform base + lane*16.
__device__ __forceinline__ void gload16(const short* gsrc, short* lds) {
  __builtin_amdgcn_global_load_lds(
      (const __attribute__((address_space(1))) unsigned int*)gsrc,
      (__attribute__((address_space(3))) unsigned int*)lds, 16, 0, 0);
}

// ---------------- workspace layout ----------------
// float region
constexpr size_t OFF_POSQ  = 0;                 // 900x256
constexpr size_t OFF_POSK  = 230400;
constexpr size_t OFF_POSV  = 460800;
constexpr size_t OFF_EMBQ  = 691200;            // 10x256 each
constexpr size_t OFF_EMBK  = 693760;
constexpr size_t OFF_EMBV  = 696320;
constexpr size_t OFF_WOOUT = 698880;            // 256x12
constexpr size_t OFF_Q2    = 701952;            // 8x256
constexpr size_t OFF_CROSS = 704000;            // 32x8x256
constexpr size_t OFF_F32_END = 769536;
// short (bf16) region, offsets in shorts from (short*)(ws+OFF_F32_END)
constexpr size_t SOFF_WOKVT = 0;                // [512][256]; Sp aliases after delta
constexpr size_t SOFF_ATTN  = 131072;           // [28800][256]; E aliases after delta
constexpr size_t SOFF_KB    = 7503872;          // [28800][256] K bf16; k2 aliases
constexpr size_t SOFF_VT    = 14876672;         // [128 bh][15 kt][64d][64t]; v2 aliases

// ---------------------------------------------------------------------------
// Small precompute GEMMs + crossOut zeroing. 114 blocks.
// ---------------------------------------------------------------------------
__global__ void k_small(const float* __restrict__ embed,
                        const float* __restrict__ wq,
                        const float* __restrict__ wk,
                        const float* __restrict__ wv,
                        const float* __restrict__ wo,
                        const float* __restrict__ step_q,
                        const float* __restrict__ w_out,
                        float* __restrict__ ws) {
  const int blk = blockIdx.x;
  if (blk >= 50) {   // zero crossOut (64 blocks x 1024 floats = 65536 floats)
    int i = (blk - 50) * 1024 + threadIdx.x * 4;
    *(float4*)&ws[OFF_CROSS + i] = make_float4(0.f, 0.f, 0.f, 0.f);
    return;
  }
  int job, base;
  if      (blk < 10)  { job = 0; base = blk; }
  else if (blk < 20)  { job = 1; base = blk - 10; }
  else if (blk < 30)  { job = 2; base = blk - 20; }
  else if (blk < 42)  { job = 3; base = blk - 30; }
  else                { job = 4; base = blk - 42; }
  const float* A; const float* Wm; float* C; int M; int N;
  switch (job) {
    case 0: A=embed;  Wm=wq;    C=ws+OFF_EMBQ;  M=10;  N=256; break;
    case 1: A=embed;  Wm=wk;    C=ws+OFF_EMBK;  M=10;  N=256; break;
    case 2: A=embed;  Wm=wv;    C=ws+OFF_EMBV;  M=10;  N=256; break;
    case 3: A=wo;     Wm=w_out; C=ws+OFF_WOOUT; M=256; N=12;  break;
    default:A=step_q; Wm=wq;    C=ws+OFF_Q2;    M=8;   N=256; break;
  }
  int idx = base * 256 + threadIdx.x;
  if (idx >= M * N) return;
  int m = idx / N, n = idx - m * N;
  const float* a = A + (size_t)m * 256;
  float acc = 0.f;
  #pragma unroll 8
  for (int k = 0; k < 256; ++k) acc = fmaf(a[k], Wm[(size_t)k * N + n], acc);
  C[idx] = acc;
}

// ---------------------------------------------------------------------------
// Tiled f32 GEMM, 64x64 tiles, 4x4 micro-tiles. Grid (15, 20).
//   nt 0..11:  posQ/K/V = pos_emb @ [wq|wk|wv]  (mt 0..14)
//   nt 12..15: woK = wo @ wk -> bf16 transposed (mt 0..3)
//   nt 16..19: woV = wo @ wv -> bf16 transposed (mt 0..3)
// ---------------------------------------------------------------------------
__global__ __launch_bounds__(256) void k_gemm_all(const float* __restrict__ pos_emb,
                                                  const float* __restrict__ wq,
                                                  const float* __restrict__ wk,
                                                  const float* __restrict__ wv,
                                                  const float* __restrict__ wo,
                                                  float* __restrict__ ws) {
  const int mt = blockIdx.x, nt = blockIdx.y;
  const bool wojob = nt >= 12;
  if (wojob && mt >= 4) return;
  const float* A = wojob ? wo : pos_emb;
  const float* W;
  float* C = nullptr;
  int n0;
  int base_n = 0;
  if (!wojob) {
    W = nt < 4 ? wq : (nt < 8 ? wk : wv);
    C = ws + (nt < 4 ? OFF_POSQ : (nt < 8 ? OFF_POSK : OFF_POSV));
    n0 = (nt & 3) * 64;
  } else {
    W = nt < 16 ? wk : wv;
    base_n = nt < 16 ? 0 : 256;
    n0 = (nt & 3) * 64;
  }
  const int m0 = mt * 64;
  const int tid = threadIdx.x, tr = tid >> 4, tc = tid & 15;
  __shared__ float As[64][68];
  __shared__ float Bs[64][68];
  float acc[4][4] = {};
  for (int kc = 0; kc < 4; ++kc) {
    __syncthreads();
    for (int i = tid; i < 1024; i += 256) {
      int row = i >> 4, c4 = (i & 15) * 4;
      int m = m0 + row; if (m > 899) m = 899;
      *(float4*)&As[row][c4] = *(const float4*)&A[(size_t)m * 256 + kc * 64 + c4];
      *(float4*)&Bs[row][c4] = *(const float4*)&W[(size_t)(kc * 64 + row) * 256 + n0 + c4];
    }
    __syncthreads();
    #pragma unroll 8
    for (int kk = 0; kk < 64; ++kk) {
      float a0 = As[4*tr+0][kk], a1 = As[4*tr+1][kk];
      float a2 = As[4*tr+2][kk], a3 = As[4*tr+3][kk];
      float4 b4 = *(const float4*)&Bs[kk][4*tc];
      acc[0][0]+=a0*b4.x; acc[0][1]+=a0*b4.y; acc[0][2]+=a0*b4.z; acc[0][3]+=a0*b4.w;
      acc[1][0]+=a1*b4.x; acc[1][1]+=a1*b4.y; acc[1][2]+=a1*b4.z; acc[1][3]+=a1*b4.w;
      acc[2][0]+=a2*b4.x; acc[2][1]+=a2*b4.y; acc[2][2]+=a2*b4.z; acc[2][3]+=a2*b4.w;
      acc[3][0]+=a3*b4.x; acc[3][1]+=a3*b4.y; acc[3][2]+=a3*b4.z; acc[3][3]+=a3*b4.w;
    }
  }
  if (!wojob) {
    #pragma unroll
    for (int i = 0; i < 4; ++i) {
      int m = m0 + 4 * tr + i;
      if (m < 900)
        *(float4*)&C[(size_t)m * 256 + n0 + 4 * tc] =
            make_float4(acc[i][0], acc[i][1], acc[i][2], acc[i][3]);
    }
  } else {
    // transpose in LDS, store bf16 [n][m] into wokvT
    __syncthreads();
    #pragma unroll
    for (int i = 0; i < 4; ++i)
      #pragma unroll
      for (int j = 0; j < 4; ++j)
        Bs[4 * tc + j][4 * tr + i] = acc[i][j];
    __syncthreads();
    short* wokvT = (short*)(ws + OFF_F32_END) + SOFF_WOKVT;
    for (int i = tid; i < 512; i += 256) {
      int row = i >> 3, ch = i & 7;
      union { short s[8]; bf16x8 v; } u;
      #pragma unroll
      for (int jj = 0; jj < 8; ++jj) u.s[jj] = f2bf(Bs[row][ch * 8 + jj]);
      *(bf16x8*)&wokvT[(size_t)(base_n + n0 + row) * 256 + m0 + ch * 8] = u.v;
    }
  }
}

// ---------------------------------------------------------------------------
// Materialize K (row-major bf16) and V^T (tiled bf16) once.
// ---------------------------------------------------------------------------
__global__ __launch_bounds__(256) void k_kv(const int* __restrict__ grid_in,
                                            const float* __restrict__ ws,
                                            short* __restrict__ Kb,
                                            short* __restrict__ VT) {
  const int kt = blockIdx.x, b = blockIdx.y;
  const int t0 = kt * 64, tid = threadIdx.x;
  const float* posK = ws + OFF_POSK;
  const float* embK = ws + OFF_EMBK;
  const float* posV = ws + OFF_POSV;
  const float* embV = ws + OFF_EMBV;

  for (int i = tid; i < 2048; i += 256) {
    int row = i >> 5, ch = i & 31;
    int t = t0 + row;
    if (t > 899) continue;
    int g = grid_in[b * 900 + t];
    const float* pk = posK + (size_t)t * 256 + ch * 8;
    const float* ek = embK + (size_t)g * 256 + ch * 8;
    float4 p0 = *(const float4*)pk, p1 = *(const float4*)(pk + 4);
    float4 e0 = *(const float4*)ek, e1 = *(const float4*)(ek + 4);
    union { short s[8]; bf16x8 v; } u;
    u.s[0] = f2bf(p0.x + e0.x); u.s[1] = f2bf(p0.y + e0.y);
    u.s[2] = f2bf(p0.z + e0.z); u.s[3] = f2bf(p0.w + e0.w);
    u.s[4] = f2bf(p1.x + e1.x); u.s[5] = f2bf(p1.y + e1.y);
    u.s[6] = f2bf(p1.z + e1.z); u.s[7] = f2bf(p1.w + e1.w);
    *(bf16x8*)&Kb[((size_t)(b * 900 + t)) * 256 + ch * 8] = u.v;
  }

  __shared__ float Lf[64 * 65];
  const int tt = tid & 63, dq = tid >> 6;
  for (int h = 0; h < 4; ++h) {
    __syncthreads();
    for (int i = tid; i < 512; i += 256) {
      int row = i >> 3, ch = i & 7;
      int t = t0 + row; if (t > 899) t = 899;
      int g = grid_in[b * 900 + t];
      const float* pv = posV + (size_t)t * 256 + h * 64 + ch * 8;
      const float* ev = embV + (size_t)g * 256 + h * 64 + ch * 8;
      float4 p0 = *(const float4*)pv, p1 = *(const float4*)(pv + 4);
      float4 e0 = *(const float4*)ev, e1 = *(const float4*)(ev + 4);
      float* L = &Lf[row * 65 + ch * 8];
      L[0] = p0.x + e0.x; L[1] = p0.y + e0.y; L[2] = p0.z + e0.z; L[3] = p0.w + e0.w;
      L[4] = p1.x + e1.x; L[5] = p1.y + e1.y; L[6] = p1.z + e1.z; L[7] = p1.w + e1.w;
    }
    __syncthreads();
    short* tile = VT + ((size_t)((b * 4 + h) * 15 + kt)) * 4096;
    #pragma unroll
    for (int dd = 0; dd < 16; ++dd) {
      int d = dq * 16 + dd;
      tile[d * 64 + tt] = f2bf(Lf[tt * 65 + d]);
    }
  }
}

// ---------------------------------------------------------------------------
// Self-attention, swapped-QK^T (S^T: lane owns one q-column), m=0 softmax.
// ---------------------------------------------------------------------------
__global__ __launch_bounds__(256) void k_attn(const int* __restrict__ grid_in,
                                              const float* __restrict__ ws,
                                              const short* __restrict__ Kb,
                                              const short* __restrict__ VT,
                                              short* __restrict__ attnOut) {
  const int bidx = blockIdx.x;                      // XCD-aware encoding
  const int bh = ((bidx >> 6) << 3) | (bidx & 7);
  const int qt = (bidx >> 3) & 7;
  const int h = bh & 3, b = bh >> 2;
  const int t0 = qt * 128, hc = h * 64;
  const int tid = threadIdx.x, w = tid >> 6, lane = tid & 63;
  const int g = lane >> 4, c16 = lane & 15;
  const size_t tileBase = (size_t)(bh * 15) * 4096;

  __shared__ __align__(16) short Ks[2][4096];
  __shared__ __align__(16) short Vs[2][4096];
  __shared__ __align__(16) short Ps[4096];

  const float* posQ = ws + OFF_POSQ;
  const float* embQ = ws + OFF_EMBQ;

  bf16x8 aQ[2][2];
  #pragma unroll
  for (int s = 0; s < 2; ++s) {
    int t = t0 + s * 64 + w * 16 + c16; if (t > 899) t = 899;
    int gq = grid_in[b * 900 + t];
    #pragma unroll
    for (int kc = 0; kc < 2; ++kc) {
      union { short s8[8]; bf16x8 v; } u;
      #pragma unroll
      for (int j = 0; j < 8; ++j) {
        int d = hc + kc * 32 + g * 8 + j;
        u.s8[j] = f2bf(0.125f * (embQ[gq * 256 + d] + posQ[(size_t)t * 256 + d]));
      }
      aQ[s][kc] = u.v;
    }
  }

#define STAGE(BUF, KT)                                                        \
  do {                                                                        \
    int kk0_ = (KT) * 64;                                                     \
    _Pragma("unroll")                                                         \
    for (int j_ = 0; j_ < 2; ++j_) {                                          \
      int c_ = j_ * 256 + w * 64 + lane;                                      \
      int row_ = c_ >> 3, ch_ = c_ & 7;                                       \
      int t_ = kk0_ + row_; if (t_ > 899) t_ = 899;                           \
      int sw_ = ((ch_ ^ row_) & 7) << 3;                                      \
      gload16(Kb + ((size_t)(b * 900 + t_)) * 256 + hc + sw_,                 \
              &Ks[BUF][(j_ * 256 + w * 64) << 3]);                            \
      gload16(VT + tileBase + (size_t)(KT) * 4096 + (row_ << 6) + sw_,        \
              &Vs[BUF][(j_ * 256 + w * 64) << 3]);                            \
    }                                                                         \
  } while (0)

  float l_[2] = {0.f, 0.f};
  f32x4 O[2][4];
  #pragma unroll
  for (int s = 0; s < 2; ++s)
    #pragma unroll
    for (int dt = 0; dt < 4; ++dt) { f32x4 z = {0.f,0.f,0.f,0.f}; O[s][dt] = z; }

  STAGE(0, 0);
  __syncthreads();

  int cur = 0;
  for (int kt = 0; kt < 15; ++kt) {
    if (kt + 1 < 15) STAGE(cur ^ 1, kt + 1);

    if (kt < 14) {
      f32x4 sacc[2][4];
      #pragma unroll
      for (int ct = 0; ct < 4; ++ct) {
        bf16x8 aK0 = *(bf16x8*)&Ks[cur][swz(ct * 16 + c16, g * 8)];
        bf16x8 aK1 = *(bf16x8*)&Ks[cur][swz(ct * 16 + c16, 32 + g * 8)];
        #pragma unroll
        for (int s = 0; s < 2; ++s) {
          f32x4 z = {0.f, 0.f, 0.f, 0.f};
          z = __builtin_amdgcn_mfma_f32_16x16x32_bf16(aK0, aQ[s][0], z, 0, 0, 0);
          z = __builtin_amdgcn_mfma_f32_16x16x32_bf16(aK1, aQ[s][1], z, 0, 0, 0);
          sacc[s][ct] = z;
        }
      }
      #pragma unroll
      for (int s = 0; s < 2; ++s) {
        float rs = 0.f;
        unsigned pk[4][2];
        #pragma unroll
        for (int ct = 0; ct < 4; ++ct) {
          float p0 = __expf(sacc[s][ct][0]);
          float p1 = __expf(sacc[s][ct][1]);
          float p2 = __expf(sacc[s][ct][2]);
          float p3 = __expf(sacc[s][ct][3]);
          rs += (p0 + p1) + (p2 + p3);
          pk[ct][0] = cvt_pk_bf16(p0, p1);
          pk[ct][1] = cvt_pk_bf16(p2, p3);
        }
        rs += __shfl_xor(rs, 16);
        rs += __shfl_xor(rs, 32);
        l_[s] += rs;
        #pragma unroll
        for (int ct = 0; ct < 4; ++ct)
          *(uint2*)&Ps[swz(w * 16 + c16, ct * 16 + 4 * g)] =
              make_uint2(pk[ct][0], pk[ct][1]);
        #pragma unroll
        for (int c = 0; c < 2; ++c) {
          bf16x8 aP = *(bf16x8*)&Ps[swz(w * 16 + c16, c * 32 + g * 8)];
          #pragma unroll
          for (int dt = 0; dt < 4; ++dt) {
            bf16x8 bV = *(bf16x8*)&Vs[cur][swz(dt * 16 + c16, c * 32 + g * 8)];
            O[s][dt] = __builtin_amdgcn_mfma_f32_16x16x32_bf16(aP, bV, O[s][dt], 0, 0, 0);
          }
        }
      }
    } else {
      bf16x8 aK0 = *(bf16x8*)&Ks[cur][swz(c16, g * 8)];
      bf16x8 aK1 = *(bf16x8*)&Ks[cur][swz(c16, 32 + g * 8)];
      #pragma unroll
      for (int s = 0; s < 2; ++s) {
        f32x4 z = {0.f, 0.f, 0.f, 0.f};
        z = __builtin_amdgcn_mfma_f32_16x16x32_bf16(aK0, aQ[s][0], z, 0, 0, 0);
        z = __builtin_amdgcn_mfma_f32_16x16x32_bf16(aK1, aQ[s][1], z, 0, 0, 0);
        float p0 = 0.f, p1 = 0.f, p2 = 0.f, p3 = 0.f;
        if (g == 0) {
          p0 = __expf(z[0]); p1 = __expf(z[1]);
          p2 = __expf(z[2]); p3 = __expf(z[3]);
        }
        float rs = (p0 + p1) + (p2 + p3);
        rs += __shfl_xor(rs, 16);
        rs += __shfl_xor(rs, 32);
        l_[s] += rs;
        *(uint2*)&Ps[swz(w * 16 + c16, 4 * g)] =
            make_uint2(cvt_pk_bf16(p0, p1), cvt_pk_bf16(p2, p3));
        *(uint2*)&Ps[swz(w * 16 + c16, 16 + 4 * g)] = make_uint2(0u, 0u);
        bf16x8 aP = *(bf16x8*)&Ps[swz(w * 16 + c16, g * 8)];
        #pragma unroll
        for (int dt = 0; dt < 4; ++dt) {
          bf16x8 bV = *(bf16x8*)&Vs[cur][swz(dt * 16 + c16, g * 8)];
          O[s][dt] = __builtin_amdgcn_mfma_f32_16x16x32_bf16(aP, bV, O[s][dt], 0, 0, 0);
        }
      }
    }

    __syncthreads();
    cur ^= 1;
  }
#undef STAGE

  #pragma unroll
  for (int s = 0; s < 2; ++s) {
    #pragma unroll
    for (int r = 0; r < 4; ++r) {
      float lq = __shfl(l_[s], (g << 4) | (4 * g + r));
      int t = t0 + s * 64 + w * 16 + 4 * g + r;
      if (t < 900) {
        float inv = 1.f / lq;
        #pragma unroll
        for (int dt = 0; dt < 4; ++dt)
          attnOut[((size_t)(b * 900 + t)) * 256 + hc + dt * 16 + c16] =
              f2bf(O[s][dt][r] * inv);
      }
    }
  }
}

// ---------------------------------------------------------------------------
// Delta GEMM: C[28800x512] = attnOut(bf16) @ [woK|woV] -> k2/v2.
// ---------------------------------------------------------------------------
__global__ __launch_bounds__(256) void k_delta(const int* __restrict__ grid_in,
                                               const float* __restrict__ ws,
                                               const short* __restrict__ attnOut,
                                               const short* __restrict__ wokvT,
                                               short* __restrict__ k2,
                                               short* __restrict__ v2) {
  const int m0 = blockIdx.x * 128, n0 = blockIdx.y * 128;
  const int tid = threadIdx.x, w = tid >> 6, lane = tid & 63;
  const int g = lane >> 4, c16 = lane & 15;
  __shared__ __align__(16) short As[8192];
  __shared__ __align__(16) short Bs[8192];
  f32x4 acc[2][8];
  #pragma unroll
  for (int rt = 0; rt < 2; ++rt)
    #pragma unroll
    for (int ct = 0; ct < 8; ++ct) { f32x4 z = {0.f,0.f,0.f,0.f}; acc[rt][ct] = z; }

  for (int kk = 0; kk < 4; ++kk) {
    if (kk) __syncthreads();
    #pragma unroll
    for (int j = 0; j < 4; ++j) {
      int c = j * 256 + w * 64 + lane;
      int row = c >> 3, ch = c & 7;
      int sw = ((ch ^ row) & 7) << 3;
      gload16(attnOut + ((size_t)(m0 + row)) * 256 + kk * 64 + sw,
              &As[(j * 256 + w * 64) << 3]);
      gload16(wokvT + ((size_t)(n0 + row)) * 256 + kk * 64 + sw,
              &Bs[(j * 256 + w * 64) << 3]);
    }
    __syncthreads();
    #pragma unroll
    for (int ks = 0; ks < 2; ++ks) {
      bf16x8 aA0 = *(bf16x8*)&As[swz(w * 32 + c16, ks * 32 + g * 8)];
      bf16x8 aA1 = *(bf16x8*)&As[swz(w * 32 + 16 + c16, ks * 32 + g * 8)];
      #pragma unroll
      for (int ct = 0; ct < 8; ++ct) {
        bf16x8 bB = *(bf16x8*)&Bs[swz(ct * 16 + c16, ks * 32 + g * 8)];
        acc[0][ct] = __builtin_amdgcn_mfma_f32_16x16x32_bf16(aA0, bB, acc[0][ct], 0, 0, 0);
        acc[1][ct] = __builtin_amdgcn_mfma_f32_16x16x32_bf16(aA1, bB, acc[1][ct], 0, 0, 0);
      }
    }
  }

  const float* embK = ws + OFF_EMBK;
  const float* posK = ws + OFF_POSK;
  const float* embV = ws + OFF_EMBV;
  const float* posV = ws + OFF_POSV;
  #pragma unroll
  for (int rt = 0; rt < 2; ++rt) {
    #pragma unroll
    for (int r = 0; r < 4; ++r) {
      int m = m0 + w * 32 + rt * 16 + 4 * g + r;
      int bb = m / 900, tok = m - bb * 900;
      int gc = grid_in[m];
      #pragma unroll
      for (int ct = 0; ct < 8; ++ct) {
        int n = n0 + ct * 16 + c16;
        float a = acc[rt][ct][r];
        if (n < 256) {
          float val = a + embK[(size_t)gc * 256 + n] + posK[(size_t)tok * 256 + n];
          k2[(((size_t)bb * 4 + (n >> 6)) * 900 + tok) * 64 + (n & 63)] = f2bf(val);
        } else {
          int d = n - 256;
          float val = a + embV[(size_t)gc * 256 + d] + posV[(size_t)tok * 256 + d];
          v2[(((size_t)bb * 4 + (d >> 6)) * 900 + tok) * 64 + (d & 63)] = f2bf(val);
        }
      }
    }
  }
}

// ---------------------------------------------------------------------------
// Cross phase A: E[bh][l][t] = exp(q2.k2/8) (m=0), partial sums Sp[bh][l][kt].
// Grid (15, 4, 32). E aliases SOFF_ATTN; Sp aliases SOFF_WOKVT (both dead).
// ---------------------------------------------------------------------------
__global__ __launch_bounds__(256) void k_crossA(const float* __restrict__ ws,
                                                const short* __restrict__ k2,
                                                float* __restrict__ E,
                                                float* __restrict__ Sp) {
  const int kt = blockIdx.x, h = blockIdx.y, b = blockIdx.z;
  const int t0 = kt * 64, bh = b * 4 + h;
  const int tid = threadIdx.x;
  __shared__ __align__(16) short Ks[4096];
  __shared__ float q2s[8][64];
  const float* q2 = ws + OFF_Q2;
  for (int idx = tid; idx < 512; idx += 256)
    q2s[idx >> 6][idx & 63] = q2[(size_t)(idx >> 6) * 256 + h * 64 + (idx & 63)];
  for (int idx = tid; idx < 512; idx += 256) {
    int row = idx >> 3, ch = idx & 7;
    int t = t0 + row;
    if (t < 900)
      *(bf16x8*)&Ks[swz(row, ch * 8)] =
          *(const bf16x8*)&k2[((size_t)bh * 900 + t) * 64 + ch * 8];
  }
  __syncthreads();

  const int tl = tid & 63, lp = tid >> 6;     // wave = lp
  const int t = t0 + tl;
  const bool valid = t < 900;
  float a0 = 0.f, a1 = 0.f;
  #pragma unroll
  for (int ch = 0; ch < 8; ++ch) {
    bf16x8 kv = *(bf16x8*)&Ks[swz(tl, ch * 8)];
    #pragma unroll
    for (int i = 0; i < 8; ++i) {
      float f = bf2f(kv[i]);
      a0 = fmaf(f, q2s[lp][ch * 8 + i], a0);
      a1 = fmaf(f, q2s[lp + 4][ch * 8 + i], a1);
    }
  }
  float e0 = valid ? __expf(a0 * 0.125f) : 0.f;
  float e1 = valid ? __expf(a1 * 0.125f) : 0.f;
  if (valid) {
    E[((size_t)bh * 8 + lp) * 900 + t] = e0;
    E[((size_t)bh * 8 + lp + 4) * 900 + t] = e1;
  }
  float r0 = e0, r1 = e1;
  #pragma unroll
  for (int mk = 1; mk < 64; mk <<= 1) {
    r0 += __shfl_xor(r0, mk);
    r1 += __shfl_xor(r1, mk);
  }
  if (tl == 0) {
    Sp[((size_t)bh * 8 + lp) * 15 + kt] = r0;
    Sp[((size_t)bh * 8 + lp + 4) * 15 + kt] = r1;
  }
}

// ---------------------------------------------------------------------------
// Cross phase B: crossOut[b][l][hc+d] += sum_t (E/S) * v2. Grid (5, 4, 32).
// ---------------------------------------------------------------------------
__global__ __launch_bounds__(256) void k_crossB(const float* __restrict__ E,
                                                const float* __restrict__ Sp,
                                                const short* __restrict__ v2,
                                                float* __restrict__ crossOut) {
  const int ts = blockIdx.x, h = blockIdx.y, b = blockIdx.z;
  const int bh = b * 4 + h;
  const int tid = threadIdx.x;
  const int d = tid & 63, lq = tid >> 6;
  __shared__ float El[8][180];
  __shared__ float SmI[8];
  if (tid < 8) {
    float s = 0.f;
    #pragma unroll
    for (int kt = 0; kt < 15; ++kt) s += Sp[((size_t)bh * 8 + tid) * 15 + kt];
    SmI[tid] = 1.f / s;
  }
  for (int idx = tid; idx < 1440; idx += 256) {
    int l = idx / 180, tt = idx - l * 180;
    El[l][tt] = E[((size_t)bh * 8 + l) * 900 + ts * 180 + tt];
  }
  __syncthreads();

  const short* vb = v2 + ((size_t)bh * 900 + ts * 180) * 64 + d;
  float a0 = 0.f, a1 = 0.f;
  #pragma unroll 4
  for (int tt = 0; tt < 180; ++tt) {
    float vf = bf2f(vb[(size_t)tt * 64]);
    a0 = fmaf(El[lq][tt], vf, a0);
    a1 = fmaf(El[lq + 4][tt], vf, a1);
  }
  atomicAdd(&crossOut[((size_t)b * 8 + lq) * 256 + h * 64 + d], a0 * SmI[lq]);
  atomicAdd(&crossOut[((size_t)b * 8 + lq + 4) * 256 + h * 64 + d], a1 * SmI[lq + 4]);
}

// logits[b,l,p] = crossOut[b,l,:] @ woOut[:,p] + b_out[p]
__global__ void k_logits(const float* __restrict__ ws,
                         const float* __restrict__ b_out,
                         float* __restrict__ out) {
  const float* crossOut = ws + OFF_CROSS;
  const float* woOut = ws + OFF_WOOUT;
  int idx = blockIdx.x * 256 + threadIdx.x;
  if (idx >= 32 * 8 * 12) return;
  int p = idx % 12;
  int bl = idx / 12;
  float acc = b_out[p];
  for (int d = 0; d < 256; ++d)
    acc = fmaf(crossOut[(size_t)bl * 256 + d], woOut[d * 12 + p], acc);
  out[idx] = acc;
}

// ---------------------------------------------------------------------------
// Program executor (verified): flood fill, rotate 90 CW about anchor, paint.
// ---------------------------------------------------------------------------
__global__ void k_execute(const int* __restrict__ grid_in,
                          const int* __restrict__ anchor,
                          float* __restrict__ outg) {
  const int b = blockIdx.x;
  const int lane = threadIdx.x;
  const int* g = grid_in + b * 900;
  int ar = anchor[2 * b], ac = anchor[2 * b + 1];
  ar = min(max(ar, 0), 29); ac = min(max(ac, 0), 29);
  const int seed = g[ar * 30 + ac];

  unsigned same = 0u;
  if (lane < 30)
    for (int c = 0; c < 30; ++c) same |= (unsigned)(g[lane * 30 + c] == seed) << c;

  unsigned cur = (lane == ar) ? (1u << ac) : 0u;
  bool changed = true;
  while (changed) {
    unsigned up = __shfl(cur, (lane + 63) & 63);
    unsigned dn = __shfl(cur, (lane + 1) & 63);
    if (lane == 0) up = 0u;
    unsigned nm = (cur | (cur << 1) | (cur >> 1) | up | dn) & same;
    changed = __any(nm != cur);
    cur = nm;
  }

  __shared__ unsigned msh[32];
  if (lane < 32) msh[lane] = (lane < 30) ? cur : 0u;
  __syncthreads();

  if (lane < 30) {
    unsigned rot = 0u;
    int cc = lane - ar + ac;
    if (cc >= 0 && cc < 30) {
      for (int nc = 0; nc < 30; ++nc) {
        int rr = ar + ac - nc;
        if (rr >= 0 && rr < 30) rot |= ((msh[rr] >> cc) & 1u) << nc;
      }
    }
    for (int c = 0; c < 30; ++c) {
      int v = ((rot >> c) & 1u) ? 3 : g[lane * 30 + c];
      outg[b * 900 + lane * 30 + c] = (float)v;
    }
  }
}

// ---------------------------------------------------------------------------
extern "C" void kernel_launch(void* const* d_in, const int* in_sizes, int n_in,
                              void* d_out, int out_size, void* d_ws, size_t ws_size,
                              hipStream_t stream) {
  const int*   grid_in = (const int*)d_in[0];
  const int*   anchor  = (const int*)d_in[1];
  const float* embed   = (const float*)d_in[2];
  const float* pos_emb = (const float*)d_in[3];
  const float* wq      = (const float*)d_in[4];
  const float* wk      = (const float*)d_in[5];
  const float* wv      = (const float*)d_in[6];
  const float* wo      = (const float*)d_in[7];
  const float* step_q  = (const float*)d_in[8];
  const float* w_out   = (const float*)d_in[9];
  const float* b_out   = (const float*)d_in[10];
  float* out = (float*)d_out;
  float* ws  = (float*)d_ws;
  short* wsS = (short*)(ws + OFF_F32_END);

  k_small<<<dim3(114), dim3(256), 0, stream>>>(embed, wq, wk, wv, wo, step_q, w_out, ws);
  k_gemm_all<<<dim3(15, 20), dim3(256), 0, stream>>>(pos_emb, wq, wk, wv, wo, ws);
  k_kv<<<dim3(15, 32), dim3(256), 0, stream>>>(grid_in, ws,
                                               wsS + SOFF_KB, wsS + SOFF_VT);
  k_attn<<<dim3(1024), dim3(256), 0, stream>>>(grid_in, ws, wsS + SOFF_KB,
                                               wsS + SOFF_VT, wsS + SOFF_ATTN);
  k_delta<<<dim3(225, 4), dim3(256), 0, stream>>>(grid_in, ws, wsS + SOFF_ATTN,
                                                  wsS + SOFF_WOKVT,
                                                  wsS + SOFF_KB, wsS + SOFF_VT);
  // E aliases SOFF_ATTN (attnOut dead after delta); Sp aliases SOFF_WOKVT.
  float* E  = (float*)(wsS + SOFF_ATTN);
  float* Sp = (float*)(wsS + SOFF_WOKVT);
  k_crossA<<<dim3(15, 4, 32), dim3(256), 0, stream>>>(ws, wsS + SOFF_KB, E, Sp);
  k_crossB<<<dim3(5, 4, 32), dim3(256), 0, stream>>>(E, Sp, wsS + SOFF_VT,
                                                     ws + OFF_CROSS);
  k_logits<<<dim3(12), dim3(256), 0, stream>>>(ws, b_out, out);
  k_execute<<<dim3(32), dim3(64), 0, stream>>>(grid_in, anchor, out + 32 * 8 * 12);
}

// Round 7
// 284.018 us; speedup vs baseline: 3.9028x; 1.0084x over previous
//
#include <hip/hip_runtime.h>

// ===========================================================================
// ARPS forward. tok = embed[grid]+pos => projections distribute over gather.
//   k_small:    tiny f32 GEMMs (embQ/K/V, wo@w_out, q2) + crossOut zeroing
//   k_gemm_all: tiled f32 GEMM posQ/K/V = pos_emb @ [wq|wk|wv]; also
//               woK/woV = wo @ [wk|wv] stored bf16 transposed
//   k_kv:       materialize K bf16 rows + V^T bf16 tiles (one gather pass)
//   k_attn:     flash self-attn, swapped-QK^T S^T layout, m=0 softmax,
//               bf16 MFMA, dbuf global_load_lds staging, XCD-aware grid
//   k_delta:    [28800x512] attnOut @ [woK|woV] MFMA GEMM -> k2/v2
//               (dbuf 2-phase pipeline + bijective XCD-chunked swizzle)
//   k_crossA:   E = exp(scores/8) per 64-tile + partial sums Sp (1920 blks)
//   k_crossB:   crossOut += (E/S) @ v2, t-split atomics (640 blks)
//   k_logits, k_execute (flood fill / rotate / paint)
// Aliasing map (stream-ordered):
//   E (3.7 MB) -> SOFF_ATTN region (14.7 MB, dead after k_delta)
//   Sp (60 KB) -> SOFF_WOKVT region (262 KB, dead after k_delta)
//   k2/v2 -> SOFF_KB / SOFF_VT (Kb/VT dead after k_attn)
// ===========================================================================

typedef __attribute__((ext_vector_type(8))) short bf16x8;   // 8 bf16 (4 VGPR)
typedef __attribute__((ext_vector_type(4))) float f32x4;    // MFMA acc

__device__ __forceinline__ short f2bf(float f) {
  union { float f; unsigned u; } v; v.f = f;
  unsigned r = v.u + 0x7fffu + ((v.u >> 16) & 1u);   // RNE
  return (short)(r >> 16);
}
__device__ __forceinline__ float bf2f(short s) {
  union { unsigned u; float f; } v; v.u = ((unsigned)(unsigned short)s) << 16;
  return v.f;
}
// pack 2 f32 -> 2 bf16 (RNE), gfx950 single instruction
__device__ __forceinline__ unsigned cvt_pk_bf16(float lo, float hi) {
  unsigned r;
  asm("v_cvt_pk_bf16_f32 %0, %1, %2" : "=v"(r) : "v"(lo), "v"(hi));
  return r;
}
// XOR-swizzled index into a [rows][64] bf16 LDS tile (row stride 128B).
__device__ __forceinline__ int swz(int row, int col) {
  return row * 64 + ((((col >> 3) ^ row) & 7) << 3) + (col & 7);
}
// async global->LDS 16B copy; LDS dest is wave-uniform base + lane*16.
__device__ __forceinline__ void gload16(const short* gsrc, short* lds) {
  __builtin_amdgcn_global_load_lds(
      (const __attribute__((address_space(1))) unsigned int*)gsrc,
      (__attribute__((address_space(3))) unsigned int*)lds, 16, 0, 0);
}

// ---------------- workspace layout ----------------
// float region
constexpr size_t OFF_POSQ  = 0;                 // 900x256
constexpr size_t OFF_POSK  = 230400;
constexpr size_t OFF_POSV  = 460800;
constexpr size_t OFF_EMBQ  = 691200;            // 10x256 each
constexpr size_t OFF_EMBK  = 693760;
constexpr size_t OFF_EMBV  = 696320;
constexpr size_t OFF_WOOUT = 698880;            // 256x12
constexpr size_t OFF_Q2    = 701952;            // 8x256
constexpr size_t OFF_CROSS = 704000;            // 32x8x256
constexpr size_t OFF_F32_END = 769536;
// short (bf16) region, offsets in shorts from (short*)(ws+OFF_F32_END)
constexpr size_t SOFF_WOKVT = 0;                // [512][256]; Sp aliases after delta
constexpr size_t SOFF_ATTN  = 131072;           // [28800][256]; E aliases after delta
constexpr size_t SOFF_KB    = 7503872;          // [28800][256] K bf16; k2 aliases
constexpr size_t SOFF_VT    = 14876672;         // [128 bh][15 kt][64d][64t]; v2 aliases

// ---------------------------------------------------------------------------
// Small precompute GEMMs + crossOut zeroing. 114 blocks.
// ---------------------------------------------------------------------------
__global__ void k_small(const float* __restrict__ embed,
                        const float* __restrict__ wq,
                        const float* __restrict__ wk,
                        const float* __restrict__ wv,
                        const float* __restrict__ wo,
                        const float* __restrict__ step_q,
                        const float* __restrict__ w_out,
                        float* __restrict__ ws) {
  const int blk = blockIdx.x;
  if (blk >= 50) {   // zero crossOut (64 blocks x 1024 floats = 65536 floats)
    int i = (blk - 50) * 1024 + threadIdx.x * 4;
    *(float4*)&ws[OFF_CROSS + i] = make_float4(0.f, 0.f, 0.f, 0.f);
    return;
  }
  int job, base;
  if      (blk < 10)  { job = 0; base = blk; }
  else if (blk < 20)  { job = 1; base = blk - 10; }
  else if (blk < 30)  { job = 2; base = blk - 20; }
  else if (blk < 42)  { job = 3; base = blk - 30; }
  else                { job = 4; base = blk - 42; }
  const float* A; const float* Wm; float* C; int M; int N;
  switch (job) {
    case 0: A=embed;  Wm=wq;    C=ws+OFF_EMBQ;  M=10;  N=256; break;
    case 1: A=embed;  Wm=wk;    C=ws+OFF_EMBK;  M=10;  N=256; break;
    case 2: A=embed;  Wm=wv;    C=ws+OFF_EMBV;  M=10;  N=256; break;
    case 3: A=wo;     Wm=w_out; C=ws+OFF_WOOUT; M=256; N=12;  break;
    default:A=step_q; Wm=wq;    C=ws+OFF_Q2;    M=8;   N=256; break;
  }
  int idx = base * 256 + threadIdx.x;
  if (idx >= M * N) return;
  int m = idx / N, n = idx - m * N;
  const float* a = A + (size_t)m * 256;
  float acc = 0.f;
  #pragma unroll 8
  for (int k = 0; k < 256; ++k) acc = fmaf(a[k], Wm[(size_t)k * N + n], acc);
  C[idx] = acc;
}

// ---------------------------------------------------------------------------
// Tiled f32 GEMM, 64x64 tiles, 4x4 micro-tiles. Grid (15, 20).
// ---------------------------------------------------------------------------
__global__ __launch_bounds__(256) void k_gemm_all(const float* __restrict__ pos_emb,
                                                  const float* __restrict__ wq,
                                                  const float* __restrict__ wk,
                                                  const float* __restrict__ wv,
                                                  const float* __restrict__ wo,
                                                  float* __restrict__ ws) {
  const int mt = blockIdx.x, nt = blockIdx.y;
  const bool wojob = nt >= 12;
  if (wojob && mt >= 4) return;
  const float* A = wojob ? wo : pos_emb;
  const float* W;
  float* C = nullptr;
  int n0;
  int base_n = 0;
  if (!wojob) {
    W = nt < 4 ? wq : (nt < 8 ? wk : wv);
    C = ws + (nt < 4 ? OFF_POSQ : (nt < 8 ? OFF_POSK : OFF_POSV));
    n0 = (nt & 3) * 64;
  } else {
    W = nt < 16 ? wk : wv;
    base_n = nt < 16 ? 0 : 256;
    n0 = (nt & 3) * 64;
  }
  const int m0 = mt * 64;
  const int tid = threadIdx.x, tr = tid >> 4, tc = tid & 15;
  __shared__ float As[64][68];
  __shared__ float Bs[64][68];
  float acc[4][4] = {};
  for (int kc = 0; kc < 4; ++kc) {
    __syncthreads();
    for (int i = tid; i < 1024; i += 256) {
      int row = i >> 4, c4 = (i & 15) * 4;
      int m = m0 + row; if (m > 899) m = 899;
      *(float4*)&As[row][c4] = *(const float4*)&A[(size_t)m * 256 + kc * 64 + c4];
      *(float4*)&Bs[row][c4] = *(const float4*)&W[(size_t)(kc * 64 + row) * 256 + n0 + c4];
    }
    __syncthreads();
    #pragma unroll 8
    for (int kk = 0; kk < 64; ++kk) {
      float a0 = As[4*tr+0][kk], a1 = As[4*tr+1][kk];
      float a2 = As[4*tr+2][kk], a3 = As[4*tr+3][kk];
      float4 b4 = *(const float4*)&Bs[kk][4*tc];
      acc[0][0]+=a0*b4.x; acc[0][1]+=a0*b4.y; acc[0][2]+=a0*b4.z; acc[0][3]+=a0*b4.w;
      acc[1][0]+=a1*b4.x; acc[1][1]+=a1*b4.y; acc[1][2]+=a1*b4.z; acc[1][3]+=a1*b4.w;
      acc[2][0]+=a2*b4.x; acc[2][1]+=a2*b4.y; acc[2][2]+=a2*b4.z; acc[2][3]+=a2*b4.w;
      acc[3][0]+=a3*b4.x; acc[3][1]+=a3*b4.y; acc[3][2]+=a3*b4.z; acc[3][3]+=a3*b4.w;
    }
  }
  if (!wojob) {
    #pragma unroll
    for (int i = 0; i < 4; ++i) {
      int m = m0 + 4 * tr + i;
      if (m < 900)
        *(float4*)&C[(size_t)m * 256 + n0 + 4 * tc] =
            make_float4(acc[i][0], acc[i][1], acc[i][2], acc[i][3]);
    }
  } else {
    // transpose in LDS, store bf16 [n][m] into wokvT
    __syncthreads();
    #pragma unroll
    for (int i = 0; i < 4; ++i)
      #pragma unroll
      for (int j = 0; j < 4; ++j)
        Bs[4 * tc + j][4 * tr + i] = acc[i][j];
    __syncthreads();
    short* wokvT = (short*)(ws + OFF_F32_END) + SOFF_WOKVT;
    for (int i = tid; i < 512; i += 256) {
      int row = i >> 3, ch = i & 7;
      union { short s[8]; bf16x8 v; } u;
      #pragma unroll
      for (int jj = 0; jj < 8; ++jj) u.s[jj] = f2bf(Bs[row][ch * 8 + jj]);
      *(bf16x8*)&wokvT[(size_t)(base_n + n0 + row) * 256 + m0 + ch * 8] = u.v;
    }
  }
}

// ---------------------------------------------------------------------------
// Materialize K (row-major bf16) and V^T (tiled bf16) once.
// ---------------------------------------------------------------------------
__global__ __launch_bounds__(256) void k_kv(const int* __restrict__ grid_in,
                                            const float* __restrict__ ws,
                                            short* __restrict__ Kb,
                                            short* __restrict__ VT) {
  const int kt = blockIdx.x, b = blockIdx.y;
  const int t0 = kt * 64, tid = threadIdx.x;
  const float* posK = ws + OFF_POSK;
  const float* embK = ws + OFF_EMBK;
  const float* posV = ws + OFF_POSV;
  const float* embV = ws + OFF_EMBV;

  for (int i = tid; i < 2048; i += 256) {
    int row = i >> 5, ch = i & 31;
    int t = t0 + row;
    if (t > 899) continue;
    int g = grid_in[b * 900 + t];
    const float* pk = posK + (size_t)t * 256 + ch * 8;
    const float* ek = embK + (size_t)g * 256 + ch * 8;
    float4 p0 = *(const float4*)pk, p1 = *(const float4*)(pk + 4);
    float4 e0 = *(const float4*)ek, e1 = *(const float4*)(ek + 4);
    union { short s[8]; bf16x8 v; } u;
    u.s[0] = f2bf(p0.x + e0.x); u.s[1] = f2bf(p0.y + e0.y);
    u.s[2] = f2bf(p0.z + e0.z); u.s[3] = f2bf(p0.w + e0.w);
    u.s[4] = f2bf(p1.x + e1.x); u.s[5] = f2bf(p1.y + e1.y);
    u.s[6] = f2bf(p1.z + e1.z); u.s[7] = f2bf(p1.w + e1.w);
    *(bf16x8*)&Kb[((size_t)(b * 900 + t)) * 256 + ch * 8] = u.v;
  }

  __shared__ float Lf[64 * 65];
  const int tt = tid & 63, dq = tid >> 6;
  for (int h = 0; h < 4; ++h) {
    __syncthreads();
    for (int i = tid; i < 512; i += 256) {
      int row = i >> 3, ch = i & 7;
      int t = t0 + row; if (t > 899) t = 899;
      int g = grid_in[b * 900 + t];
      const float* pv = posV + (size_t)t * 256 + h * 64 + ch * 8;
      const float* ev = embV + (size_t)g * 256 + h * 64 + ch * 8;
      float4 p0 = *(const float4*)pv, p1 = *(const float4*)(pv + 4);
      float4 e0 = *(const float4*)ev, e1 = *(const float4*)(ev + 4);
      float* L = &Lf[row * 65 + ch * 8];
      L[0] = p0.x + e0.x; L[1] = p0.y + e0.y; L[2] = p0.z + e0.z; L[3] = p0.w + e0.w;
      L[4] = p1.x + e1.x; L[5] = p1.y + e1.y; L[6] = p1.z + e1.z; L[7] = p1.w + e1.w;
    }
    __syncthreads();
    short* tile = VT + ((size_t)((b * 4 + h) * 15 + kt)) * 4096;
    #pragma unroll
    for (int dd = 0; dd < 16; ++dd) {
      int d = dq * 16 + dd;
      tile[d * 64 + tt] = f2bf(Lf[tt * 65 + d]);
    }
  }
}

// ---------------------------------------------------------------------------
// Self-attention, swapped-QK^T (S^T: lane owns one q-column), m=0 softmax.
// ---------------------------------------------------------------------------
__global__ __launch_bounds__(256) void k_attn(const int* __restrict__ grid_in,
                                              const float* __restrict__ ws,
                                              const short* __restrict__ Kb,
                                              const short* __restrict__ VT,
                                              short* __restrict__ attnOut) {
  const int bidx = blockIdx.x;                      // XCD-aware encoding
  const int bh = ((bidx >> 6) << 3) | (bidx & 7);
  const int qt = (bidx >> 3) & 7;
  const int h = bh & 3, b = bh >> 2;
  const int t0 = qt * 128, hc = h * 64;
  const int tid = threadIdx.x, w = tid >> 6, lane = tid & 63;
  const int g = lane >> 4, c16 = lane & 15;
  const size_t tileBase = (size_t)(bh * 15) * 4096;

  __shared__ __align__(16) short Ks[2][4096];
  __shared__ __align__(16) short Vs[2][4096];
  __shared__ __align__(16) short Ps[4096];

  const float* posQ = ws + OFF_POSQ;
  const float* embQ = ws + OFF_EMBQ;

  bf16x8 aQ[2][2];
  #pragma unroll
  for (int s = 0; s < 2; ++s) {
    int t = t0 + s * 64 + w * 16 + c16; if (t > 899) t = 899;
    int gq = grid_in[b * 900 + t];
    #pragma unroll
    for (int kc = 0; kc < 2; ++kc) {
      union { short s8[8]; bf16x8 v; } u;
      #pragma unroll
      for (int j = 0; j < 8; ++j) {
        int d = hc + kc * 32 + g * 8 + j;
        u.s8[j] = f2bf(0.125f * (embQ[gq * 256 + d] + posQ[(size_t)t * 256 + d]));
      }
      aQ[s][kc] = u.v;
    }
  }

#define STAGE(BUF, KT)                                                        \
  do {                                                                        \
    int kk0_ = (KT) * 64;                                                     \
    _Pragma("unroll")                                                         \
    for (int j_ = 0; j_ < 2; ++j_) {                                          \
      int c_ = j_ * 256 + w * 64 + lane;                                      \
      int row_ = c_ >> 3, ch_ = c_ & 7;                                       \
      int t_ = kk0_ + row_; if (t_ > 899) t_ = 899;                           \
      int sw_ = ((ch_ ^ row_) & 7) << 3;                                      \
      gload16(Kb + ((size_t)(b * 900 + t_)) * 256 + hc + sw_,                 \
              &Ks[BUF][(j_ * 256 + w * 64) << 3]);                            \
      gload16(VT + tileBase + (size_t)(KT) * 4096 + (row_ << 6) + sw_,        \
              &Vs[BUF][(j_ * 256 + w * 64) << 3]);                            \
    }                                                                         \
  } while (0)

  float l_[2] = {0.f, 0.f};
  f32x4 O[2][4];
  #pragma unroll
  for (int s = 0; s < 2; ++s)
    #pragma unroll
    for (int dt = 0; dt < 4; ++dt) { f32x4 z = {0.f,0.f,0.f,0.f}; O[s][dt] = z; }

  STAGE(0, 0);
  __syncthreads();

  int cur = 0;
  for (int kt = 0; kt < 15; ++kt) {
    if (kt + 1 < 15) STAGE(cur ^ 1, kt + 1);

    if (kt < 14) {
      f32x4 sacc[2][4];
      #pragma unroll
      for (int ct = 0; ct < 4; ++ct) {
        bf16x8 aK0 = *(bf16x8*)&Ks[cur][swz(ct * 16 + c16, g * 8)];
        bf16x8 aK1 = *(bf16x8*)&Ks[cur][swz(ct * 16 + c16, 32 + g * 8)];
        #pragma unroll
        for (int s = 0; s < 2; ++s) {
          f32x4 z = {0.f, 0.f, 0.f, 0.f};
          z = __builtin_amdgcn_mfma_f32_16x16x32_bf16(aK0, aQ[s][0], z, 0, 0, 0);
          z = __builtin_amdgcn_mfma_f32_16x16x32_bf16(aK1, aQ[s][1], z, 0, 0, 0);
          sacc[s][ct] = z;
        }
      }
      #pragma unroll
      for (int s = 0; s < 2; ++s) {
        float rs = 0.f;
        unsigned pk[4][2];
        #pragma unroll
        for (int ct = 0; ct < 4; ++ct) {
          float p0 = __expf(sacc[s][ct][0]);
          float p1 = __expf(sacc[s][ct][1]);
          float p2 = __expf(sacc[s][ct][2]);
          float p3 = __expf(sacc[s][ct][3]);
          rs += (p0 + p1) + (p2 + p3);
          pk[ct][0] = cvt_pk_bf16(p0, p1);
          pk[ct][1] = cvt_pk_bf16(p2, p3);
        }
        rs += __shfl_xor(rs, 16);
        rs += __shfl_xor(rs, 32);
        l_[s] += rs;
        #pragma unroll
        for (int ct = 0; ct < 4; ++ct)
          *(uint2*)&Ps[swz(w * 16 + c16, ct * 16 + 4 * g)] =
              make_uint2(pk[ct][0], pk[ct][1]);
        #pragma unroll
        for (int c = 0; c < 2; ++c) {
          bf16x8 aP = *(bf16x8*)&Ps[swz(w * 16 + c16, c * 32 + g * 8)];
          #pragma unroll
          for (int dt = 0; dt < 4; ++dt) {
            bf16x8 bV = *(bf16x8*)&Vs[cur][swz(dt * 16 + c16, c * 32 + g * 8)];
            O[s][dt] = __builtin_amdgcn_mfma_f32_16x16x32_bf16(aP, bV, O[s][dt], 0, 0, 0);
          }
        }
      }
    } else {
      bf16x8 aK0 = *(bf16x8*)&Ks[cur][swz(c16, g * 8)];
      bf16x8 aK1 = *(bf16x8*)&Ks[cur][swz(c16, 32 + g * 8)];
      #pragma unroll
      for (int s = 0; s < 2; ++s) {
        f32x4 z = {0.f, 0.f, 0.f, 0.f};
        z = __builtin_amdgcn_mfma_f32_16x16x32_bf16(aK0, aQ[s][0], z, 0, 0, 0);
        z = __builtin_amdgcn_mfma_f32_16x16x32_bf16(aK1, aQ[s][1], z, 0, 0, 0);
        float p0 = 0.f, p1 = 0.f, p2 = 0.f, p3 = 0.f;
        if (g == 0) {
          p0 = __expf(z[0]); p1 = __expf(z[1]);
          p2 = __expf(z[2]); p3 = __expf(z[3]);
        }
        float rs = (p0 + p1) + (p2 + p3);
        rs += __shfl_xor(rs, 16);
        rs += __shfl_xor(rs, 32);
        l_[s] += rs;
        *(uint2*)&Ps[swz(w * 16 + c16, 4 * g)] =
            make_uint2(cvt_pk_bf16(p0, p1), cvt_pk_bf16(p2, p3));
        *(uint2*)&Ps[swz(w * 16 + c16, 16 + 4 * g)] = make_uint2(0u, 0u);
        bf16x8 aP = *(bf16x8*)&Ps[swz(w * 16 + c16, g * 8)];
        #pragma unroll
        for (int dt = 0; dt < 4; ++dt) {
          bf16x8 bV = *(bf16x8*)&Vs[cur][swz(dt * 16 + c16, g * 8)];
          O[s][dt] = __builtin_amdgcn_mfma_f32_16x16x32_bf16(aP, bV, O[s][dt], 0, 0, 0);
        }
      }
    }

    __syncthreads();
    cur ^= 1;
  }
#undef STAGE

  #pragma unroll
  for (int s = 0; s < 2; ++s) {
    #pragma unroll
    for (int r = 0; r < 4; ++r) {
      float lq = __shfl(l_[s], (g << 4) | (4 * g + r));
      int t = t0 + s * 64 + w * 16 + 4 * g + r;
      if (t < 900) {
        float inv = 1.f / lq;
        #pragma unroll
        for (int dt = 0; dt < 4; ++dt)
          attnOut[((size_t)(b * 900 + t)) * 256 + hc + dt * 16 + c16] =
              f2bf(O[s][dt][r] * inv);
      }
    }
  }
}

// ---------------------------------------------------------------------------
// Delta GEMM: C[28800x512] = attnOut(bf16) @ [woK|woV] -> k2/v2.
// 1D grid of 900 blocks, bijective XCD-chunked swizzle with n-tile fastest
// (same attnOut tile reused 4x within one XCD's L2). Double-buffered
// global_load_lds staging: STAGE(next) issued before compute(cur).
// ---------------------------------------------------------------------------
__global__ __launch_bounds__(256) void k_delta(const int* __restrict__ grid_in,
                                               const float* __restrict__ ws,
                                               const short* __restrict__ attnOut,
                                               const short* __restrict__ wokvT,
                                               short* __restrict__ k2,
                                               short* __restrict__ v2) {
  // bijective XCD chunking: 900 ids over 8 XCDs, q=112 r=4 (m204 formula)
  const int wgid = blockIdx.x;
  const int xcd = wgid & 7, loc = wgid >> 3;
  const int nid = (xcd < 4 ? xcd * 113 : 452 + (xcd - 4) * 112) + loc;
  const int m0 = (nid >> 2) * 128, n0 = (nid & 3) * 128;

  const int tid = threadIdx.x, w = tid >> 6, lane = tid & 63;
  const int g = lane >> 4, c16 = lane & 15;
  __shared__ __align__(16) short As[2][8192];
  __shared__ __align__(16) short Bs[2][8192];
  f32x4 acc[2][8];
  #pragma unroll
  for (int rt = 0; rt < 2; ++rt)
    #pragma unroll
    for (int ct = 0; ct < 8; ++ct) { f32x4 z = {0.f,0.f,0.f,0.f}; acc[rt][ct] = z; }

#define DSTAGE(BUF, KK)                                                       \
  do {                                                                        \
    _Pragma("unroll")                                                         \
    for (int j_ = 0; j_ < 4; ++j_) {                                          \
      int c_ = j_ * 256 + w * 64 + lane;                                      \
      int row_ = c_ >> 3, ch_ = c_ & 7;                                       \
      int sw_ = ((ch_ ^ row_) & 7) << 3;                                      \
      gload16(attnOut + ((size_t)(m0 + row_)) * 256 + (KK) * 64 + sw_,        \
              &As[BUF][(j_ * 256 + w * 64) << 3]);                            \
      gload16(wokvT + ((size_t)(n0 + row_)) * 256 + (KK) * 64 + sw_,          \
              &Bs[BUF][(j_ * 256 + w * 64) << 3]);                            \
    }                                                                         \
  } while (0)

  DSTAGE(0, 0);
  __syncthreads();

  int cur = 0;
  for (int kk = 0; kk < 4; ++kk) {
    if (kk < 3) DSTAGE(cur ^ 1, kk + 1);   // loads overlap compute below
    #pragma unroll
    for (int ks = 0; ks < 2; ++ks) {
      bf16x8 aA0 = *(bf16x8*)&As[cur][swz(w * 32 + c16, ks * 32 + g * 8)];
      bf16x8 aA1 = *(bf16x8*)&As[cur][swz(w * 32 + 16 + c16, ks * 32 + g * 8)];
      #pragma unroll
      for (int ct = 0; ct < 8; ++ct) {
        bf16x8 bB = *(bf16x8*)&Bs[cur][swz(ct * 16 + c16, ks * 32 + g * 8)];
        acc[0][ct] = __builtin_amdgcn_mfma_f32_16x16x32_bf16(aA0, bB, acc[0][ct], 0, 0, 0);
        acc[1][ct] = __builtin_amdgcn_mfma_f32_16x16x32_bf16(aA1, bB, acc[1][ct], 0, 0, 0);
      }
    }
    __syncthreads();   // drains next-tile loads; orders buffer reuse
    cur ^= 1;
  }
#undef DSTAGE

  const float* embK = ws + OFF_EMBK;
  const float* posK = ws + OFF_POSK;
  const float* embV = ws + OFF_EMBV;
  const float* posV = ws + OFF_POSV;
  #pragma unroll
  for (int rt = 0; rt < 2; ++rt) {
    #pragma unroll
    for (int r = 0; r < 4; ++r) {
      int m = m0 + w * 32 + rt * 16 + 4 * g + r;
      int bb = m / 900, tok = m - bb * 900;
      int gc = grid_in[m];
      #pragma unroll
      for (int ct = 0; ct < 8; ++ct) {
        int n = n0 + ct * 16 + c16;
        float a = acc[rt][ct][r];
        if (n < 256) {
          float val = a + embK[(size_t)gc * 256 + n] + posK[(size_t)tok * 256 + n];
          k2[(((size_t)bb * 4 + (n >> 6)) * 900 + tok) * 64 + (n & 63)] = f2bf(val);
        } else {
          int d = n - 256;
          float val = a + embV[(size_t)gc * 256 + d] + posV[(size_t)tok * 256 + d];
          v2[(((size_t)bb * 4 + (d >> 6)) * 900 + tok) * 64 + (d & 63)] = f2bf(val);
        }
      }
    }
  }
}

// ---------------------------------------------------------------------------
// Cross phase A: E[bh][l][t] = exp(q2.k2/8) (m=0), partial sums Sp[bh][l][kt].
// ---------------------------------------------------------------------------
__global__ __launch_bounds__(256) void k_crossA(const float* __restrict__ ws,
                                                const short* __restrict__ k2,
                                                float* __restrict__ E,
                                                float* __restrict__ Sp) {
  const int kt = blockIdx.x, h = blockIdx.y, b = blockIdx.z;
  const int t0 = kt * 64, bh = b * 4 + h;
  const int tid = threadIdx.x;
  __shared__ __align__(16) short Ks[4096];
  __shared__ float q2s[8][64];
  const float* q2 = ws + OFF_Q2;
  for (int idx = tid; idx < 512; idx += 256)
    q2s[idx >> 6][idx & 63] = q2[(size_t)(idx >> 6) * 256 + h * 64 + (idx & 63)];
  for (int idx = tid; idx < 512; idx += 256) {
    int row = idx >> 3, ch = idx & 7;
    int t = t0 + row;
    if (t < 900)
      *(bf16x8*)&Ks[swz(row, ch * 8)] =
          *(const bf16x8*)&k2[((size_t)bh * 900 + t) * 64 + ch * 8];
  }
  __syncthreads();

  const int tl = tid & 63, lp = tid >> 6;     // wave = lp
  const int t = t0 + tl;
  const bool valid = t < 900;
  float a0 = 0.f, a1 = 0.f;
  #pragma unroll
  for (int ch = 0; ch < 8; ++ch) {
    bf16x8 kv = *(bf16x8*)&Ks[swz(tl, ch * 8)];
    #pragma unroll
    for (int i = 0; i < 8; ++i) {
      float f = bf2f(kv[i]);
      a0 = fmaf(f, q2s[lp][ch * 8 + i], a0);
      a1 = fmaf(f, q2s[lp + 4][ch * 8 + i], a1);
    }
  }
  float e0 = valid ? __expf(a0 * 0.125f) : 0.f;
  float e1 = valid ? __expf(a1 * 0.125f) : 0.f;
  if (valid) {
    E[((size_t)bh * 8 + lp) * 900 + t] = e0;
    E[((size_t)bh * 8 + lp + 4) * 900 + t] = e1;
  }
  float r0 = e0, r1 = e1;
  #pragma unroll
  for (int mk = 1; mk < 64; mk <<= 1) {
    r0 += __shfl_xor(r0, mk);
    r1 += __shfl_xor(r1, mk);
  }
  if (tl == 0) {
    Sp[((size_t)bh * 8 + lp) * 15 + kt] = r0;
    Sp[((size_t)bh * 8 + lp + 4) * 15 + kt] = r1;
  }
}

// ---------------------------------------------------------------------------
// Cross phase B: crossOut[b][l][hc+d] += sum_t (E/S) * v2. Grid (5, 4, 32).
// ---------------------------------------------------------------------------
__global__ __launch_bounds__(256) void k_crossB(const float* __restrict__ E,
                                                const float* __restrict__ Sp,
                                                const short* __restrict__ v2,
                                                float* __restrict__ crossOut) {
  const int ts = blockIdx.x, h = blockIdx.y, b = blockIdx.z;
  const int bh = b * 4 + h;
  const int tid = threadIdx.x;
  const int d = tid & 63, lq = tid >> 6;
  __shared__ float El[8][180];
  __shared__ float SmI[8];
  if (tid < 8) {
    float s = 0.f;
    #pragma unroll
    for (int kt = 0; kt < 15; ++kt) s += Sp[((size_t)bh * 8 + tid) * 15 + kt];
    SmI[tid] = 1.f / s;
  }
  for (int idx = tid; idx < 1440; idx += 256) {
    int l = idx / 180, tt = idx - l * 180;
    El[l][tt] = E[((size_t)bh * 8 + l) * 900 + ts * 180 + tt];
  }
  __syncthreads();

  const short* vb = v2 + ((size_t)bh * 900 + ts * 180) * 64 + d;
  float a0 = 0.f, a1 = 0.f;
  #pragma unroll 4
  for (int tt = 0; tt < 180; ++tt) {
    float vf = bf2f(vb[(size_t)tt * 64]);
    a0 = fmaf(El[lq][tt], vf, a0);
    a1 = fmaf(El[lq + 4][tt], vf, a1);
  }
  atomicAdd(&crossOut[((size_t)b * 8 + lq) * 256 + h * 64 + d], a0 * SmI[lq]);
  atomicAdd(&crossOut[((size_t)b * 8 + lq + 4) * 256 + h * 64 + d], a1 * SmI[lq + 4]);
}

// logits[b,l,p] = crossOut[b,l,:] @ woOut[:,p] + b_out[p]   (48 x 64)
__global__ void k_logits(const float* __restrict__ ws,
                         const float* __restrict__ b_out,
                         float* __restrict__ out) {
  const float* crossOut = ws + OFF_CROSS;
  const float* woOut = ws + OFF_WOOUT;
  int idx = blockIdx.x * 64 + threadIdx.x;
  if (idx >= 32 * 8 * 12) return;
  int p = idx % 12;
  int bl = idx / 12;
  float acc = b_out[p];
  for (int d = 0; d < 256; ++d)
    acc = fmaf(crossOut[(size_t)bl * 256 + d], woOut[d * 12 + p], acc);
  out[idx] = acc;
}

// ---------------------------------------------------------------------------
// Program executor (verified): flood fill, rotate 90 CW about anchor, paint.
// ---------------------------------------------------------------------------
__global__ void k_execute(const int* __restrict__ grid_in,
                          const int* __restrict__ anchor,
                          float* __restrict__ outg) {
  const int b = blockIdx.x;
  const int lane = threadIdx.x;
  const int* g = grid_in + b * 900;
  int ar = anchor[2 * b], ac = anchor[2 * b + 1];
  ar = min(max(ar, 0), 29); ac = min(max(ac, 0), 29);
  const int seed = g[ar * 30 + ac];

  unsigned same = 0u;
  if (lane < 30)
    for (int c = 0; c < 30; ++c) same |= (unsigned)(g[lane * 30 + c] == seed) << c;

  unsigned cur = (lane == ar) ? (1u << ac) : 0u;
  bool changed = true;
  while (changed) {
    unsigned up = __shfl(cur, (lane + 63) & 63);
    unsigned dn = __shfl(cur, (lane + 1) & 63);
    if (lane == 0) up = 0u;
    unsigned nm = (cur | (cur << 1) | (cur >> 1) | up | dn) & same;
    changed = __any(nm != cur);
    cur = nm;
  }

  __shared__ unsigned msh[32];
  if (lane < 32) msh[lane] = (lane < 30) ? cur : 0u;
  __syncthreads();

  if (lane < 30) {
    unsigned rot = 0u;
    int cc = lane - ar + ac;
    if (cc >= 0 && cc < 30) {
      for (int nc = 0; nc < 30; ++nc) {
        int rr = ar + ac - nc;
        if (rr >= 0 && rr < 30) rot |= ((msh[rr] >> cc) & 1u) << nc;
      }
    }
    for (int c = 0; c < 30; ++c) {
      int v = ((rot >> c) & 1u) ? 3 : g[lane * 30 + c];
      outg[b * 900 + lane * 30 + c] = (float)v;
    }
  }
}

// ---------------------------------------------------------------------------
extern "C" void kernel_launch(void* const* d_in, const int* in_sizes, int n_in,
                              void* d_out, int out_size, void* d_ws, size_t ws_size,
                              hipStream_t stream) {
  const int*   grid_in = (const int*)d_in[0];
  const int*   anchor  = (const int*)d_in[1];
  const float* embed   = (const float*)d_in[2];
  const float* pos_emb = (const float*)d_in[3];
  const float* wq      = (const float*)d_in[4];
  const float* wk      = (const float*)d_in[5];
  const float* wv      = (const float*)d_in[6];
  const float* wo      = (const float*)d_in[7];
  const float* step_q  = (const float*)d_in[8];
  const float* w_out   = (const float*)d_in[9];
  const float* b_out   = (const float*)d_in[10];
  float* out = (float*)d_out;
  float* ws  = (float*)d_ws;
  short* wsS = (short*)(ws + OFF_F32_END);

  k_small<<<dim3(114), dim3(256), 0, stream>>>(embed, wq, wk, wv, wo, step_q, w_out, ws);
  k_gemm_all<<<dim3(15, 20), dim3(256), 0, stream>>>(pos_emb, wq, wk, wv, wo, ws);
  k_kv<<<dim3(15, 32), dim3(256), 0, stream>>>(grid_in, ws,
                                               wsS + SOFF_KB, wsS + SOFF_VT);
  k_attn<<<dim3(1024), dim3(256), 0, stream>>>(grid_in, ws, wsS + SOFF_KB,
                                               wsS + SOFF_VT, wsS + SOFF_ATTN);
  k_delta<<<dim3(900), dim3(256), 0, stream>>>(grid_in, ws, wsS + SOFF_ATTN,
                                               wsS + SOFF_WOKVT,
                                               wsS + SOFF_KB, wsS + SOFF_VT);
  // E aliases SOFF_ATTN (attnOut dead after delta); Sp aliases SOFF_WOKVT.
  float* E  = (float*)(wsS + SOFF_ATTN);
  float* Sp = (float*)(wsS + SOFF_WOKVT);
  k_crossA<<<dim3(15, 4, 32), dim3(256), 0, stream>>>(ws, wsS + SOFF_KB, E, Sp);
  k_crossB<<<dim3(5, 4, 32), dim3(256), 0, stream>>>(E, Sp, wsS + SOFF_VT,
                                                     ws + OFF_CROSS);
  k_logits<<<dim3(48), dim3(64), 0, stream>>>(ws, b_out, out);
  k_execute<<<dim3(32), dim3(64), 0, stream>>>(grid_in, anchor, out + 32 * 8 * 12);
}

// Round 8
// 245.131 us; speedup vs baseline: 4.5219x; 1.1586x over previous
//
#include <hip/hip_runtime.h>

// ===========================================================================
// ARPS forward. tok = embed[grid]+pos => projections distribute over gather.
// Cross-attention fully factored (no k2/v2 materialization):
//   score[b,h,l,t] = 0.125*(qp[lh][t] + qe[lh][g] + q2k[lh]·attnOut[b,t])
//   crossOut       = (1/S)(E@V + (E@attnOut)@woV)   [V == self-attn V tiles]
//   logits         = crossMHA @ (wo@w_out)  folded via WVO_h = woV_h@woOut_h
// Kernels:
//   k_small:   tiny f32 GEMMs (embQ/K/V, woOut, q2)
//   k_gemm_all:posQ/K/V = pos_emb@[wq|wk|wv]; woK/woV -> bf16 transposed
//   k_pre2:    q2k(bf16), qp, qe, WVO precomputes
//   k_kv:      K bf16 rows + V^T bf16 tiles (one gather pass)
//   k_attn:    flash self-attn (unchanged, verified)
//   k_crossA:  E = exp(score) via MFMA (attnOut @ q2k^T) + Sp partial sums
//   k_crossP:  partial GEMMs Upart = E@attnOut, Vpart = E@V  (per b,ktg)
//   k_crossR:  reduce partials + emit logits
//   k_execute: flood fill / rotate / paint
// Aliasing (stream-ordered): E/Upart/Vpart in SOFF_KB (Kb dead after attn);
//   Sp in SOFF_WOKVT (dead after pre2); qp/qe/WVO/q2k in old crossOut space.
// ===========================================================================

typedef __attribute__((ext_vector_type(8))) short bf16x8;   // 8 bf16 (4 VGPR)
typedef __attribute__((ext_vector_type(4))) float f32x4;    // MFMA acc

__device__ __forceinline__ short f2bf(float f) {
  union { float f; unsigned u; } v; v.f = f;
  unsigned r = v.u + 0x7fffu + ((v.u >> 16) & 1u);   // RNE
  return (short)(r >> 16);
}
__device__ __forceinline__ float bf2f(short s) {
  union { unsigned u; float f; } v; v.u = ((unsigned)(unsigned short)s) << 16;
  return v.f;
}
__device__ __forceinline__ unsigned cvt_pk_bf16(float lo, float hi) {
  unsigned r;
  asm("v_cvt_pk_bf16_f32 %0, %1, %2" : "=v"(r) : "v"(lo), "v"(hi));
  return r;
}
// XOR-swizzled index into a [rows][64] bf16 LDS tile.
__device__ __forceinline__ int swz(int row, int col) {
  return row * 64 + ((((col >> 3) ^ row) & 7) << 3) + (col & 7);
}
// XOR-swizzled index into a [rows][256] bf16 LDS tile (per-64-col blocks).
__device__ __forceinline__ int a256(int row, int col) {
  return row * 256 + (col & ~63) + (((((col >> 3) & 7) ^ row) & 7) << 3);
}
// async global->LDS 16B copy; LDS dest must be wave-uniform (HW adds lane*16).
__device__ __forceinline__ void gload16(const short* gsrc, short* lds) {
  __builtin_amdgcn_global_load_lds(
      (const __attribute__((address_space(1))) unsigned int*)gsrc,
      (__attribute__((address_space(3))) unsigned int*)lds, 16, 0, 0);
}

// ---------------- workspace layout ----------------
// float region
constexpr size_t OFF_POSQ  = 0;                 // 900x256
constexpr size_t OFF_POSK  = 230400;
constexpr size_t OFF_POSV  = 460800;
constexpr size_t OFF_EMBQ  = 691200;            // 10x256 each
constexpr size_t OFF_EMBK  = 693760;
constexpr size_t OFF_EMBV  = 696320;
constexpr size_t OFF_WOOUT = 698880;            // 256x12  (wo@w_out)
constexpr size_t OFF_Q2    = 701952;            // 8x256   (step_q@wq)
constexpr size_t OFF_QP    = 704000;            // [32lh][900] f32
constexpr size_t OFF_QE    = OFF_QP + 28800;    // [32lh][16] f32 (colors 0..9)
constexpr size_t OFF_WVO   = OFF_QE + 512;      // [4h][256][12] f32
constexpr size_t OFF_Q2K   = OFF_WVO + 12288;   // [32lh][256] bf16 (8192 shorts)
constexpr size_t OFF_F32_END = 769536;
// short region (offsets from (short*)(ws+OFF_F32_END))
constexpr size_t SOFF_WOKVT = 0;                // [512][256]; Sp aliases after pre2
constexpr size_t SOFF_ATTN  = 131072;           // [28800][256] attnOut
constexpr size_t SOFF_KB    = 7503872;          // Kb [28800][256]; E/parts alias
constexpr size_t SOFF_VT    = 14876672;         // [128 bh][15 kt][64d][64t]
constexpr size_t SOFF_E     = SOFF_KB;                 // [32b][32lh][960] bf16
constexpr size_t SOFF_UPART = SOFF_KB + 983040;        // [8][32b][32lh][256]
constexpr size_t SOFF_VPART = SOFF_UPART + 2097152;    // [8][32b][4h][64d][8l]

// ---------------------------------------------------------------------------
// Small precompute GEMMs. 50 blocks.
// ---------------------------------------------------------------------------
__global__ void k_small(const float* __restrict__ embed,
                        const float* __restrict__ wq,
                        const float* __restrict__ wk,
                        const float* __restrict__ wv,
                        const float* __restrict__ wo,
                        const float* __restrict__ step_q,
                        const float* __restrict__ w_out,
                        float* __restrict__ ws) {
  const int blk = blockIdx.x;
  int job, base;
  if      (blk < 10)  { job = 0; base = blk; }
  else if (blk < 20)  { job = 1; base = blk - 10; }
  else if (blk < 30)  { job = 2; base = blk - 20; }
  else if (blk < 42)  { job = 3; base = blk - 30; }
  else                { job = 4; base = blk - 42; }
  const float* A; const float* Wm; float* C; int M; int N;
  switch (job) {
    case 0: A=embed;  Wm=wq;    C=ws+OFF_EMBQ;  M=10;  N=256; break;
    case 1: A=embed;  Wm=wk;    C=ws+OFF_EMBK;  M=10;  N=256; break;
    case 2: A=embed;  Wm=wv;    C=ws+OFF_EMBV;  M=10;  N=256; break;
    case 3: A=wo;     Wm=w_out; C=ws+OFF_WOOUT; M=256; N=12;  break;
    default:A=step_q; Wm=wq;    C=ws+OFF_Q2;    M=8;   N=256; break;
  }
  int idx = base * 256 + threadIdx.x;
  if (idx >= M * N) return;
  int m = idx / N, n = idx - m * N;
  const float* a = A + (size_t)m * 256;
  float acc = 0.f;
  #pragma unroll 8
  for (int k = 0; k < 256; ++k) acc = fmaf(a[k], Wm[(size_t)k * N + n], acc);
  C[idx] = acc;
}

// ---------------------------------------------------------------------------
// Tiled f32 GEMM, 64x64 tiles. Grid (15, 20).
//   nt 0..11: posQ/K/V;  nt 12..19: woK|woV -> bf16 transposed (mt 0..3)
// ---------------------------------------------------------------------------
__global__ __launch_bounds__(256) void k_gemm_all(const float* __restrict__ pos_emb,
                                                  const float* __restrict__ wq,
                                                  const float* __restrict__ wk,
                                                  const float* __restrict__ wv,
                                                  const float* __restrict__ wo,
                                                  float* __restrict__ ws) {
  const int mt = blockIdx.x, nt = blockIdx.y;
  const bool wojob = nt >= 12;
  if (wojob && mt >= 4) return;
  const float* A = wojob ? wo : pos_emb;
  const float* W;
  float* C = nullptr;
  int n0;
  int base_n = 0;
  if (!wojob) {
    W = nt < 4 ? wq : (nt < 8 ? wk : wv);
    C = ws + (nt < 4 ? OFF_POSQ : (nt < 8 ? OFF_POSK : OFF_POSV));
    n0 = (nt & 3) * 64;
  } else {
    W = nt < 16 ? wk : wv;
    base_n = nt < 16 ? 0 : 256;
    n0 = (nt & 3) * 64;
  }
  const int m0 = mt * 64;
  const int tid = threadIdx.x, tr = tid >> 4, tc = tid & 15;
  __shared__ float As[64][68];
  __shared__ float Bs[64][68];
  float acc[4][4] = {};
  for (int kc = 0; kc < 4; ++kc) {
    __syncthreads();
    for (int i = tid; i < 1024; i += 256) {
      int row = i >> 4, c4 = (i & 15) * 4;
      int m = m0 + row; if (m > 899) m = 899;
      *(float4*)&As[row][c4] = *(const float4*)&A[(size_t)m * 256 + kc * 64 + c4];
      *(float4*)&Bs[row][c4] = *(const float4*)&W[(size_t)(kc * 64 + row) * 256 + n0 + c4];
    }
    __syncthreads();
    #pragma unroll 8
    for (int kk = 0; kk < 64; ++kk) {
      float a0 = As[4*tr+0][kk], a1 = As[4*tr+1][kk];
      float a2 = As[4*tr+2][kk], a3 = As[4*tr+3][kk];
      float4 b4 = *(const float4*)&Bs[kk][4*tc];
      acc[0][0]+=a0*b4.x; acc[0][1]+=a0*b4.y; acc[0][2]+=a0*b4.z; acc[0][3]+=a0*b4.w;
      acc[1][0]+=a1*b4.x; acc[1][1]+=a1*b4.y; acc[1][2]+=a1*b4.z; acc[1][3]+=a1*b4.w;
      acc[2][0]+=a2*b4.x; acc[2][1]+=a2*b4.y; acc[2][2]+=a2*b4.z; acc[2][3]+=a2*b4.w;
      acc[3][0]+=a3*b4.x; acc[3][1]+=a3*b4.y; acc[3][2]+=a3*b4.z; acc[3][3]+=a3*b4.w;
    }
  }
  if (!wojob) {
    #pragma unroll
    for (int i = 0; i < 4; ++i) {
      int m = m0 + 4 * tr + i;
      if (m < 900)
        *(float4*)&C[(size_t)m * 256 + n0 + 4 * tc] =
            make_float4(acc[i][0], acc[i][1], acc[i][2], acc[i][3]);
    }
  } else {
    __syncthreads();
    #pragma unroll
    for (int i = 0; i < 4; ++i)
      #pragma unroll
      for (int j = 0; j < 4; ++j)
        Bs[4 * tc + j][4 * tr + i] = acc[i][j];
    __syncthreads();
    short* wokvT = (short*)(ws + OFF_F32_END) + SOFF_WOKVT;
    for (int i = tid; i < 512; i += 256) {
      int row = i >> 3, ch = i & 7;
      union { short s[8]; bf16x8 v; } u;
      #pragma unroll
      for (int jj = 0; jj < 8; ++jj) u.s[jj] = f2bf(Bs[row][ch * 8 + jj]);
      *(bf16x8*)&wokvT[(size_t)(base_n + n0 + row) * 256 + m0 + ch * 8] = u.v;
    }
  }
}

// ---------------------------------------------------------------------------
// pre2: q2k[32][256] bf16, qp[32][900], qe[32][16], WVO[4][256][12]. 69 blocks.
// ---------------------------------------------------------------------------
__global__ __launch_bounds__(256) void k_pre2(float* __restrict__ ws) {
  const float* q2 = ws + OFF_Q2;
  const short* wokvT = (const short*)(ws + OFF_F32_END) + SOFF_WOKVT;
  const int blk = blockIdx.x, tid = threadIdx.x;
  if (blk < 32) {                       // q2k[lh][j] = sum_dd q2[l][hs+dd]*woK[j][hs+dd]
    int lh = blk, h = lh >> 3, l = lh & 7;
    __shared__ float qs[64];
    if (tid < 64) qs[tid] = q2[l * 256 + h * 64 + tid];
    __syncthreads();
    float acc = 0.f;
    for (int dd = 0; dd < 64; ++dd)
      acc = fmaf(qs[dd], bf2f(wokvT[(size_t)(h * 64 + dd) * 256 + tid]), acc);
    ((short*)(ws + OFF_Q2K))[lh * 256 + tid] = f2bf(acc);
  } else if (blk < 64) {                // qp[lh][t]
    int lh = blk - 32, h = lh >> 3, l = lh & 7;
    __shared__ float qs[64];
    if (tid < 64) qs[tid] = q2[l * 256 + h * 64 + tid];
    __syncthreads();
    const float* posK = ws + OFF_POSK;
    for (int t = tid; t < 900; t += 256) {
      float acc = 0.f;
      const float* pr = posK + (size_t)t * 256 + h * 64;
      #pragma unroll 8
      for (int dd = 0; dd < 64; ++dd) acc = fmaf(qs[dd], pr[dd], acc);
      ws[OFF_QP + (size_t)lh * 900 + t] = acc;
    }
  } else if (blk == 64) {               // qe[lh][c]
    const float* embK = ws + OFF_EMBK;
    if (tid < 320) {
      int lh = tid / 10, c = tid - lh * 10;
      int h = lh >> 3, l = lh & 7;
      float acc = 0.f;
      const float* qrow = q2 + l * 256 + h * 64;
      const float* er = embK + (size_t)c * 256 + h * 64;
      for (int dd = 0; dd < 64; ++dd) acc = fmaf(qrow[dd], er[dd], acc);
      ws[OFF_QE + lh * 16 + c] = acc;
    }
  } else {                              // WVO_h[j][p] = sum_dd woV[j][hs+dd]*woOut[hs+dd][p]
    int h = blk - 65;
    const float* woOut = ws + OFF_WOOUT;
    __shared__ float wos[64][12];
    for (int i = tid; i < 768; i += 256) wos[i / 12][i % 12] = woOut[(h * 64 + i / 12) * 12 + i % 12];
    __syncthreads();
    float acc[12] = {};
    for (int dd = 0; dd < 64; ++dd) {
      float v = bf2f(wokvT[(size_t)(256 + h * 64 + dd) * 256 + tid]);
      #pragma unroll
      for (int p = 0; p < 12; ++p) acc[p] = fmaf(v, wos[dd][p], acc[p]);
    }
    #pragma unroll
    for (int p = 0; p < 12; ++p)
      ws[OFF_WVO + ((size_t)h * 256 + tid) * 12 + p] = acc[p];
  }
}

// ---------------------------------------------------------------------------
// Materialize K (row-major bf16) and V^T (tiled bf16) once. (verified)
// ---------------------------------------------------------------------------
__global__ __launch_bounds__(256) void k_kv(const int* __restrict__ grid_in,
                                            const float* __restrict__ ws,
                                            short* __restrict__ Kb,
                                            short* __restrict__ VT) {
  const int kt = blockIdx.x, b = blockIdx.y;
  const int t0 = kt * 64, tid = threadIdx.x;
  const float* posK = ws + OFF_POSK;
  const float* embK = ws + OFF_EMBK;
  const float* posV = ws + OFF_POSV;
  const float* embV = ws + OFF_EMBV;

  for (int i = tid; i < 2048; i += 256) {
    int row = i >> 5, ch = i & 31;
    int t = t0 + row;
    if (t > 899) continue;
    int g = grid_in[b * 900 + t];
    const float* pk = posK + (size_t)t * 256 + ch * 8;
    const float* ek = embK + (size_t)g * 256 + ch * 8;
    float4 p0 = *(const float4*)pk, p1 = *(const float4*)(pk + 4);
    float4 e0 = *(const float4*)ek, e1 = *(const float4*)(ek + 4);
    union { short s[8]; bf16x8 v; } u;
    u.s[0] = f2bf(p0.x + e0.x); u.s[1] = f2bf(p0.y + e0.y);
    u.s[2] = f2bf(p0.z + e0.z); u.s[3] = f2bf(p0.w + e0.w);
    u.s[4] = f2bf(p1.x + e1.x); u.s[5] = f2bf(p1.y + e1.y);
    u.s[6] = f2bf(p1.z + e1.z); u.s[7] = f2bf(p1.w + e1.w);
    *(bf16x8*)&Kb[((size_t)(b * 900 + t)) * 256 + ch * 8] = u.v;
  }

  __shared__ float Lf[64 * 65];
  const int tt = tid & 63, dq = tid >> 6;
  for (int h = 0; h < 4; ++h) {
    __syncthreads();
    for (int i = tid; i < 512; i += 256) {
      int row = i >> 3, ch = i & 7;
      int t = t0 + row; if (t > 899) t = 899;
      int g = grid_in[b * 900 + t];
      const float* pv = posV + (size_t)t * 256 + h * 64 + ch * 8;
      const float* ev = embV + (size_t)g * 256 + h * 64 + ch * 8;
      float4 p0 = *(const float4*)pv, p1 = *(const float4*)(pv + 4);
      float4 e0 = *(const float4*)ev, e1 = *(const float4*)(ev + 4);
      float* L = &Lf[row * 65 + ch * 8];
      L[0] = p0.x + e0.x; L[1] = p0.y + e0.y; L[2] = p0.z + e0.z; L[3] = p0.w + e0.w;
      L[4] = p1.x + e1.x; L[5] = p1.y + e1.y; L[6] = p1.z + e1.z; L[7] = p1.w + e1.w;
    }
    __syncthreads();
    short* tile = VT + ((size_t)((b * 4 + h) * 15 + kt)) * 4096;
    #pragma unroll
    for (int dd = 0; dd < 16; ++dd) {
      int d = dq * 16 + dd;
      tile[d * 64 + tt] = f2bf(Lf[tt * 65 + d]);
    }
  }
}

// ---------------------------------------------------------------------------
// Self-attention (unchanged, verified): swapped-QK^T, m=0 softmax, dbuf.
// ---------------------------------------------------------------------------
__global__ __launch_bounds__(256) void k_attn(const int* __restrict__ grid_in,
                                              const float* __restrict__ ws,
                                              const short* __restrict__ Kb,
                                              const short* __restrict__ VT,
                                              short* __restrict__ attnOut) {
  const int bidx = blockIdx.x;
  const int bh = ((bidx >> 6) << 3) | (bidx & 7);
  const int qt = (bidx >> 3) & 7;
  const int h = bh & 3, b = bh >> 2;
  const int t0 = qt * 128, hc = h * 64;
  const int tid = threadIdx.x, w = tid >> 6, lane = tid & 63;
  const int g = lane >> 4, c16 = lane & 15;
  const size_t tileBase = (size_t)(bh * 15) * 4096;

  __shared__ __align__(16) short Ks[2][4096];
  __shared__ __align__(16) short Vs[2][4096];
  __shared__ __align__(16) short Ps[4096];

  const float* posQ = ws + OFF_POSQ;
  const float* embQ = ws + OFF_EMBQ;

  bf16x8 aQ[2][2];
  #pragma unroll
  for (int s = 0; s < 2; ++s) {
    int t = t0 + s * 64 + w * 16 + c16; if (t > 899) t = 899;
    int gq = grid_in[b * 900 + t];
    #pragma unroll
    for (int kc = 0; kc < 2; ++kc) {
      union { short s8[8]; bf16x8 v; } u;
      #pragma unroll
      for (int j = 0; j < 8; ++j) {
        int d = hc + kc * 32 + g * 8 + j;
        u.s8[j] = f2bf(0.125f * (embQ[gq * 256 + d] + posQ[(size_t)t * 256 + d]));
      }
      aQ[s][kc] = u.v;
    }
  }

#define STAGE(BUF, KT)                                                        \
  do {                                                                        \
    int kk0_ = (KT) * 64;                                                     \
    _Pragma("unroll")                                                         \
    for (int j_ = 0; j_ < 2; ++j_) {                                          \
      int c_ = j_ * 256 + w * 64 + lane;                                      \
      int row_ = c_ >> 3, ch_ = c_ & 7;                                       \
      int t_ = kk0_ + row_; if (t_ > 899) t_ = 899;                           \
      int sw_ = ((ch_ ^ row_) & 7) << 3;                                      \
      gload16(Kb + ((size_t)(b * 900 + t_)) * 256 + hc + sw_,                 \
              &Ks[BUF][(j_ * 256 + w * 64) << 3]);                            \
      gload16(VT + tileBase + (size_t)(KT) * 4096 + (row_ << 6) + sw_,        \
              &Vs[BUF][(j_ * 256 + w * 64) << 3]);                            \
    }                                                                         \
  } while (0)

  float l_[2] = {0.f, 0.f};
  f32x4 O[2][4];
  #pragma unroll
  for (int s = 0; s < 2; ++s)
    #pragma unroll
    for (int dt = 0; dt < 4; ++dt) { f32x4 z = {0.f,0.f,0.f,0.f}; O[s][dt] = z; }

  STAGE(0, 0);
  __syncthreads();

  int cur = 0;
  for (int kt = 0; kt < 15; ++kt) {
    if (kt + 1 < 15) STAGE(cur ^ 1, kt + 1);

    if (kt < 14) {
      f32x4 sacc[2][4];
      #pragma unroll
      for (int ct = 0; ct < 4; ++ct) {
        bf16x8 aK0 = *(bf16x8*)&Ks[cur][swz(ct * 16 + c16, g * 8)];
        bf16x8 aK1 = *(bf16x8*)&Ks[cur][swz(ct * 16 + c16, 32 + g * 8)];
        #pragma unroll
        for (int s = 0; s < 2; ++s) {
          f32x4 z = {0.f, 0.f, 0.f, 0.f};
          z = __builtin_amdgcn_mfma_f32_16x16x32_bf16(aK0, aQ[s][0], z, 0, 0, 0);
          z = __builtin_amdgcn_mfma_f32_16x16x32_bf16(aK1, aQ[s][1], z, 0, 0, 0);
          sacc[s][ct] = z;
        }
      }
      #pragma unroll
      for (int s = 0; s < 2; ++s) {
        float rs = 0.f;
        unsigned pk[4][2];
        #pragma unroll
        for (int ct = 0; ct < 4; ++ct) {
          float p0 = __expf(sacc[s][ct][0]);
          float p1 = __expf(sacc[s][ct][1]);
          float p2 = __expf(sacc[s][ct][2]);
          float p3 = __expf(sacc[s][ct][3]);
          rs += (p0 + p1) + (p2 + p3);
          pk[ct][0] = cvt_pk_bf16(p0, p1);
          pk[ct][1] = cvt_pk_bf16(p2, p3);
        }
        rs += __shfl_xor(rs, 16);
        rs += __shfl_xor(rs, 32);
        l_[s] += rs;
        #pragma unroll
        for (int ct = 0; ct < 4; ++ct)
          *(uint2*)&Ps[swz(w * 16 + c16, ct * 16 + 4 * g)] =
              make_uint2(pk[ct][0], pk[ct][1]);
        #pragma unroll
        for (int c = 0; c < 2; ++c) {
          bf16x8 aP = *(bf16x8*)&Ps[swz(w * 16 + c16, c * 32 + g * 8)];
          #pragma unroll
          for (int dt = 0; dt < 4; ++dt) {
            bf16x8 bV = *(bf16x8*)&Vs[cur][swz(dt * 16 + c16, c * 32 + g * 8)];
            O[s][dt] = __builtin_amdgcn_mfma_f32_16x16x32_bf16(aP, bV, O[s][dt], 0, 0, 0);
          }
        }
      }
    } else {
      bf16x8 aK0 = *(bf16x8*)&Ks[cur][swz(c16, g * 8)];
      bf16x8 aK1 = *(bf16x8*)&Ks[cur][swz(c16, 32 + g * 8)];
      #pragma unroll
      for (int s = 0; s < 2; ++s) {
        f32x4 z = {0.f, 0.f, 0.f, 0.f};
        z = __builtin_amdgcn_mfma_f32_16x16x32_bf16(aK0, aQ[s][0], z, 0, 0, 0);
        z = __builtin_amdgcn_mfma_f32_16x16x32_bf16(aK1, aQ[s][1], z, 0, 0, 0);
        float p0 = 0.f, p1 = 0.f, p2 = 0.f, p3 = 0.f;
        if (g == 0) {
          p0 = __expf(z[0]); p1 = __expf(z[1]);
          p2 = __expf(z[2]); p3 = __expf(z[3]);
        }
        float rs = (p0 + p1) + (p2 + p3);
        rs += __shfl_xor(rs, 16);
        rs += __shfl_xor(rs, 32);
        l_[s] += rs;
        *(uint2*)&Ps[swz(w * 16 + c16, 4 * g)] =
            make_uint2(cvt_pk_bf16(p0, p1), cvt_pk_bf16(p2, p3));
        *(uint2*)&Ps[swz(w * 16 + c16, 16 + 4 * g)] = make_uint2(0u, 0u);
        bf16x8 aP = *(bf16x8*)&Ps[swz(w * 16 + c16, g * 8)];
        #pragma unroll
        for (int dt = 0; dt < 4; ++dt) {
          bf16x8 bV = *(bf16x8*)&Vs[cur][swz(dt * 16 + c16, g * 8)];
          O[s][dt] = __builtin_amdgcn_mfma_f32_16x16x32_bf16(aP, bV, O[s][dt], 0, 0, 0);
        }
      }
    }

    __syncthreads();
    cur ^= 1;
  }
#undef STAGE

  #pragma unroll
  for (int s = 0; s < 2; ++s) {
    #pragma unroll
    for (int r = 0; r < 4; ++r) {
      float lq = __shfl(l_[s], (g << 4) | (4 * g + r));
      int t = t0 + s * 64 + w * 16 + 4 * g + r;
      if (t < 900) {
        float inv = 1.f / lq;
        #pragma unroll
        for (int dt = 0; dt < 4; ++dt)
          attnOut[((size_t)(b * 900 + t)) * 256 + hc + dt * 16 + c16] =
              f2bf(O[s][dt][r] * inv);
      }
    }
  }
}

// ---------------------------------------------------------------------------
// crossA: E[b][lh][t] = exp(0.125*(qp+qe+attnOut.q2k)), zero-padded t>=900.
// MFMA: D[t][lh] = attnOut_tile(64x256) @ q2k^T. Grid (15 kt, 32 b).
// ---------------------------------------------------------------------------
__global__ __launch_bounds__(256) void k_crossA(const int* __restrict__ grid_in,
                                                const float* __restrict__ ws,
                                                const short* __restrict__ attnOut,
                                                short* __restrict__ E,
                                                float* __restrict__ Sp) {
  const int kt = blockIdx.x, b = blockIdx.y;
  const int t0 = kt * 64;
  const int tid = threadIdx.x, w = tid >> 6, lane = tid & 63;
  const int g = lane >> 4, c16 = lane & 15;
  __shared__ __align__(16) short Aat[16384];   // [64][256] swz
  __shared__ __align__(16) short Qk[8192];     // [32][256] swz
  __shared__ float qpL[32 * 72];
  __shared__ float qeL[512];
  __shared__ int   gtl[64];
  __shared__ float spW[128];

  // stage attnOut tile (source-swizzled gload16; dest wave-uniform)
  #pragma unroll
  for (int it = 0; it < 8; ++it) {
    int idx = it * 256 + w * 64 + lane;
    int row = idx >> 5, ch = idx & 31;
    int t = t0 + row; if (t > 899) t = 899;
    int sw = (((ch & 7) ^ row) & 7) << 3;
    gload16(attnOut + ((size_t)(b * 900 + t)) * 256 + (ch >> 3) * 64 + sw,
            &Aat[(it * 256 + w * 64) << 3]);
  }
  const short* q2k = (const short*)(ws + OFF_Q2K);
  #pragma unroll
  for (int it = 0; it < 4; ++it) {
    int idx = it * 256 + w * 64 + lane;
    int row = idx >> 5, ch = idx & 31;
    int sw = (((ch & 7) ^ row) & 7) << 3;
    gload16(q2k + (size_t)row * 256 + (ch >> 3) * 64 + sw,
            &Qk[(it * 256 + w * 64) << 3]);
  }
  #pragma unroll
  for (int it = 0; it < 2; ++it) {
    int idx = it * 256 + tid, row = idx >> 4, c4 = (idx & 15) * 4;
    *(float4*)&qpL[row * 72 + c4] = *(const float4*)&ws[OFF_QP + (size_t)row * 900 + t0 + c4];
  }
  for (int idx = tid; idx < 512; idx += 256) qeL[idx] = ws[OFF_QE + idx];
  if (tid < 64) { int t = t0 + tid; gtl[tid] = grid_in[b * 900 + (t > 899 ? 899 : t)]; }
  __syncthreads();

  f32x4 sacc[2];
  { f32x4 z = {0.f,0.f,0.f,0.f}; sacc[0] = z; sacc[1] = z; }
  #pragma unroll
  for (int kk = 0; kk < 8; ++kk) {
    bf16x8 aA = *(bf16x8*)&Aat[a256(w * 16 + c16, kk * 32 + g * 8)];
    bf16x8 b0 = *(bf16x8*)&Qk[a256(c16, kk * 32 + g * 8)];
    bf16x8 b1 = *(bf16x8*)&Qk[a256(16 + c16, kk * 32 + g * 8)];
    sacc[0] = __builtin_amdgcn_mfma_f32_16x16x32_bf16(aA, b0, sacc[0], 0, 0, 0);
    sacc[1] = __builtin_amdgcn_mfma_f32_16x16x32_bf16(aA, b1, sacc[1], 0, 0, 0);
  }
  #pragma unroll
  for (int ct = 0; ct < 2; ++ct) {
    int lh = ct * 16 + c16;
    float e[4]; float rs = 0.f;
    #pragma unroll
    for (int r = 0; r < 4; ++r) {
      int tl = w * 16 + g * 4 + r;
      float s = 0.125f * (sacc[ct][r] + qpL[lh * 72 + tl] + qeL[lh * 16 + gtl[tl]]);
      e[r] = (t0 + tl < 900) ? __expf(s) : 0.f;
      rs += e[r];
    }
    *(uint2*)&E[((size_t)(b * 32 + lh)) * 960 + t0 + w * 16 + g * 4] =
        make_uint2(cvt_pk_bf16(e[0], e[1]), cvt_pk_bf16(e[2], e[3]));
    rs += __shfl_xor(rs, 16);
    rs += __shfl_xor(rs, 32);
    if (g == 0) spW[w * 32 + lh] = rs;
  }
  __syncthreads();
  if (tid < 32)
    Sp[((size_t)b * 32 + tid) * 15 + kt] =
        spW[tid] + spW[32 + tid] + spW[64 + tid] + spW[96 + tid];
}

// ---------------------------------------------------------------------------
// crossP: Upart[ktg][b][lh][j] = sum_t E*attnOut, Vpart[ktg][b][h][d][l] =
// sum_t E*V (from VT tiles). Grid (8 ktg, 32 b). ktg=7 covers 1 tile.
// ---------------------------------------------------------------------------
__global__ __launch_bounds__(256) void k_crossP(const short* __restrict__ attnOut,
                                                const short* __restrict__ E,
                                                const short* __restrict__ VT,
                                                short* __restrict__ Upart,
                                                short* __restrict__ Vpart) {
  const int ktg = blockIdx.x, b = blockIdx.y;
  const int tid = threadIdx.x, w = tid >> 6, lane = tid & 63;
  const int g = lane >> 4, c16 = lane & 15;
  const int h = w, ctv = h >> 1;
  __shared__ __align__(16) short AT[256 * 72];   // attnOut^T [j][t], skewed
  __shared__ __align__(16) short Et[2048];       // [32][64] swz
  __shared__ __align__(16) short VTl[16384];     // [4][64][64] swz

  f32x4 Uacc[2][4], Vacc[4];
  { f32x4 z = {0.f,0.f,0.f,0.f};
    #pragma unroll
    for (int a = 0; a < 2; ++a)
      #pragma unroll
      for (int q = 0; q < 4; ++q) Uacc[a][q] = z;
    #pragma unroll
    for (int a = 0; a < 4; ++a) Vacc[a] = z; }

  const int ntile = (ktg < 7) ? 2 : 1;
  for (int tt = 0; tt < ntile; ++tt) {
    const int kt = ktg * 2 + tt, t0 = kt * 64;
    if (tt) __syncthreads();
    // transpose-stage attnOut^T (reg-staged; skew spreads banks)
    #pragma unroll
    for (int it = 0; it < 8; ++it) {
      int idx = it * 256 + tid;
      int tl = idx >> 5, jc = idx & 31;
      int t = t0 + tl; if (t > 899) t = 899;
      bf16x8 v = *(const bf16x8*)&attnOut[((size_t)(b * 900 + t)) * 256 + jc * 8];
      #pragma unroll
      for (int ii = 0; ii < 8; ++ii)
        AT[(jc * 8 + ii) * 72 + ((((tl >> 3) ^ jc) & 7) << 3) + (tl & 7)] = v[ii];
    }
    // E tile [32][64] swz (gload16)
    {
      int idx = w * 64 + lane;
      int row = idx >> 3, ch = idx & 7;
      int sw = ((ch ^ row) & 7) << 3;
      gload16(E + ((size_t)(b * 32 + row)) * 960 + t0 + sw, &Et[(w * 64) << 3]);
    }
    // VT tiles (4 h)
    #pragma unroll
    for (int it = 0; it < 8; ++it) {
      int idx = it * 256 + w * 64 + lane;
      int hh = idx >> 9, rem = idx & 511;
      int row = rem >> 3, ch = rem & 7;
      int sw = ((ch ^ row) & 7) << 3;
      gload16(VT + ((size_t)((b * 4 + hh) * 15 + kt)) * 4096 + row * 64 + sw,
              &VTl[(it * 256 + w * 64) << 3]);
    }
    __syncthreads();
    #pragma unroll
    for (int kk = 0; kk < 2; ++kk) {
      bf16x8 aE0 = *(bf16x8*)&Et[swz(c16, kk * 32 + g * 8)];
      bf16x8 aE1 = *(bf16x8*)&Et[swz(16 + c16, kk * 32 + g * 8)];
      #pragma unroll
      for (int q = 0; q < 4; ++q) {
        int j = (w * 4 + q) * 16 + c16;
        int tch = kk * 4 + g;
        bf16x8 bA = *(bf16x8*)&AT[j * 72 + (((tch ^ (j >> 3)) & 7) << 3)];
        Uacc[0][q] = __builtin_amdgcn_mfma_f32_16x16x32_bf16(aE0, bA, Uacc[0][q], 0, 0, 0);
        Uacc[1][q] = __builtin_amdgcn_mfma_f32_16x16x32_bf16(aE1, bA, Uacc[1][q], 0, 0, 0);
      }
      bf16x8 bE = (ctv == 0) ? aE0 : aE1;
      #pragma unroll
      for (int rt = 0; rt < 4; ++rt) {
        bf16x8 aV = *(bf16x8*)&VTl[h * 4096 + swz(rt * 16 + c16, kk * 32 + g * 8)];
        Vacc[rt] = __builtin_amdgcn_mfma_f32_16x16x32_bf16(aV, bE, Vacc[rt], 0, 0, 0);
      }
    }
  }
  // write partials (bf16)
  #pragma unroll
  for (int rt = 0; rt < 2; ++rt)
    #pragma unroll
    for (int q = 0; q < 4; ++q) {
      int j = (w * 4 + q) * 16 + c16;
      #pragma unroll
      for (int r = 0; r < 4; ++r) {
        int lh = rt * 16 + g * 4 + r;
        Upart[(((size_t)(ktg * 32 + b)) * 32 + lh) * 256 + j] = f2bf(Uacc[rt][q][r]);
      }
    }
  if ((c16 >> 3) == (h & 1)) {
    int l = c16 & 7;
    #pragma unroll
    for (int rt = 0; rt < 4; ++rt)
      #pragma unroll
      for (int r = 0; r < 4; ++r) {
        int d = rt * 16 + g * 4 + r;
        Vpart[((((size_t)(ktg * 32 + b)) * 4 + h) * 64 + d) * 8 + l] = f2bf(Vacc[rt][r]);
      }
  }
}

// ---------------------------------------------------------------------------
// crossR: reduce partials, emit logits. Grid 256 (b*8+l), 64 threads.
// ---------------------------------------------------------------------------
__global__ void k_crossR(const float* __restrict__ ws,
                         const float* __restrict__ b_out,
                         const short* __restrict__ Upart,
                         const short* __restrict__ Vpart,
                         const float* __restrict__ Sp,
                         float* __restrict__ out) {
  const int bl = blockIdx.x, b = bl >> 3, l = bl & 7;
  const int tid = threadIdx.x;
  __shared__ float Us[4][256];
  __shared__ float Vsm[4][64];
  __shared__ float Sinv[4];
  __shared__ float part[4][12];
  for (int h = 0; h < 4; ++h) {
    int lh = h * 8 + l;
    for (int j = tid; j < 256; j += 64) {
      float a = 0.f;
      #pragma unroll
      for (int kg = 0; kg < 8; ++kg)
        a += bf2f(Upart[(((size_t)(kg * 32 + b)) * 32 + lh) * 256 + j]);
      Us[h][j] = a;
    }
    float a = 0.f;
    #pragma unroll
    for (int kg = 0; kg < 8; ++kg)
      a += bf2f(Vpart[((((size_t)(kg * 32 + b)) * 4 + h) * 64 + tid) * 8 + l]);
    Vsm[h][tid] = a;
  }
  if (tid < 4) {
    int lh = tid * 8 + l;
    float s = 0.f;
    #pragma unroll
    for (int k = 0; k < 15; ++k) s += Sp[((size_t)b * 32 + lh) * 15 + k];
    Sinv[tid] = 1.f / s;
  }
  __syncthreads();
  if (tid < 48) {
    int h = tid / 12, p = tid % 12;
    const float* woOut = ws + OFF_WOOUT;
    const float* WVO = ws + OFF_WVO;
    float acc = 0.f;
    for (int dd = 0; dd < 64; ++dd)
      acc = fmaf(Vsm[h][dd], woOut[(h * 64 + dd) * 12 + p], acc);
    for (int j = 0; j < 256; ++j)
      acc = fmaf(Us[h][j], WVO[((size_t)h * 256 + j) * 12 + p], acc);
    part[h][p] = acc * Sinv[h];
  }
  __syncthreads();
  if (tid < 12)
    out[(size_t)bl * 12 + tid] =
        b_out[tid] + part[0][tid] + part[1][tid] + part[2][tid] + part[3][tid];
}

// ---------------------------------------------------------------------------
// Program executor (verified): flood fill, rotate 90 CW about anchor, paint.
// ---------------------------------------------------------------------------
__global__ void k_execute(const int* __restrict__ grid_in,
                          const int* __restrict__ anchor,
                          float* __restrict__ outg) {
  const int b = blockIdx.x;
  const int lane = threadIdx.x;
  const int* g = grid_in + b * 900;
  int ar = anchor[2 * b], ac = anchor[2 * b + 1];
  ar = min(max(ar, 0), 29); ac = min(max(ac, 0), 29);
  const int seed = g[ar * 30 + ac];

  unsigned same = 0u;
  if (lane < 30)
    for (int c = 0; c < 30; ++c) same |= (unsigned)(g[lane * 30 + c] == seed) << c;

  unsigned cur = (lane == ar) ? (1u << ac) : 0u;
  bool changed = true;
  while (changed) {
    unsigned up = __shfl(cur, (lane + 63) & 63);
    unsigned dn = __shfl(cur, (lane + 1) & 63);
    if (lane == 0) up = 0u;
    unsigned nm = (cur | (cur << 1) | (cur >> 1) | up | dn) & same;
    changed = __any(nm != cur);
    cur = nm;
  }

  __shared__ unsigned msh[32];
  if (lane < 32) msh[lane] = (lane < 30) ? cur : 0u;
  __syncthreads();

  if (lane < 30) {
    unsigned rot = 0u;
    int cc = lane - ar + ac;
    if (cc >= 0 && cc < 30) {
      for (int nc = 0; nc < 30; ++nc) {
        int rr = ar + ac - nc;
        if (rr >= 0 && rr < 30) rot |= ((msh[rr] >> cc) & 1u) << nc;
      }
    }
    for (int c = 0; c < 30; ++c) {
      int v = ((rot >> c) & 1u) ? 3 : g[lane * 30 + c];
      outg[b * 900 + lane * 30 + c] = (float)v;
    }
  }
}

// ---------------------------------------------------------------------------
extern "C" void kernel_launch(void* const* d_in, const int* in_sizes, int n_in,
                              void* d_out, int out_size, void* d_ws, size_t ws_size,
                              hipStream_t stream) {
  const int*   grid_in = (const int*)d_in[0];
  const int*   anchor  = (const int*)d_in[1];
  const float* embed   = (const float*)d_in[2];
  const float* pos_emb = (const float*)d_in[3];
  const float* wq      = (const float*)d_in[4];
  const float* wk      = (const float*)d_in[5];
  const float* wv      = (const float*)d_in[6];
  const float* wo      = (const float*)d_in[7];
  const float* step_q  = (const float*)d_in[8];
  const float* w_out   = (const float*)d_in[9];
  const float* b_out   = (const float*)d_in[10];
  float* out = (float*)d_out;
  float* ws  = (float*)d_ws;
  short* wsS = (short*)(ws + OFF_F32_END);

  k_small<<<dim3(50), dim3(256), 0, stream>>>(embed, wq, wk, wv, wo, step_q, w_out, ws);
  k_gemm_all<<<dim3(15, 20), dim3(256), 0, stream>>>(pos_emb, wq, wk, wv, wo, ws);
  k_pre2<<<dim3(69), dim3(256), 0, stream>>>(ws);
  k_kv<<<dim3(15, 32), dim3(256), 0, stream>>>(grid_in, ws,
                                               wsS + SOFF_KB, wsS + SOFF_VT);
  k_attn<<<dim3(1024), dim3(256), 0, stream>>>(grid_in, ws, wsS + SOFF_KB,
                                               wsS + SOFF_VT, wsS + SOFF_ATTN);
  // E / partials alias Kb (dead after attn); Sp aliases wokvT (dead after pre2)
  short* E  = wsS + SOFF_E;
  float* Sp = (float*)(wsS + SOFF_WOKVT);
  k_crossA<<<dim3(15, 32), dim3(256), 0, stream>>>(grid_in, ws, wsS + SOFF_ATTN, E, Sp);
  k_crossP<<<dim3(8, 32), dim3(256), 0, stream>>>(wsS + SOFF_ATTN, E, wsS + SOFF_VT,
                                                  wsS + SOFF_UPART, wsS + SOFF_VPART);
  k_crossR<<<dim3(256), dim3(64), 0, stream>>>(ws, b_out, wsS + SOFF_UPART,
                                               wsS + SOFF_VPART, Sp, out);
  k_execute<<<dim3(32), dim3(64), 0, stream>>>(grid_in, anchor, out + 32 * 8 * 12);
}

// Round 9
// 226.560 us; speedup vs baseline: 4.8925x; 1.0820x over previous
//
#include <hip/hip_runtime.h>

// ===========================================================================
// ARPS forward. tok = embed[grid]+pos => projections distribute over gather.
// Cross-attention fully factored (no k2/v2):
//   score[b,h,l,t] = 0.125*(qp[lh][t] + qe[lh][g] + q2k[lh]·attnOut[b,t])
//   crossOut       = (1/S)(E@V + (E@attnOut)@woV); logits fold via WVO.
// Kernels (8 launches):
//   k_pre:    merged tiny GEMMs + tiled 64x64 GEMMs (posQ/K/V, woK/V^T bf16)
//   k_pre2:   q2k(bf16), qp, qe, WVO precomputes
//   k_kv:     K bf16 rows + V^T bf16 tiles (vectorized 16B stores)
//   k_attn:   flash self-attn, swapped-QK^T, m=0 softmax (exp2 path)
//   k_crossA: E = exp2(c*score) via MFMA + Sp partial sums
//   k_crossP: partial GEMMs Upart = E@attnOut, Vpart = E@V
//   k_crossR: reduce partials + emit logits
//   k_execute: flood fill / rotate / paint
// ===========================================================================

typedef __attribute__((ext_vector_type(8))) short bf16x8;   // 8 bf16 (4 VGPR)
typedef __attribute__((ext_vector_type(4))) float f32x4;    // MFMA acc

constexpr float kScl = 0.18033688011112042f;   // 0.125 * log2(e)

__device__ __forceinline__ short f2bf(float f) {
  union { float f; unsigned u; } v; v.f = f;
  unsigned r = v.u + 0x7fffu + ((v.u >> 16) & 1u);   // RNE
  return (short)(r >> 16);
}
__device__ __forceinline__ float bf2f(short s) {
  union { unsigned u; float f; } v; v.u = ((unsigned)(unsigned short)s) << 16;
  return v.f;
}
__device__ __forceinline__ unsigned cvt_pk_bf16(float lo, float hi) {
  unsigned r;
  asm("v_cvt_pk_bf16_f32 %0, %1, %2" : "=v"(r) : "v"(lo), "v"(hi));
  return r;
}
__device__ __forceinline__ float exp2f_fast(float x) {
  return __builtin_amdgcn_exp2f(x);
}
// XOR-swizzled index into a [rows][64] bf16 LDS tile.
__device__ __forceinline__ int swz(int row, int col) {
  return row * 64 + ((((col >> 3) ^ row) & 7) << 3) + (col & 7);
}
// XOR-swizzled index into a [rows][256] bf16 LDS tile (per-64-col blocks).
__device__ __forceinline__ int a256(int row, int col) {
  return row * 256 + (col & ~63) + (((((col >> 3) & 7) ^ row) & 7) << 3);
}
// async global->LDS 16B copy; LDS dest must be wave-uniform (HW adds lane*16).
__device__ __forceinline__ void gload16(const short* gsrc, short* lds) {
  __builtin_amdgcn_global_load_lds(
      (const __attribute__((address_space(1))) unsigned int*)gsrc,
      (__attribute__((address_space(3))) unsigned int*)lds, 16, 0, 0);
}

// ---------------- workspace layout ----------------
// float region
constexpr size_t OFF_POSQ  = 0;                 // 900x256
constexpr size_t OFF_POSK  = 230400;
constexpr size_t OFF_POSV  = 460800;
constexpr size_t OFF_EMBQ  = 691200;            // 10x256 each
constexpr size_t OFF_EMBK  = 693760;
constexpr size_t OFF_EMBV  = 696320;
constexpr size_t OFF_WOOUT = 698880;            // 256x12  (wo@w_out)
constexpr size_t OFF_Q2    = 701952;            // 8x256   (step_q@wq)
constexpr size_t OFF_QP    = 704000;            // [32lh][900] f32
constexpr size_t OFF_QE    = OFF_QP + 28800;    // [32lh][16] f32
constexpr size_t OFF_WVO   = OFF_QE + 512;      // [4h][256][12] f32
constexpr size_t OFF_Q2K   = OFF_WVO + 12288;   // [32lh][256] bf16
constexpr size_t OFF_F32_END = 769536;
// short region
constexpr size_t SOFF_WOKVT = 0;                // [512][256]; Sp aliases after pre2
constexpr size_t SOFF_ATTN  = 131072;           // [28800][256] attnOut
constexpr size_t SOFF_KB    = 7503872;          // Kb; E/parts alias after attn
constexpr size_t SOFF_VT    = 14876672;         // [128 bh][15 kt][64d][64t]
constexpr size_t SOFF_E     = SOFF_KB;                 // [32b][32lh][960] bf16
constexpr size_t SOFF_UPART = SOFF_KB + 983040;        // [8][32b][32lh][256]
constexpr size_t SOFF_VPART = SOFF_UPART + 2097152;    // [8][32b][4h][64d][8l]

// ---------------------------------------------------------------------------
// k_pre: merged precompute. 262 blocks:
//   0..179: 64x64-tiled posQ/K/V = pos_emb @ [wq|wk|wv]
//   180..211: woK|woV = wo @ [wk|wv] -> bf16 transposed
//   212..261: tiny one-thread-per-output GEMMs (embQ/K/V, woOut, q2)
// ---------------------------------------------------------------------------
__global__ __launch_bounds__(256) void k_pre(const float* __restrict__ pos_emb,
                                             const float* __restrict__ embed,
                                             const float* __restrict__ wq,
                                             const float* __restrict__ wk,
                                             const float* __restrict__ wv,
                                             const float* __restrict__ wo,
                                             const float* __restrict__ step_q,
                                             const float* __restrict__ w_out,
                                             float* __restrict__ ws) {
  const int blk = blockIdx.x;
  const int tid = threadIdx.x;
  if (blk >= 212) {           // tiny jobs
    const int b2 = blk - 212;
    int job, base;
    if      (b2 < 10) { job = 0; base = b2; }
    else if (b2 < 20) { job = 1; base = b2 - 10; }
    else if (b2 < 30) { job = 2; base = b2 - 20; }
    else if (b2 < 42) { job = 3; base = b2 - 30; }
    else              { job = 4; base = b2 - 42; }
    const float* A; const float* Wm; float* C; int M; int N;
    switch (job) {
      case 0: A=embed;  Wm=wq;    C=ws+OFF_EMBQ;  M=10;  N=256; break;
      case 1: A=embed;  Wm=wk;    C=ws+OFF_EMBK;  M=10;  N=256; break;
      case 2: A=embed;  Wm=wv;    C=ws+OFF_EMBV;  M=10;  N=256; break;
      case 3: A=wo;     Wm=w_out; C=ws+OFF_WOOUT; M=256; N=12;  break;
      default:A=step_q; Wm=wq;    C=ws+OFF_Q2;    M=8;   N=256; break;
    }
    int idx = base * 256 + tid;
    if (idx >= M * N) return;
    int m = idx / N, n = idx - m * N;
    const float* a = A + (size_t)m * 256;
    float acc = 0.f;
    #pragma unroll 8
    for (int k = 0; k < 256; ++k) acc = fmaf(a[k], Wm[(size_t)k * N + n], acc);
    C[idx] = acc;
    return;
  }

  // 64x64-tiled GEMM jobs
  bool wojob; int mt, n0, base_n = 0;
  const float* A; const float* W; float* C = nullptr;
  if (blk < 180) {
    wojob = false; mt = blk % 15; int nt = blk / 15;
    A = pos_emb;
    W = nt < 4 ? wq : (nt < 8 ? wk : wv);
    C = ws + (nt < 4 ? OFF_POSQ : (nt < 8 ? OFF_POSK : OFF_POSV));
    n0 = (nt & 3) * 64;
  } else {
    wojob = true; int j = blk - 180; mt = j & 3; int nt2 = j >> 2;
    A = wo;
    W = nt2 < 4 ? wk : wv;
    base_n = nt2 < 4 ? 0 : 256;
    n0 = (nt2 & 3) * 64;
  }
  const int m0 = mt * 64;
  const int tr = tid >> 4, tc = tid & 15;
  __shared__ float As[64][68];
  __shared__ float Bs[64][68];
  float acc[4][4] = {};
  for (int kc = 0; kc < 4; ++kc) {
    __syncthreads();
    for (int i = tid; i < 1024; i += 256) {
      int row = i >> 4, c4 = (i & 15) * 4;
      int m = m0 + row; if (m > 899) m = 899;
      *(float4*)&As[row][c4] = *(const float4*)&A[(size_t)m * 256 + kc * 64 + c4];
      *(float4*)&Bs[row][c4] = *(const float4*)&W[(size_t)(kc * 64 + row) * 256 + n0 + c4];
    }
    __syncthreads();
    #pragma unroll 8
    for (int kk = 0; kk < 64; ++kk) {
      float a0 = As[4*tr+0][kk], a1 = As[4*tr+1][kk];
      float a2 = As[4*tr+2][kk], a3 = As[4*tr+3][kk];
      float4 b4 = *(const float4*)&Bs[kk][4*tc];
      acc[0][0]+=a0*b4.x; acc[0][1]+=a0*b4.y; acc[0][2]+=a0*b4.z; acc[0][3]+=a0*b4.w;
      acc[1][0]+=a1*b4.x; acc[1][1]+=a1*b4.y; acc[1][2]+=a1*b4.z; acc[1][3]+=a1*b4.w;
      acc[2][0]+=a2*b4.x; acc[2][1]+=a2*b4.y; acc[2][2]+=a2*b4.z; acc[2][3]+=a2*b4.w;
      acc[3][0]+=a3*b4.x; acc[3][1]+=a3*b4.y; acc[3][2]+=a3*b4.z; acc[3][3]+=a3*b4.w;
    }
  }
  if (!wojob) {
    #pragma unroll
    for (int i = 0; i < 4; ++i) {
      int m = m0 + 4 * tr + i;
      if (m < 900)
        *(float4*)&C[(size_t)m * 256 + n0 + 4 * tc] =
            make_float4(acc[i][0], acc[i][1], acc[i][2], acc[i][3]);
    }
  } else {
    __syncthreads();
    #pragma unroll
    for (int i = 0; i < 4; ++i)
      #pragma unroll
      for (int j = 0; j < 4; ++j)
        Bs[4 * tc + j][4 * tr + i] = acc[i][j];
    __syncthreads();
    short* wokvT = (short*)(ws + OFF_F32_END) + SOFF_WOKVT;
    for (int i = tid; i < 512; i += 256) {
      int row = i >> 3, ch = i & 7;
      union { short s[8]; bf16x8 v; } u;
      #pragma unroll
      for (int jj = 0; jj < 8; ++jj) u.s[jj] = f2bf(Bs[row][ch * 8 + jj]);
      *(bf16x8*)&wokvT[(size_t)(base_n + n0 + row) * 256 + m0 + ch * 8] = u.v;
    }
  }
}

// ---------------------------------------------------------------------------
// pre2: q2k[32][256] bf16, qp[32][900], qe[32][16], WVO[4][256][12]. 69 blocks.
// ---------------------------------------------------------------------------
__global__ __launch_bounds__(256) void k_pre2(float* __restrict__ ws) {
  const float* q2 = ws + OFF_Q2;
  const short* wokvT = (const short*)(ws + OFF_F32_END) + SOFF_WOKVT;
  const int blk = blockIdx.x, tid = threadIdx.x;
  if (blk < 32) {
    int lh = blk, h = lh >> 3, l = lh & 7;
    __shared__ float qs[64];
    if (tid < 64) qs[tid] = q2[l * 256 + h * 64 + tid];
    __syncthreads();
    float acc = 0.f;
    for (int dd = 0; dd < 64; ++dd)
      acc = fmaf(qs[dd], bf2f(wokvT[(size_t)(h * 64 + dd) * 256 + tid]), acc);
    ((short*)(ws + OFF_Q2K))[lh * 256 + tid] = f2bf(acc);
  } else if (blk < 64) {
    int lh = blk - 32, h = lh >> 3, l = lh & 7;
    __shared__ float qs[64];
    if (tid < 64) qs[tid] = q2[l * 256 + h * 64 + tid];
    __syncthreads();
    const float* posK = ws + OFF_POSK;
    for (int t = tid; t < 900; t += 256) {
      float acc = 0.f;
      const float* pr = posK + (size_t)t * 256 + h * 64;
      #pragma unroll 8
      for (int dd = 0; dd < 64; ++dd) acc = fmaf(qs[dd], pr[dd], acc);
      ws[OFF_QP + (size_t)lh * 900 + t] = acc;
    }
  } else if (blk == 64) {
    const float* embK = ws + OFF_EMBK;
    if (tid < 320) {
      int lh = tid / 10, c = tid - lh * 10;
      int h = lh >> 3, l = lh & 7;
      float acc = 0.f;
      const float* qrow = q2 + l * 256 + h * 64;
      const float* er = embK + (size_t)c * 256 + h * 64;
      for (int dd = 0; dd < 64; ++dd) acc = fmaf(qrow[dd], er[dd], acc);
      ws[OFF_QE + lh * 16 + c] = acc;
    }
  } else {
    int h = blk - 65;
    const float* woOut = ws + OFF_WOOUT;
    __shared__ float wos[64][12];
    for (int i = tid; i < 768; i += 256) wos[i / 12][i % 12] = woOut[(h * 64 + i / 12) * 12 + i % 12];
    __syncthreads();
    float acc[12] = {};
    for (int dd = 0; dd < 64; ++dd) {
      float v = bf2f(wokvT[(size_t)(256 + h * 64 + dd) * 256 + tid]);
      #pragma unroll
      for (int p = 0; p < 12; ++p) acc[p] = fmaf(v, wos[dd][p], acc[p]);
    }
    #pragma unroll
    for (int p = 0; p < 12; ++p)
      ws[OFF_WVO + ((size_t)h * 256 + tid) * 12 + p] = acc[p];
  }
}

// ---------------------------------------------------------------------------
// Materialize K (row-major bf16) and V^T (tiled bf16). Vectorized stores.
// ---------------------------------------------------------------------------
__global__ __launch_bounds__(256) void k_kv(const int* __restrict__ grid_in,
                                            const float* __restrict__ ws,
                                            short* __restrict__ Kb,
                                            short* __restrict__ VT) {
  const int kt = blockIdx.x, b = blockIdx.y;
  const int t0 = kt * 64, tid = threadIdx.x;
  const float* posK = ws + OFF_POSK;
  const float* embK = ws + OFF_EMBK;
  const float* posV = ws + OFF_POSV;
  const float* embV = ws + OFF_EMBV;

  for (int i = tid; i < 2048; i += 256) {
    int row = i >> 5, ch = i & 31;
    int t = t0 + row;
    if (t > 899) continue;
    int g = grid_in[b * 900 + t];
    const float* pk = posK + (size_t)t * 256 + ch * 8;
    const float* ek = embK + (size_t)g * 256 + ch * 8;
    float4 p0 = *(const float4*)pk, p1 = *(const float4*)(pk + 4);
    float4 e0 = *(const float4*)ek, e1 = *(const float4*)(ek + 4);
    union { short s[8]; bf16x8 v; } u;
    u.s[0] = f2bf(p0.x + e0.x); u.s[1] = f2bf(p0.y + e0.y);
    u.s[2] = f2bf(p0.z + e0.z); u.s[3] = f2bf(p0.w + e0.w);
    u.s[4] = f2bf(p1.x + e1.x); u.s[5] = f2bf(p1.y + e1.y);
    u.s[6] = f2bf(p1.z + e1.z); u.s[7] = f2bf(p1.w + e1.w);
    *(bf16x8*)&Kb[((size_t)(b * 900 + t)) * 256 + ch * 8] = u.v;
  }

  __shared__ float Lf[64 * 65];
  for (int h = 0; h < 4; ++h) {
    __syncthreads();
    for (int i = tid; i < 512; i += 256) {
      int row = i >> 3, ch = i & 7;
      int t = t0 + row; if (t > 899) t = 899;
      int g = grid_in[b * 900 + t];
      const float* pv = posV + (size_t)t * 256 + h * 64 + ch * 8;
      const float* ev = embV + (size_t)g * 256 + h * 64 + ch * 8;
      float4 p0 = *(const float4*)pv, p1 = *(const float4*)(pv + 4);
      float4 e0 = *(const float4*)ev, e1 = *(const float4*)(ev + 4);
      float* L = &Lf[row * 65 + ch * 8];
      L[0] = p0.x + e0.x; L[1] = p0.y + e0.y; L[2] = p0.z + e0.z; L[3] = p0.w + e0.w;
      L[4] = p1.x + e1.x; L[5] = p1.y + e1.y; L[6] = p1.z + e1.z; L[7] = p1.w + e1.w;
    }
    __syncthreads();
    short* tile = VT + ((size_t)((b * 4 + h) * 15 + kt)) * 4096;
    #pragma unroll
    for (int u = 0; u < 2; ++u) {
      int unit = u * 256 + tid;         // 0..511
      int d = unit >> 3;                // 0..63
      int t8 = (unit & 7) * 8;          // 0,8,...,56
      union { short s[8]; bf16x8 v; } p;
      #pragma unroll
      for (int i = 0; i < 8; ++i) p.s[i] = f2bf(Lf[(t8 + i) * 65 + d]);
      *(bf16x8*)&tile[d * 64 + t8] = p.v;
    }
  }
}

// ---------------------------------------------------------------------------
// Self-attention: swapped-QK^T, m=0 softmax (exp2 path), dbuf gload_lds.
// ---------------------------------------------------------------------------
__global__ __launch_bounds__(256) void k_attn(const int* __restrict__ grid_in,
                                              const float* __restrict__ ws,
                                              const short* __restrict__ Kb,
                                              const short* __restrict__ VT,
                                              short* __restrict__ attnOut) {
  const int bidx = blockIdx.x;
  const int bh = ((bidx >> 6) << 3) | (bidx & 7);
  const int qt = (bidx >> 3) & 7;
  const int h = bh & 3, b = bh >> 2;
  const int t0 = qt * 128, hc = h * 64;
  const int tid = threadIdx.x, w = tid >> 6, lane = tid & 63;
  const int g = lane >> 4, c16 = lane & 15;
  const size_t tileBase = (size_t)(bh * 15) * 4096;

  __shared__ __align__(16) short Ks[2][4096];
  __shared__ __align__(16) short Vs[2][4096];
  __shared__ __align__(16) short Ps[4096];

  const float* posQ = ws + OFF_POSQ;
  const float* embQ = ws + OFF_EMBQ;

  // Q fragments (scale 0.125*log2e folded -> exp2 softmax)
  bf16x8 aQ[2][2];
  #pragma unroll
  for (int s = 0; s < 2; ++s) {
    int t = t0 + s * 64 + w * 16 + c16; if (t > 899) t = 899;
    int gq = grid_in[b * 900 + t];
    #pragma unroll
    for (int kc = 0; kc < 2; ++kc) {
      union { short s8[8]; bf16x8 v; } u;
      #pragma unroll
      for (int j = 0; j < 8; ++j) {
        int d = hc + kc * 32 + g * 8 + j;
        u.s8[j] = f2bf(kScl * (embQ[gq * 256 + d] + posQ[(size_t)t * 256 + d]));
      }
      aQ[s][kc] = u.v;
    }
  }

#define STAGE(BUF, KT)                                                        \
  do {                                                                        \
    int kk0_ = (KT) * 64;                                                     \
    _Pragma("unroll")                                                         \
    for (int j_ = 0; j_ < 2; ++j_) {                                          \
      int c_ = j_ * 256 + w * 64 + lane;                                      \
      int row_ = c_ >> 3, ch_ = c_ & 7;                                       \
      int t_ = kk0_ + row_; if (t_ > 899) t_ = 899;                           \
      int sw_ = ((ch_ ^ row_) & 7) << 3;                                      \
      gload16(Kb + ((size_t)(b * 900 + t_)) * 256 + hc + sw_,                 \
              &Ks[BUF][(j_ * 256 + w * 64) << 3]);                            \
      gload16(VT + tileBase + (size_t)(KT) * 4096 + (row_ << 6) + sw_,        \
              &Vs[BUF][(j_ * 256 + w * 64) << 3]);                            \
    }                                                                         \
  } while (0)

  float l_[2] = {0.f, 0.f};
  f32x4 O[2][4];
  #pragma unroll
  for (int s = 0; s < 2; ++s)
    #pragma unroll
    for (int dt = 0; dt < 4; ++dt) { f32x4 z = {0.f,0.f,0.f,0.f}; O[s][dt] = z; }

  STAGE(0, 0);
  __syncthreads();

  int cur = 0;
  for (int kt = 0; kt < 15; ++kt) {
    if (kt + 1 < 15) STAGE(cur ^ 1, kt + 1);

    if (kt < 14) {
      f32x4 sacc[2][4];
      #pragma unroll
      for (int ct = 0; ct < 4; ++ct) {
        bf16x8 aK0 = *(bf16x8*)&Ks[cur][swz(ct * 16 + c16, g * 8)];
        bf16x8 aK1 = *(bf16x8*)&Ks[cur][swz(ct * 16 + c16, 32 + g * 8)];
        #pragma unroll
        for (int s = 0; s < 2; ++s) {
          f32x4 z = {0.f, 0.f, 0.f, 0.f};
          z = __builtin_amdgcn_mfma_f32_16x16x32_bf16(aK0, aQ[s][0], z, 0, 0, 0);
          z = __builtin_amdgcn_mfma_f32_16x16x32_bf16(aK1, aQ[s][1], z, 0, 0, 0);
          sacc[s][ct] = z;
        }
      }
      #pragma unroll
      for (int s = 0; s < 2; ++s) {
        float rs = 0.f;
        unsigned pk[4][2];
        #pragma unroll
        for (int ct = 0; ct < 4; ++ct) {
          float p0 = exp2f_fast(sacc[s][ct][0]);
          float p1 = exp2f_fast(sacc[s][ct][1]);
          float p2 = exp2f_fast(sacc[s][ct][2]);
          float p3 = exp2f_fast(sacc[s][ct][3]);
          rs += (p0 + p1) + (p2 + p3);
          pk[ct][0] = cvt_pk_bf16(p0, p1);
          pk[ct][1] = cvt_pk_bf16(p2, p3);
        }
        rs += __shfl_xor(rs, 16);
        rs += __shfl_xor(rs, 32);
        l_[s] += rs;
        #pragma unroll
        for (int ct = 0; ct < 4; ++ct)
          *(uint2*)&Ps[swz(w * 16 + c16, ct * 16 + 4 * g)] =
              make_uint2(pk[ct][0], pk[ct][1]);
        #pragma unroll
        for (int c = 0; c < 2; ++c) {
          bf16x8 aP = *(bf16x8*)&Ps[swz(w * 16 + c16, c * 32 + g * 8)];
          #pragma unroll
          for (int dt = 0; dt < 4; ++dt) {
            bf16x8 bV = *(bf16x8*)&Vs[cur][swz(dt * 16 + c16, c * 32 + g * 8)];
            O[s][dt] = __builtin_amdgcn_mfma_f32_16x16x32_bf16(aP, bV, O[s][dt], 0, 0, 0);
          }
        }
      }
    } else {
      bf16x8 aK0 = *(bf16x8*)&Ks[cur][swz(c16, g * 8)];
      bf16x8 aK1 = *(bf16x8*)&Ks[cur][swz(c16, 32 + g * 8)];
      #pragma unroll
      for (int s = 0; s < 2; ++s) {
        f32x4 z = {0.f, 0.f, 0.f, 0.f};
        z = __builtin_amdgcn_mfma_f32_16x16x32_bf16(aK0, aQ[s][0], z, 0, 0, 0);
        z = __builtin_amdgcn_mfma_f32_16x16x32_bf16(aK1, aQ[s][1], z, 0, 0, 0);
        float p0 = 0.f, p1 = 0.f, p2 = 0.f, p3 = 0.f;
        if (g == 0) {
          p0 = exp2f_fast(z[0]); p1 = exp2f_fast(z[1]);
          p2 = exp2f_fast(z[2]); p3 = exp2f_fast(z[3]);
        }
        float rs = (p0 + p1) + (p2 + p3);
        rs += __shfl_xor(rs, 16);
        rs += __shfl_xor(rs, 32);
        l_[s] += rs;
        *(uint2*)&Ps[swz(w * 16 + c16, 4 * g)] =
            make_uint2(cvt_pk_bf16(p0, p1), cvt_pk_bf16(p2, p3));
        *(uint2*)&Ps[swz(w * 16 + c16, 16 + 4 * g)] = make_uint2(0u, 0u);
        bf16x8 aP = *(bf16x8*)&Ps[swz(w * 16 + c16, g * 8)];
        #pragma unroll
        for (int dt = 0; dt < 4; ++dt) {
          bf16x8 bV = *(bf16x8*)&Vs[cur][swz(dt * 16 + c16, g * 8)];
          O[s][dt] = __builtin_amdgcn_mfma_f32_16x16x32_bf16(aP, bV, O[s][dt], 0, 0, 0);
        }
      }
    }

    __syncthreads();
    cur ^= 1;
  }
#undef STAGE

  #pragma unroll
  for (int s = 0; s < 2; ++s) {
    #pragma unroll
    for (int r = 0; r < 4; ++r) {
      float lq = __shfl(l_[s], (g << 4) | (4 * g + r));
      int t = t0 + s * 64 + w * 16 + 4 * g + r;
      if (t < 900) {
        float inv = 1.f / lq;
        #pragma unroll
        for (int dt = 0; dt < 4; ++dt)
          attnOut[((size_t)(b * 900 + t)) * 256 + hc + dt * 16 + c16] =
              f2bf(O[s][dt][r] * inv);
      }
    }
  }
}

// ---------------------------------------------------------------------------
// crossA: E[b][lh][t] = exp2(kScl*(qp+qe+attnOut.q2k)). Grid (15 kt, 32 b).
// ---------------------------------------------------------------------------
__global__ __launch_bounds__(256) void k_crossA(const int* __restrict__ grid_in,
                                                const float* __restrict__ ws,
                                                const short* __restrict__ attnOut,
                                                short* __restrict__ E,
                                                float* __restrict__ Sp) {
  const int kt = blockIdx.x, b = blockIdx.y;
  const int t0 = kt * 64;
  const int tid = threadIdx.x, w = tid >> 6, lane = tid & 63;
  const int g = lane >> 4, c16 = lane & 15;
  __shared__ __align__(16) short Aat[16384];   // [64][256] swz
  __shared__ __align__(16) short Qk[8192];     // [32][256] swz
  __shared__ float qpL[32 * 72];
  __shared__ float qeL[512];
  __shared__ int   gtl[64];
  __shared__ float spW[128];

  #pragma unroll
  for (int it = 0; it < 8; ++it) {
    int idx = it * 256 + w * 64 + lane;
    int row = idx >> 5, ch = idx & 31;
    int t = t0 + row; if (t > 899) t = 899;
    int sw = (((ch & 7) ^ row) & 7) << 3;
    gload16(attnOut + ((size_t)(b * 900 + t)) * 256 + (ch >> 3) * 64 + sw,
            &Aat[(it * 256 + w * 64) << 3]);
  }
  const short* q2k = (const short*)(ws + OFF_Q2K);
  #pragma unroll
  for (int it = 0; it < 4; ++it) {
    int idx = it * 256 + w * 64 + lane;
    int row = idx >> 5, ch = idx & 31;
    int sw = (((ch & 7) ^ row) & 7) << 3;
    gload16(q2k + (size_t)row * 256 + (ch >> 3) * 64 + sw,
            &Qk[(it * 256 + w * 64) << 3]);
  }
  #pragma unroll
  for (int it = 0; it < 2; ++it) {
    int idx = it * 256 + tid, row = idx >> 4, c4 = (idx & 15) * 4;
    *(float4*)&qpL[row * 72 + c4] = *(const float4*)&ws[OFF_QP + (size_t)row * 900 + t0 + c4];
  }
  for (int idx = tid; idx < 512; idx += 256) qeL[idx] = ws[OFF_QE + idx];
  if (tid < 64) { int t = t0 + tid; gtl[tid] = grid_in[b * 900 + (t > 899 ? 899 : t)]; }
  __syncthreads();

  f32x4 sacc[2];
  { f32x4 z = {0.f,0.f,0.f,0.f}; sacc[0] = z; sacc[1] = z; }
  #pragma unroll
  for (int kk = 0; kk < 8; ++kk) {
    bf16x8 aA = *(bf16x8*)&Aat[a256(w * 16 + c16, kk * 32 + g * 8)];
    bf16x8 b0 = *(bf16x8*)&Qk[a256(c16, kk * 32 + g * 8)];
    bf16x8 b1 = *(bf16x8*)&Qk[a256(16 + c16, kk * 32 + g * 8)];
    sacc[0] = __builtin_amdgcn_mfma_f32_16x16x32_bf16(aA, b0, sacc[0], 0, 0, 0);
    sacc[1] = __builtin_amdgcn_mfma_f32_16x16x32_bf16(aA, b1, sacc[1], 0, 0, 0);
  }
  #pragma unroll
  for (int ct = 0; ct < 2; ++ct) {
    int lh = ct * 16 + c16;
    float e[4]; float rs = 0.f;
    #pragma unroll
    for (int r = 0; r < 4; ++r) {
      int tl = w * 16 + g * 4 + r;
      float s = kScl * (sacc[ct][r] + qpL[lh * 72 + tl] + qeL[lh * 16 + gtl[tl]]);
      e[r] = (t0 + tl < 900) ? exp2f_fast(s) : 0.f;
      rs += e[r];
    }
    *(uint2*)&E[((size_t)(b * 32 + lh)) * 960 + t0 + w * 16 + g * 4] =
        make_uint2(cvt_pk_bf16(e[0], e[1]), cvt_pk_bf16(e[2], e[3]));
    rs += __shfl_xor(rs, 16);
    rs += __shfl_xor(rs, 32);
    if (g == 0) spW[w * 32 + lh] = rs;
  }
  __syncthreads();
  if (tid < 32)
    Sp[((size_t)b * 32 + tid) * 15 + kt] =
        spW[tid] + spW[32 + tid] + spW[64 + tid] + spW[96 + tid];
}

// ---------------------------------------------------------------------------
// crossP: Upart = E@attnOut, Vpart = E@V. Grid (8 ktg, 32 b).
// ---------------------------------------------------------------------------
__global__ __launch_bounds__(256) void k_crossP(const short* __restrict__ attnOut,
                                                const short* __restrict__ E,
                                                const short* __restrict__ VT,
                                                short* __restrict__ Upart,
                                                short* __restrict__ Vpart) {
  const int ktg = blockIdx.x, b = blockIdx.y;
  const int tid = threadIdx.x, w = tid >> 6, lane = tid & 63;
  const int g = lane >> 4, c16 = lane & 15;
  const int h = w, ctv = h >> 1;
  __shared__ __align__(16) short AT[256 * 72];
  __shared__ __align__(16) short Et[2048];
  __shared__ __align__(16) short VTl[16384];

  f32x4 Uacc[2][4], Vacc[4];
  { f32x4 z = {0.f,0.f,0.f,0.f};
    #pragma unroll
    for (int a = 0; a < 2; ++a)
      #pragma unroll
      for (int q = 0; q < 4; ++q) Uacc[a][q] = z;
    #pragma unroll
    for (int a = 0; a < 4; ++a) Vacc[a] = z; }

  const int ntile = (ktg < 7) ? 2 : 1;
  for (int tt = 0; tt < ntile; ++tt) {
    const int kt = ktg * 2 + tt, t0 = kt * 64;
    if (tt) __syncthreads();
    #pragma unroll
    for (int it = 0; it < 8; ++it) {
      int idx = it * 256 + tid;
      int tl = idx >> 5, jc = idx & 31;
      int t = t0 + tl; if (t > 899) t = 899;
      bf16x8 v = *(const bf16x8*)&attnOut[((size_t)(b * 900 + t)) * 256 + jc * 8];
      #pragma unroll
      for (int ii = 0; ii < 8; ++ii)
        AT[(jc * 8 + ii) * 72 + ((((tl >> 3) ^ jc) & 7) << 3) + (tl & 7)] = v[ii];
    }
    {
      int idx = w * 64 + lane;
      int row = idx >> 3, ch = idx & 7;
      int sw = ((ch ^ row) & 7) << 3;
      gload16(E + ((size_t)(b * 32 + row)) * 960 + t0 + sw, &Et[(w * 64) << 3]);
    }
    #pragma unroll
    for (int it = 0; it < 8; ++it) {
      int idx = it * 256 + w * 64 + lane;
      int hh = idx >> 9, rem = idx & 511;
      int row = rem >> 3, ch = rem & 7;
      int sw = ((ch ^ row) & 7) << 3;
      gload16(VT + ((size_t)((b * 4 + hh) * 15 + kt)) * 4096 + row * 64 + sw,
              &VTl[(it * 256 + w * 64) << 3]);
    }
    __syncthreads();
    #pragma unroll
    for (int kk = 0; kk < 2; ++kk) {
      bf16x8 aE0 = *(bf16x8*)&Et[swz(c16, kk * 32 + g * 8)];
      bf16x8 aE1 = *(bf16x8*)&Et[swz(16 + c16, kk * 32 + g * 8)];
      #pragma unroll
      for (int q = 0; q < 4; ++q) {
        int j = (w * 4 + q) * 16 + c16;
        int tch = kk * 4 + g;
        bf16x8 bA = *(bf16x8*)&AT[j * 72 + (((tch ^ (j >> 3)) & 7) << 3)];
        Uacc[0][q] = __builtin_amdgcn_mfma_f32_16x16x32_bf16(aE0, bA, Uacc[0][q], 0, 0, 0);
        Uacc[1][q] = __builtin_amdgcn_mfma_f32_16x16x32_bf16(aE1, bA, Uacc[1][q], 0, 0, 0);
      }
      bf16x8 bE = (ctv == 0) ? aE0 : aE1;
      #pragma unroll
      for (int rt = 0; rt < 4; ++rt) {
        bf16x8 aV = *(bf16x8*)&VTl[h * 4096 + swz(rt * 16 + c16, kk * 32 + g * 8)];
        Vacc[rt] = __builtin_amdgcn_mfma_f32_16x16x32_bf16(aV, bE, Vacc[rt], 0, 0, 0);
      }
    }
  }
  #pragma unroll
  for (int rt = 0; rt < 2; ++rt)
    #pragma unroll
    for (int q = 0; q < 4; ++q) {
      int j = (w * 4 + q) * 16 + c16;
      #pragma unroll
      for (int r = 0; r < 4; ++r) {
        int lh = rt * 16 + g * 4 + r;
        Upart[(((size_t)(ktg * 32 + b)) * 32 + lh) * 256 + j] = f2bf(Uacc[rt][q][r]);
      }
    }
  if ((c16 >> 3) == (h & 1)) {
    int l = c16 & 7;
    #pragma unroll
    for (int rt = 0; rt < 4; ++rt)
      #pragma unroll
      for (int r = 0; r < 4; ++r) {
        int d = rt * 16 + g * 4 + r;
        Vpart[((((size_t)(ktg * 32 + b)) * 4 + h) * 64 + d) * 8 + l] = f2bf(Vacc[rt][r]);
      }
  }
}

// ---------------------------------------------------------------------------
// crossR: reduce partials, emit logits. Grid 256 (b*8+l), 64 threads.
// ---------------------------------------------------------------------------
__global__ void k_crossR(const float* __restrict__ ws,
                         const float* __restrict__ b_out,
                         const short* __restrict__ Upart,
                         const short* __restrict__ Vpart,
                         const float* __restrict__ Sp,
                         float* __restrict__ out) {
  const int bl = blockIdx.x, b = bl >> 3, l = bl & 7;
  const int tid = threadIdx.x;
  __shared__ float Us[4][256];
  __shared__ float Vsm[4][64];
  __shared__ float Sinv[4];
  __shared__ float part[4][12];
  for (int h = 0; h < 4; ++h) {
    int lh = h * 8 + l;
    for (int j = tid; j < 256; j += 64) {
      float a = 0.f;
      #pragma unroll
      for (int kg = 0; kg < 8; ++kg)
        a += bf2f(Upart[(((size_t)(kg * 32 + b)) * 32 + lh) * 256 + j]);
      Us[h][j] = a;
    }
    float a = 0.f;
    #pragma unroll
    for (int kg = 0; kg < 8; ++kg)
      a += bf2f(Vpart[((((size_t)(kg * 32 + b)) * 4 + h) * 64 + tid) * 8 + l]);
    Vsm[h][tid] = a;
  }
  if (tid < 4) {
    int lh = tid * 8 + l;
    float s = 0.f;
    #pragma unroll
    for (int k = 0; k < 15; ++k) s += Sp[((size_t)b * 32 + lh) * 15 + k];
    Sinv[tid] = 1.f / s;
  }
  __syncthreads();
  if (tid < 48) {
    int h = tid / 12, p = tid % 12;
    const float* woOut = ws + OFF_WOOUT;
    const float* WVO = ws + OFF_WVO;
    float acc = 0.f;
    for (int dd = 0; dd < 64; ++dd)
      acc = fmaf(Vsm[h][dd], woOut[(h * 64 + dd) * 12 + p], acc);
    for (int j = 0; j < 256; ++j)
      acc = fmaf(Us[h][j], WVO[((size_t)h * 256 + j) * 12 + p], acc);
    part[h][p] = acc * Sinv[h];
  }
  __syncthreads();
  if (tid < 12)
    out[(size_t)bl * 12 + tid] =
        b_out[tid] + part[0][tid] + part[1][tid] + part[2][tid] + part[3][tid];
}

// ---------------------------------------------------------------------------
// Program executor (verified): flood fill, rotate 90 CW about anchor, paint.
// ---------------------------------------------------------------------------
__global__ void k_execute(const int* __restrict__ grid_in,
                          const int* __restrict__ anchor,
                          float* __restrict__ outg) {
  const int b = blockIdx.x;
  const int lane = threadIdx.x;
  const int* g = grid_in + b * 900;
  int ar = anchor[2 * b], ac = anchor[2 * b + 1];
  ar = min(max(ar, 0), 29); ac = min(max(ac, 0), 29);
  const int seed = g[ar * 30 + ac];

  unsigned same = 0u;
  if (lane < 30)
    for (int c = 0; c < 30; ++c) same |= (unsigned)(g[lane * 30 + c] == seed) << c;

  unsigned cur = (lane == ar) ? (1u << ac) : 0u;
  bool changed = true;
  while (changed) {
    unsigned up = __shfl(cur, (lane + 63) & 63);
    unsigned dn = __shfl(cur, (lane + 1) & 63);
    if (lane == 0) up = 0u;
    unsigned nm = (cur | (cur << 1) | (cur >> 1) | up | dn) & same;
    changed = __any(nm != cur);
    cur = nm;
  }

  __shared__ unsigned msh[32];
  if (lane < 32) msh[lane] = (lane < 30) ? cur : 0u;
  __syncthreads();

  if (lane < 30) {
    unsigned rot = 0u;
    int cc = lane - ar + ac;
    if (cc >= 0 && cc < 30) {
      for (int nc = 0; nc < 30; ++nc) {
        int rr = ar + ac - nc;
        if (rr >= 0 && rr < 30) rot |= ((msh[rr] >> cc) & 1u) << nc;
      }
    }
    for (int c = 0; c < 30; ++c) {
      int v = ((rot >> c) & 1u) ? 3 : g[lane * 30 + c];
      outg[b * 900 + lane * 30 + c] = (float)v;
    }
  }
}

// ---------------------------------------------------------------------------
extern "C" void kernel_launch(void* const* d_in, const int* in_sizes, int n_in,
                              void* d_out, int out_size, void* d_ws, size_t ws_size,
                              hipStream_t stream) {
  const int*   grid_in = (const int*)d_in[0];
  const int*   anchor  = (const int*)d_in[1];
  const float* embed   = (const float*)d_in[2];
  const float* pos_emb = (const float*)d_in[3];
  const float* wq      = (const float*)d_in[4];
  const float* wk      = (const float*)d_in[5];
  const float* wv      = (const float*)d_in[6];
  const float* wo      = (const float*)d_in[7];
  const float* step_q  = (const float*)d_in[8];
  const float* w_out   = (const float*)d_in[9];
  const float* b_out   = (const float*)d_in[10];
  float* out = (float*)d_out;
  float* ws  = (float*)d_ws;
  short* wsS = (short*)(ws + OFF_F32_END);

  k_pre<<<dim3(262), dim3(256), 0, stream>>>(pos_emb, embed, wq, wk, wv, wo,
                                             step_q, w_out, ws);
  k_pre2<<<dim3(69), dim3(256), 0, stream>>>(ws);
  k_kv<<<dim3(15, 32), dim3(256), 0, stream>>>(grid_in, ws,
                                               wsS + SOFF_KB, wsS + SOFF_VT);
  k_attn<<<dim3(1024), dim3(256), 0, stream>>>(grid_in, ws, wsS + SOFF_KB,
                                               wsS + SOFF_VT, wsS + SOFF_ATTN);
  short* E  = wsS + SOFF_E;
  float* Sp = (float*)(wsS + SOFF_WOKVT);
  k_crossA<<<dim3(15, 32), dim3(256), 0, stream>>>(grid_in, ws, wsS + SOFF_ATTN, E, Sp);
  k_crossP<<<dim3(8, 32), dim3(256), 0, stream>>>(wsS + SOFF_ATTN, E, wsS + SOFF_VT,
                                                  wsS + SOFF_UPART, wsS + SOFF_VPART);
  k_crossR<<<dim3(256), dim3(64), 0, stream>>>(ws, b_out, wsS + SOFF_UPART,
                                               wsS + SOFF_VPART, Sp, out);
  k_execute<<<dim3(32), dim3(64), 0, stream>>>(grid_in, anchor, out + 32 * 8 * 12);
}

// Round 10
// 210.998 us; speedup vs baseline: 5.2534x; 1.0738x over previous
//
#include <hip/hip_runtime.h>

// ===========================================================================
// ARPS forward. tok = embed[grid]+pos => projections distribute over gather.
// Cross-attention fully factored (no k2/v2):
//   score[b,h,l,t] = 0.125*(qp[lh][t] + qe[lh][g] + q2k[lh]·attnOut[b,t])
//   crossOut       = (1/S)(E@V + (E@attnOut)@woV); logits fold via WVO.
// Kernels (6 launches):
//   k_pre:    merged tiny GEMMs + tiled 64x64 GEMMs (posQ/K/V, woK/V^T bf16)
//   k_kvp:    K bf16 rows + V^T bf16 tiles (blocks 0..479) + pre2 jobs
//             (q2k, qp, qe, WVO; blocks 480..548)
//   k_attn:   flash self-attn, swapped-QK^T, m=0 softmax (exp2), dbuf,
//             double-P buffer w/ hoisted V reads, setprio on MFMA clusters
//   k_crossA: E = exp2(c*score) via MFMA + Sp partial sums
//   k_crossP: partial GEMMs Upart = E@attnOut, Vpart = E@V
//   k_tail:   crossR reduce+logits (blocks 0..255) + executor (256..287)
// ===========================================================================

typedef __attribute__((ext_vector_type(8))) short bf16x8;   // 8 bf16 (4 VGPR)
typedef __attribute__((ext_vector_type(4))) float f32x4;    // MFMA acc

constexpr float kScl = 0.18033688011112042f;   // 0.125 * log2(e)

__device__ __forceinline__ short f2bf(float f) {
  union { float f; unsigned u; } v; v.f = f;
  unsigned r = v.u + 0x7fffu + ((v.u >> 16) & 1u);   // RNE
  return (short)(r >> 16);
}
__device__ __forceinline__ float bf2f(short s) {
  union { unsigned u; float f; } v; v.u = ((unsigned)(unsigned short)s) << 16;
  return v.f;
}
__device__ __forceinline__ unsigned cvt_pk_bf16(float lo, float hi) {
  unsigned r;
  asm("v_cvt_pk_bf16_f32 %0, %1, %2" : "=v"(r) : "v"(lo), "v"(hi));
  return r;
}
__device__ __forceinline__ float exp2f_fast(float x) {
  return __builtin_amdgcn_exp2f(x);
}
// XOR-swizzled index into a [rows][64] bf16 LDS tile.
__device__ __forceinline__ int swz(int row, int col) {
  return row * 64 + ((((col >> 3) ^ row) & 7) << 3) + (col & 7);
}
// XOR-swizzled index into a [rows][256] bf16 LDS tile (per-64-col blocks).
__device__ __forceinline__ int a256(int row, int col) {
  return row * 256 + (col & ~63) + (((((col >> 3) & 7) ^ row) & 7) << 3);
}
// async global->LDS 16B copy; LDS dest must be wave-uniform (HW adds lane*16).
__device__ __forceinline__ void gload16(const short* gsrc, short* lds) {
  __builtin_amdgcn_global_load_lds(
      (const __attribute__((address_space(1))) unsigned int*)gsrc,
      (__attribute__((address_space(3))) unsigned int*)lds, 16, 0, 0);
}

// ---------------- workspace layout ----------------
// float region
constexpr size_t OFF_POSQ  = 0;                 // 900x256
constexpr size_t OFF_POSK  = 230400;
constexpr size_t OFF_POSV  = 460800;
constexpr size_t OFF_EMBQ  = 691200;            // 10x256 each
constexpr size_t OFF_EMBK  = 693760;
constexpr size_t OFF_EMBV  = 696320;
constexpr size_t OFF_WOOUT = 698880;            // 256x12  (wo@w_out)
constexpr size_t OFF_Q2    = 701952;            // 8x256   (step_q@wq)
constexpr size_t OFF_QP    = 704000;            // [32lh][900] f32
constexpr size_t OFF_QE    = OFF_QP + 28800;    // [32lh][16] f32
constexpr size_t OFF_WVO   = OFF_QE + 512;      // [4h][256][12] f32
constexpr size_t OFF_Q2K   = OFF_WVO + 12288;   // [32lh][256] bf16
constexpr size_t OFF_F32_END = 769536;
// short region
constexpr size_t SOFF_WOKVT = 0;                // [512][256]; Sp aliases after kvp
constexpr size_t SOFF_ATTN  = 131072;           // [28800][256] attnOut
constexpr size_t SOFF_KB    = 7503872;          // Kb; E/parts alias after attn
constexpr size_t SOFF_VT    = 14876672;         // [128 bh][15 kt][64d][64t]
constexpr size_t SOFF_E     = SOFF_KB;                 // [32b][32lh][960] bf16
constexpr size_t SOFF_UPART = SOFF_KB + 983040;        // [8][32b][32lh][256]
constexpr size_t SOFF_VPART = SOFF_UPART + 2097152;    // [8][32b][4h][64d][8l]

// ---------------------------------------------------------------------------
// k_pre: merged precompute. 262 blocks:
//   0..179: 64x64-tiled posQ/K/V = pos_emb @ [wq|wk|wv]
//   180..211: woK|woV = wo @ [wk|wv] -> bf16 transposed
//   212..261: tiny one-thread-per-output GEMMs (embQ/K/V, woOut, q2)
// ---------------------------------------------------------------------------
__global__ __launch_bounds__(256) void k_pre(const float* __restrict__ pos_emb,
                                             const float* __restrict__ embed,
                                             const float* __restrict__ wq,
                                             const float* __restrict__ wk,
                                             const float* __restrict__ wv,
                                             const float* __restrict__ wo,
                                             const float* __restrict__ step_q,
                                             const float* __restrict__ w_out,
                                             float* __restrict__ ws) {
  const int blk = blockIdx.x;
  const int tid = threadIdx.x;
  if (blk >= 212) {           // tiny jobs
    const int b2 = blk - 212;
    int job, base;
    if      (b2 < 10) { job = 0; base = b2; }
    else if (b2 < 20) { job = 1; base = b2 - 10; }
    else if (b2 < 30) { job = 2; base = b2 - 20; }
    else if (b2 < 42) { job = 3; base = b2 - 30; }
    else              { job = 4; base = b2 - 42; }
    const float* A; const float* Wm; float* C; int M; int N;
    switch (job) {
      case 0: A=embed;  Wm=wq;    C=ws+OFF_EMBQ;  M=10;  N=256; break;
      case 1: A=embed;  Wm=wk;    C=ws+OFF_EMBK;  M=10;  N=256; break;
      case 2: A=embed;  Wm=wv;    C=ws+OFF_EMBV;  M=10;  N=256; break;
      case 3: A=wo;     Wm=w_out; C=ws+OFF_WOOUT; M=256; N=12;  break;
      default:A=step_q; Wm=wq;    C=ws+OFF_Q2;    M=8;   N=256; break;
    }
    int idx = base * 256 + tid;
    if (idx >= M * N) return;
    int m = idx / N, n = idx - m * N;
    const float* a = A + (size_t)m * 256;
    float acc = 0.f;
    #pragma unroll 8
    for (int k = 0; k < 256; ++k) acc = fmaf(a[k], Wm[(size_t)k * N + n], acc);
    C[idx] = acc;
    return;
  }

  bool wojob; int mt, n0, base_n = 0;
  const float* A; const float* W; float* C = nullptr;
  if (blk < 180) {
    wojob = false; mt = blk % 15; int nt = blk / 15;
    A = pos_emb;
    W = nt < 4 ? wq : (nt < 8 ? wk : wv);
    C = ws + (nt < 4 ? OFF_POSQ : (nt < 8 ? OFF_POSK : OFF_POSV));
    n0 = (nt & 3) * 64;
  } else {
    wojob = true; int j = blk - 180; mt = j & 3; int nt2 = j >> 2;
    A = wo;
    W = nt2 < 4 ? wk : wv;
    base_n = nt2 < 4 ? 0 : 256;
    n0 = (nt2 & 3) * 64;
  }
  const int m0 = mt * 64;
  const int tr = tid >> 4, tc = tid & 15;
  __shared__ float As[64][68];
  __shared__ float Bs[64][68];
  float acc[4][4] = {};
  for (int kc = 0; kc < 4; ++kc) {
    __syncthreads();
    for (int i = tid; i < 1024; i += 256) {
      int row = i >> 4, c4 = (i & 15) * 4;
      int m = m0 + row; if (m > 899) m = 899;
      *(float4*)&As[row][c4] = *(const float4*)&A[(size_t)m * 256 + kc * 64 + c4];
      *(float4*)&Bs[row][c4] = *(const float4*)&W[(size_t)(kc * 64 + row) * 256 + n0 + c4];
    }
    __syncthreads();
    #pragma unroll 8
    for (int kk = 0; kk < 64; ++kk) {
      float a0 = As[4*tr+0][kk], a1 = As[4*tr+1][kk];
      float a2 = As[4*tr+2][kk], a3 = As[4*tr+3][kk];
      float4 b4 = *(const float4*)&Bs[kk][4*tc];
      acc[0][0]+=a0*b4.x; acc[0][1]+=a0*b4.y; acc[0][2]+=a0*b4.z; acc[0][3]+=a0*b4.w;
      acc[1][0]+=a1*b4.x; acc[1][1]+=a1*b4.y; acc[1][2]+=a1*b4.z; acc[1][3]+=a1*b4.w;
      acc[2][0]+=a2*b4.x; acc[2][1]+=a2*b4.y; acc[2][2]+=a2*b4.z; acc[2][3]+=a2*b4.w;
      acc[3][0]+=a3*b4.x; acc[3][1]+=a3*b4.y; acc[3][2]+=a3*b4.z; acc[3][3]+=a3*b4.w;
    }
  }
  if (!wojob) {
    #pragma unroll
    for (int i = 0; i < 4; ++i) {
      int m = m0 + 4 * tr + i;
      if (m < 900)
        *(float4*)&C[(size_t)m * 256 + n0 + 4 * tc] =
            make_float4(acc[i][0], acc[i][1], acc[i][2], acc[i][3]);
    }
  } else {
    __syncthreads();
    #pragma unroll
    for (int i = 0; i < 4; ++i)
      #pragma unroll
      for (int j = 0; j < 4; ++j)
        Bs[4 * tc + j][4 * tr + i] = acc[i][j];
    __syncthreads();
    short* wokvT = (short*)(ws + OFF_F32_END) + SOFF_WOKVT;
    for (int i = tid; i < 512; i += 256) {
      int row = i >> 3, ch = i & 7;
      union { short s[8]; bf16x8 v; } u;
      #pragma unroll
      for (int jj = 0; jj < 8; ++jj) u.s[jj] = f2bf(Bs[row][ch * 8 + jj]);
      *(bf16x8*)&wokvT[(size_t)(base_n + n0 + row) * 256 + m0 + ch * 8] = u.v;
    }
  }
}

// ---------------------------------------------------------------------------
// k_kvp: blocks 0..479 materialize K bf16 rows + V^T bf16 tiles;
//        blocks 480..548 run the pre2 jobs (q2k, qp, qe, WVO).
// ---------------------------------------------------------------------------
__global__ __launch_bounds__(256) void k_kvp(const int* __restrict__ grid_in,
                                             float* __restrict__ ws,
                                             short* __restrict__ Kb,
                                             short* __restrict__ VT) {
  const int blk = blockIdx.x, tid = threadIdx.x;
  __shared__ float Lf[64 * 65];

  if (blk >= 480) {   // ---- pre2 jobs ----
    const int b2 = blk - 480;
    const float* q2 = ws + OFF_Q2;
    const short* wokvT = (const short*)(ws + OFF_F32_END) + SOFF_WOKVT;
    if (b2 < 32) {
      int lh = b2, h = lh >> 3, l = lh & 7;
      float* qs = Lf;
      if (tid < 64) qs[tid] = q2[l * 256 + h * 64 + tid];
      __syncthreads();
      float acc = 0.f;
      for (int dd = 0; dd < 64; ++dd)
        acc = fmaf(qs[dd], bf2f(wokvT[(size_t)(h * 64 + dd) * 256 + tid]), acc);
      ((short*)(ws + OFF_Q2K))[lh * 256 + tid] = f2bf(acc);
    } else if (b2 < 64) {
      int lh = b2 - 32, h = lh >> 3, l = lh & 7;
      float* qs = Lf;
      if (tid < 64) qs[tid] = q2[l * 256 + h * 64 + tid];
      __syncthreads();
      const float* posK = ws + OFF_POSK;
      for (int t = tid; t < 900; t += 256) {
        float acc = 0.f;
        const float* pr = posK + (size_t)t * 256 + h * 64;
        #pragma unroll 8
        for (int dd = 0; dd < 64; ++dd) acc = fmaf(qs[dd], pr[dd], acc);
        ws[OFF_QP + (size_t)lh * 900 + t] = acc;
      }
    } else if (b2 == 64) {
      const float* embK = ws + OFF_EMBK;
      if (tid < 320) {
        int lh = tid / 10, c = tid - lh * 10;
        int h = lh >> 3, l = lh & 7;
        float acc = 0.f;
        const float* qrow = q2 + l * 256 + h * 64;
        const float* er = embK + (size_t)c * 256 + h * 64;
        for (int dd = 0; dd < 64; ++dd) acc = fmaf(qrow[dd], er[dd], acc);
        ws[OFF_QE + lh * 16 + c] = acc;
      }
    } else {
      int h = b2 - 65;
      const float* woOut = ws + OFF_WOOUT;
      float (*wos)[12] = (float(*)[12])Lf;
      for (int i = tid; i < 768; i += 256)
        wos[i / 12][i % 12] = woOut[(h * 64 + i / 12) * 12 + i % 12];
      __syncthreads();
      float acc[12] = {};
      for (int dd = 0; dd < 64; ++dd) {
        float v = bf2f(wokvT[(size_t)(256 + h * 64 + dd) * 256 + tid]);
        #pragma unroll
        for (int p = 0; p < 12; ++p) acc[p] = fmaf(v, wos[dd][p], acc[p]);
      }
      #pragma unroll
      for (int p = 0; p < 12; ++p)
        ws[OFF_WVO + ((size_t)h * 256 + tid) * 12 + p] = acc[p];
    }
    return;
  }

  // ---- kv job ----
  const int kt = blk % 15, b = blk / 15;
  const int t0 = kt * 64;
  const float* posK = ws + OFF_POSK;
  const float* embK = ws + OFF_EMBK;
  const float* posV = ws + OFF_POSV;
  const float* embV = ws + OFF_EMBV;

  for (int i = tid; i < 2048; i += 256) {
    int row = i >> 5, ch = i & 31;
    int t = t0 + row;
    if (t > 899) continue;
    int g = grid_in[b * 900 + t];
    const float* pk = posK + (size_t)t * 256 + ch * 8;
    const float* ek = embK + (size_t)g * 256 + ch * 8;
    float4 p0 = *(const float4*)pk, p1 = *(const float4*)(pk + 4);
    float4 e0 = *(const float4*)ek, e1 = *(const float4*)(ek + 4);
    union { short s[8]; bf16x8 v; } u;
    u.s[0] = f2bf(p0.x + e0.x); u.s[1] = f2bf(p0.y + e0.y);
    u.s[2] = f2bf(p0.z + e0.z); u.s[3] = f2bf(p0.w + e0.w);
    u.s[4] = f2bf(p1.x + e1.x); u.s[5] = f2bf(p1.y + e1.y);
    u.s[6] = f2bf(p1.z + e1.z); u.s[7] = f2bf(p1.w + e1.w);
    *(bf16x8*)&Kb[((size_t)(b * 900 + t)) * 256 + ch * 8] = u.v;
  }

  for (int h = 0; h < 4; ++h) {
    __syncthreads();
    for (int i = tid; i < 512; i += 256) {
      int row = i >> 3, ch = i & 7;
      int t = t0 + row; if (t > 899) t = 899;
      int g = grid_in[b * 900 + t];
      const float* pv = posV + (size_t)t * 256 + h * 64 + ch * 8;
      const float* ev = embV + (size_t)g * 256 + h * 64 + ch * 8;
      float4 p0 = *(const float4*)pv, p1 = *(const float4*)(pv + 4);
      float4 e0 = *(const float4*)ev, e1 = *(const float4*)(ev + 4);
      float* L = &Lf[row * 65 + ch * 8];
      L[0] = p0.x + e0.x; L[1] = p0.y + e0.y; L[2] = p0.z + e0.z; L[3] = p0.w + e0.w;
      L[4] = p1.x + e1.x; L[5] = p1.y + e1.y; L[6] = p1.z + e1.z; L[7] = p1.w + e1.w;
    }
    __syncthreads();
    short* tile = VT + ((size_t)((b * 4 + h) * 15 + kt)) * 4096;
    #pragma unroll
    for (int u = 0; u < 2; ++u) {
      int unit = u * 256 + tid;
      int d = unit >> 3;
      int t8 = (unit & 7) * 8;
      union { short s[8]; bf16x8 v; } p;
      #pragma unroll
      for (int i = 0; i < 8; ++i) p.s[i] = f2bf(Lf[(t8 + i) * 65 + d]);
      *(bf16x8*)&tile[d * 64 + t8] = p.v;
    }
  }
}

// ---------------------------------------------------------------------------
// Self-attention: swapped-QK^T, m=0 softmax (exp2), dbuf gload_lds,
// DOUBLE P buffer -> V fragments read once per tile (not per subtile).
// ---------------------------------------------------------------------------
__global__ __launch_bounds__(256) void k_attn(const int* __restrict__ grid_in,
                                              const float* __restrict__ ws,
                                              const short* __restrict__ Kb,
                                              const short* __restrict__ VT,
                                              short* __restrict__ attnOut) {
  const int bidx = blockIdx.x;
  const int bh = ((bidx >> 6) << 3) | (bidx & 7);
  const int qt = (bidx >> 3) & 7;
  const int h = bh & 3, b = bh >> 2;
  const int t0 = qt * 128, hc = h * 64;
  const int tid = threadIdx.x, w = tid >> 6, lane = tid & 63;
  const int g = lane >> 4, c16 = lane & 15;
  const size_t tileBase = (size_t)(bh * 15) * 4096;

  __shared__ __align__(16) short Ks[2][4096];
  __shared__ __align__(16) short Vs[2][4096];
  __shared__ __align__(16) short Ps[2][4096];   // one per q-subtile

  const float* posQ = ws + OFF_POSQ;
  const float* embQ = ws + OFF_EMBQ;

  bf16x8 aQ[2][2];
  #pragma unroll
  for (int s = 0; s < 2; ++s) {
    int t = t0 + s * 64 + w * 16 + c16; if (t > 899) t = 899;
    int gq = grid_in[b * 900 + t];
    #pragma unroll
    for (int kc = 0; kc < 2; ++kc) {
      union { short s8[8]; bf16x8 v; } u;
      #pragma unroll
      for (int j = 0; j < 8; ++j) {
        int d = hc + kc * 32 + g * 8 + j;
        u.s8[j] = f2bf(kScl * (embQ[gq * 256 + d] + posQ[(size_t)t * 256 + d]));
      }
      aQ[s][kc] = u.v;
    }
  }

#define STAGE(BUF, KT)                                                        \
  do {                                                                        \
    int kk0_ = (KT) * 64;                                                     \
    _Pragma("unroll")                                                         \
    for (int j_ = 0; j_ < 2; ++j_) {                                          \
      int c_ = j_ * 256 + w * 64 + lane;                                      \
      int row_ = c_ >> 3, ch_ = c_ & 7;                                       \
      int t_ = kk0_ + row_; if (t_ > 899) t_ = 899;                           \
      int sw_ = ((ch_ ^ row_) & 7) << 3;                                      \
      gload16(Kb + ((size_t)(b * 900 + t_)) * 256 + hc + sw_,                 \
              &Ks[BUF][(j_ * 256 + w * 64) << 3]);                            \
      gload16(VT + tileBase + (size_t)(KT) * 4096 + (row_ << 6) + sw_,        \
              &Vs[BUF][(j_ * 256 + w * 64) << 3]);                            \
    }                                                                         \
  } while (0)

  float l_[2] = {0.f, 0.f};
  f32x4 O[2][4];
  #pragma unroll
  for (int s = 0; s < 2; ++s)
    #pragma unroll
    for (int dt = 0; dt < 4; ++dt) { f32x4 z = {0.f,0.f,0.f,0.f}; O[s][dt] = z; }

  STAGE(0, 0);
  __syncthreads();

  int cur = 0;
  for (int kt = 0; kt < 15; ++kt) {
    if (kt + 1 < 15) STAGE(cur ^ 1, kt + 1);

    if (kt < 14) {
      f32x4 sacc[2][4];
      __builtin_amdgcn_s_setprio(1);
      #pragma unroll
      for (int ct = 0; ct < 4; ++ct) {
        bf16x8 aK0 = *(bf16x8*)&Ks[cur][swz(ct * 16 + c16, g * 8)];
        bf16x8 aK1 = *(bf16x8*)&Ks[cur][swz(ct * 16 + c16, 32 + g * 8)];
        #pragma unroll
        for (int s = 0; s < 2; ++s) {
          f32x4 z = {0.f, 0.f, 0.f, 0.f};
          z = __builtin_amdgcn_mfma_f32_16x16x32_bf16(aK0, aQ[s][0], z, 0, 0, 0);
          z = __builtin_amdgcn_mfma_f32_16x16x32_bf16(aK1, aQ[s][1], z, 0, 0, 0);
          sacc[s][ct] = z;
        }
      }
      __builtin_amdgcn_s_setprio(0);
      #pragma unroll
      for (int s = 0; s < 2; ++s) {
        float rs = 0.f;
        unsigned pk[4][2];
        #pragma unroll
        for (int ct = 0; ct < 4; ++ct) {
          float p0 = exp2f_fast(sacc[s][ct][0]);
          float p1 = exp2f_fast(sacc[s][ct][1]);
          float p2 = exp2f_fast(sacc[s][ct][2]);
          float p3 = exp2f_fast(sacc[s][ct][3]);
          rs += (p0 + p1) + (p2 + p3);
          pk[ct][0] = cvt_pk_bf16(p0, p1);
          pk[ct][1] = cvt_pk_bf16(p2, p3);
        }
        rs += __shfl_xor(rs, 16);
        rs += __shfl_xor(rs, 32);
        l_[s] += rs;
        #pragma unroll
        for (int ct = 0; ct < 4; ++ct)
          *(uint2*)&Ps[s][swz(w * 16 + c16, ct * 16 + 4 * g)] =
              make_uint2(pk[ct][0], pk[ct][1]);
      }
      // ---- PV with V fragments read once (shared by both subtiles) ----
      __builtin_amdgcn_s_setprio(1);
      #pragma unroll
      for (int c = 0; c < 2; ++c) {
        bf16x8 aP0 = *(bf16x8*)&Ps[0][swz(w * 16 + c16, c * 32 + g * 8)];
        bf16x8 aP1 = *(bf16x8*)&Ps[1][swz(w * 16 + c16, c * 32 + g * 8)];
        #pragma unroll
        for (int dt = 0; dt < 4; ++dt) {
          bf16x8 bV = *(bf16x8*)&Vs[cur][swz(dt * 16 + c16, c * 32 + g * 8)];
          O[0][dt] = __builtin_amdgcn_mfma_f32_16x16x32_bf16(aP0, bV, O[0][dt], 0, 0, 0);
          O[1][dt] = __builtin_amdgcn_mfma_f32_16x16x32_bf16(aP1, bV, O[1][dt], 0, 0, 0);
        }
      }
      __builtin_amdgcn_s_setprio(0);
    } else {
      bf16x8 aK0 = *(bf16x8*)&Ks[cur][swz(c16, g * 8)];
      bf16x8 aK1 = *(bf16x8*)&Ks[cur][swz(c16, 32 + g * 8)];
      #pragma unroll
      for (int s = 0; s < 2; ++s) {
        f32x4 z = {0.f, 0.f, 0.f, 0.f};
        z = __builtin_amdgcn_mfma_f32_16x16x32_bf16(aK0, aQ[s][0], z, 0, 0, 0);
        z = __builtin_amdgcn_mfma_f32_16x16x32_bf16(aK1, aQ[s][1], z, 0, 0, 0);
        float p0 = 0.f, p1 = 0.f, p2 = 0.f, p3 = 0.f;
        if (g == 0) {
          p0 = exp2f_fast(z[0]); p1 = exp2f_fast(z[1]);
          p2 = exp2f_fast(z[2]); p3 = exp2f_fast(z[3]);
        }
        float rs = (p0 + p1) + (p2 + p3);
        rs += __shfl_xor(rs, 16);
        rs += __shfl_xor(rs, 32);
        l_[s] += rs;
        *(uint2*)&Ps[s][swz(w * 16 + c16, 4 * g)] =
            make_uint2(cvt_pk_bf16(p0, p1), cvt_pk_bf16(p2, p3));
        *(uint2*)&Ps[s][swz(w * 16 + c16, 16 + 4 * g)] = make_uint2(0u, 0u);
      }
      bf16x8 aP0 = *(bf16x8*)&Ps[0][swz(w * 16 + c16, g * 8)];
      bf16x8 aP1 = *(bf16x8*)&Ps[1][swz(w * 16 + c16, g * 8)];
      #pragma unroll
      for (int dt = 0; dt < 4; ++dt) {
        bf16x8 bV = *(bf16x8*)&Vs[cur][swz(dt * 16 + c16, g * 8)];
        O[0][dt] = __builtin_amdgcn_mfma_f32_16x16x32_bf16(aP0, bV, O[0][dt], 0, 0, 0);
        O[1][dt] = __builtin_amdgcn_mfma_f32_16x16x32_bf16(aP1, bV, O[1][dt], 0, 0, 0);
      }
    }

    __syncthreads();
    cur ^= 1;
  }
#undef STAGE

  #pragma unroll
  for (int s = 0; s < 2; ++s) {
    #pragma unroll
    for (int r = 0; r < 4; ++r) {
      float lq = __shfl(l_[s], (g << 4) | (4 * g + r));
      int t = t0 + s * 64 + w * 16 + 4 * g + r;
      if (t < 900) {
        float inv = 1.f / lq;
        #pragma unroll
        for (int dt = 0; dt < 4; ++dt)
          attnOut[((size_t)(b * 900 + t)) * 256 + hc + dt * 16 + c16] =
              f2bf(O[s][dt][r] * inv);
      }
    }
  }
}

// ---------------------------------------------------------------------------
// crossA: E[b][lh][t] = exp2(kScl*(qp+qe+attnOut.q2k)). Grid (15 kt, 32 b).
// ---------------------------------------------------------------------------
__global__ __launch_bounds__(256) void k_crossA(const int* __restrict__ grid_in,
                                                const float* __restrict__ ws,
                                                const short* __restrict__ attnOut,
                                                short* __restrict__ E,
                                                float* __restrict__ Sp) {
  const int kt = blockIdx.x, b = blockIdx.y;
  const int t0 = kt * 64;
  const int tid = threadIdx.x, w = tid >> 6, lane = tid & 63;
  const int g = lane >> 4, c16 = lane & 15;
  __shared__ __align__(16) short Aat[16384];   // [64][256] swz
  __shared__ __align__(16) short Qk[8192];     // [32][256] swz
  __shared__ float qpL[32 * 72];
  __shared__ float qeL[512];
  __shared__ int   gtl[64];
  __shared__ float spW[128];

  #pragma unroll
  for (int it = 0; it < 8; ++it) {
    int idx = it * 256 + w * 64 + lane;
    int row = idx >> 5, ch = idx & 31;
    int t = t0 + row; if (t > 899) t = 899;
    int sw = (((ch & 7) ^ row) & 7) << 3;
    gload16(attnOut + ((size_t)(b * 900 + t)) * 256 + (ch >> 3) * 64 + sw,
            &Aat[(it * 256 + w * 64) << 3]);
  }
  const short* q2k = (const short*)(ws + OFF_Q2K);
  #pragma unroll
  for (int it = 0; it < 4; ++it) {
    int idx = it * 256 + w * 64 + lane;
    int row = idx >> 5, ch = idx & 31;
    int sw = (((ch & 7) ^ row) & 7) << 3;
    gload16(q2k + (size_t)row * 256 + (ch >> 3) * 64 + sw,
            &Qk[(it * 256 + w * 64) << 3]);
  }
  #pragma unroll
  for (int it = 0; it < 2; ++it) {
    int idx = it * 256 + tid, row = idx >> 4, c4 = (idx & 15) * 4;
    *(float4*)&qpL[row * 72 + c4] = *(const float4*)&ws[OFF_QP + (size_t)row * 900 + t0 + c4];
  }
  for (int idx = tid; idx < 512; idx += 256) qeL[idx] = ws[OFF_QE + idx];
  if (tid < 64) { int t = t0 + tid; gtl[tid] = grid_in[b * 900 + (t > 899 ? 899 : t)]; }
  __syncthreads();

  f32x4 sacc[2];
  { f32x4 z = {0.f,0.f,0.f,0.f}; sacc[0] = z; sacc[1] = z; }
  #pragma unroll
  for (int kk = 0; kk < 8; ++kk) {
    bf16x8 aA = *(bf16x8*)&Aat[a256(w * 16 + c16, kk * 32 + g * 8)];
    bf16x8 b0 = *(bf16x8*)&Qk[a256(c16, kk * 32 + g * 8)];
    bf16x8 b1 = *(bf16x8*)&Qk[a256(16 + c16, kk * 32 + g * 8)];
    sacc[0] = __builtin_amdgcn_mfma_f32_16x16x32_bf16(aA, b0, sacc[0], 0, 0, 0);
    sacc[1] = __builtin_amdgcn_mfma_f32_16x16x32_bf16(aA, b1, sacc[1], 0, 0, 0);
  }
  #pragma unroll
  for (int ct = 0; ct < 2; ++ct) {
    int lh = ct * 16 + c16;
    float e[4]; float rs = 0.f;
    #pragma unroll
    for (int r = 0; r < 4; ++r) {
      int tl = w * 16 + g * 4 + r;
      float s = kScl * (sacc[ct][r] + qpL[lh * 72 + tl] + qeL[lh * 16 + gtl[tl]]);
      e[r] = (t0 + tl < 900) ? exp2f_fast(s) : 0.f;
      rs += e[r];
    }
    *(uint2*)&E[((size_t)(b * 32 + lh)) * 960 + t0 + w * 16 + g * 4] =
        make_uint2(cvt_pk_bf16(e[0], e[1]), cvt_pk_bf16(e[2], e[3]));
    rs += __shfl_xor(rs, 16);
    rs += __shfl_xor(rs, 32);
    if (g == 0) spW[w * 32 + lh] = rs;
  }
  __syncthreads();
  if (tid < 32)
    Sp[((size_t)b * 32 + tid) * 15 + kt] =
        spW[tid] + spW[32 + tid] + spW[64 + tid] + spW[96 + tid];
}

// ---------------------------------------------------------------------------
// crossP: Upart = E@attnOut, Vpart = E@V. Grid (8 ktg, 32 b).
// ---------------------------------------------------------------------------
__global__ __launch_bounds__(256) void k_crossP(const short* __restrict__ attnOut,
                                                const short* __restrict__ E,
                                                const short* __restrict__ VT,
                                                short* __restrict__ Upart,
                                                short* __restrict__ Vpart) {
  const int ktg = blockIdx.x, b = blockIdx.y;
  const int tid = threadIdx.x, w = tid >> 6, lane = tid & 63;
  const int g = lane >> 4, c16 = lane & 15;
  const int h = w, ctv = h >> 1;
  __shared__ __align__(16) short AT[256 * 72];
  __shared__ __align__(16) short Et[2048];
  __shared__ __align__(16) short VTl[16384];

  f32x4 Uacc[2][4], Vacc[4];
  { f32x4 z = {0.f,0.f,0.f,0.f};
    #pragma unroll
    for (int a = 0; a < 2; ++a)
      #pragma unroll
      for (int q = 0; q < 4; ++q) Uacc[a][q] = z;
    #pragma unroll
    for (int a = 0; a < 4; ++a) Vacc[a] = z; }

  const int ntile = (ktg < 7) ? 2 : 1;
  for (int tt = 0; tt < ntile; ++tt) {
    const int kt = ktg * 2 + tt, t0 = kt * 64;
    if (tt) __syncthreads();
    #pragma unroll
    for (int it = 0; it < 8; ++it) {
      int idx = it * 256 + tid;
      int tl = idx >> 5, jc = idx & 31;
      int t = t0 + tl; if (t > 899) t = 899;
      bf16x8 v = *(const bf16x8*)&attnOut[((size_t)(b * 900 + t)) * 256 + jc * 8];
      #pragma unroll
      for (int ii = 0; ii < 8; ++ii)
        AT[(jc * 8 + ii) * 72 + ((((tl >> 3) ^ jc) & 7) << 3) + (tl & 7)] = v[ii];
    }
    {
      int idx = w * 64 + lane;
      int row = idx >> 3, ch = idx & 7;
      int sw = ((ch ^ row) & 7) << 3;
      gload16(E + ((size_t)(b * 32 + row)) * 960 + t0 + sw, &Et[(w * 64) << 3]);
    }
    #pragma unroll
    for (int it = 0; it < 8; ++it) {
      int idx = it * 256 + w * 64 + lane;
      int hh = idx >> 9, rem = idx & 511;
      int row = rem >> 3, ch = rem & 7;
      int sw = ((ch ^ row) & 7) << 3;
      gload16(VT + ((size_t)((b * 4 + hh) * 15 + kt)) * 4096 + row * 64 + sw,
              &VTl[(it * 256 + w * 64) << 3]);
    }
    __syncthreads();
    #pragma unroll
    for (int kk = 0; kk < 2; ++kk) {
      bf16x8 aE0 = *(bf16x8*)&Et[swz(c16, kk * 32 + g * 8)];
      bf16x8 aE1 = *(bf16x8*)&Et[swz(16 + c16, kk * 32 + g * 8)];
      #pragma unroll
      for (int q = 0; q < 4; ++q) {
        int j = (w * 4 + q) * 16 + c16;
        int tch = kk * 4 + g;
        bf16x8 bA = *(bf16x8*)&AT[j * 72 + (((tch ^ (j >> 3)) & 7) << 3)];
        Uacc[0][q] = __builtin_amdgcn_mfma_f32_16x16x32_bf16(aE0, bA, Uacc[0][q], 0, 0, 0);
        Uacc[1][q] = __builtin_amdgcn_mfma_f32_16x16x32_bf16(aE1, bA, Uacc[1][q], 0, 0, 0);
      }
      bf16x8 bE = (ctv == 0) ? aE0 : aE1;
      #pragma unroll
      for (int rt = 0; rt < 4; ++rt) {
        bf16x8 aV = *(bf16x8*)&VTl[h * 4096 + swz(rt * 16 + c16, kk * 32 + g * 8)];
        Vacc[rt] = __builtin_amdgcn_mfma_f32_16x16x32_bf16(aV, bE, Vacc[rt], 0, 0, 0);
      }
    }
  }
  #pragma unroll
  for (int rt = 0; rt < 2; ++rt)
    #pragma unroll
    for (int q = 0; q < 4; ++q) {
      int j = (w * 4 + q) * 16 + c16;
      #pragma unroll
      for (int r = 0; r < 4; ++r) {
        int lh = rt * 16 + g * 4 + r;
        Upart[(((size_t)(ktg * 32 + b)) * 32 + lh) * 256 + j] = f2bf(Uacc[rt][q][r]);
      }
    }
  if ((c16 >> 3) == (h & 1)) {
    int l = c16 & 7;
    #pragma unroll
    for (int rt = 0; rt < 4; ++rt)
      #pragma unroll
      for (int r = 0; r < 4; ++r) {
        int d = rt * 16 + g * 4 + r;
        Vpart[((((size_t)(ktg * 32 + b)) * 4 + h) * 64 + d) * 8 + l] = f2bf(Vacc[rt][r]);
      }
  }
}

// ---------------------------------------------------------------------------
// k_tail: blocks 0..255 = crossR (reduce partials, emit logits);
//         blocks 256..287 = program executor. 64 threads each.
// ---------------------------------------------------------------------------
__global__ void k_tail(const float* __restrict__ ws,
                       const float* __restrict__ b_out,
                       const short* __restrict__ Upart,
                       const short* __restrict__ Vpart,
                       const float* __restrict__ Sp,
                       const int* __restrict__ grid_in,
                       const int* __restrict__ anchor,
                       float* __restrict__ out) {
  const int tid = threadIdx.x;
  __shared__ float Us[4][256];
  __shared__ float Vsm[4][64];
  __shared__ float Sinv[4];
  __shared__ float part[4][12];
  __shared__ unsigned msh[32];

  if (blockIdx.x >= 256) {
    // ---- executor: flood fill, rotate 90 CW about anchor, paint ----
    const int b = blockIdx.x - 256;
    const int lane = tid;
    const int* g = grid_in + b * 900;
    float* outg = out + 32 * 8 * 12;
    int ar = anchor[2 * b], ac = anchor[2 * b + 1];
    ar = min(max(ar, 0), 29); ac = min(max(ac, 0), 29);
    const int seed = g[ar * 30 + ac];

    unsigned same = 0u;
    if (lane < 30)
      for (int c = 0; c < 30; ++c) same |= (unsigned)(g[lane * 30 + c] == seed) << c;

    unsigned cur = (lane == ar) ? (1u << ac) : 0u;
    bool changed = true;
    while (changed) {
      unsigned up = __shfl(cur, (lane + 63) & 63);
      unsigned dn = __shfl(cur, (lane + 1) & 63);
      if (lane == 0) up = 0u;
      unsigned nm = (cur | (cur << 1) | (cur >> 1) | up | dn) & same;
      changed = __any(nm != cur);
      cur = nm;
    }

    if (lane < 32) msh[lane] = (lane < 30) ? cur : 0u;
    __syncthreads();

    if (lane < 30) {
      unsigned rot = 0u;
      int cc = lane - ar + ac;
      if (cc >= 0 && cc < 30) {
        for (int nc = 0; nc < 30; ++nc) {
          int rr = ar + ac - nc;
          if (rr >= 0 && rr < 30) rot |= ((msh[rr] >> cc) & 1u) << nc;
        }
      }
      for (int c = 0; c < 30; ++c) {
        int v = ((rot >> c) & 1u) ? 3 : g[lane * 30 + c];
        outg[b * 900 + lane * 30 + c] = (float)v;
      }
    }
    return;
  }

  // ---- crossR ----
  const int bl = blockIdx.x, b = bl >> 3, l = bl & 7;
  for (int h = 0; h < 4; ++h) {
    int lh = h * 8 + l;
    for (int j = tid; j < 256; j += 64) {
      float a = 0.f;
      #pragma unroll
      for (int kg = 0; kg < 8; ++kg)
        a += bf2f(Upart[(((size_t)(kg * 32 + b)) * 32 + lh) * 256 + j]);
      Us[h][j] = a;
    }
    float a = 0.f;
    #pragma unroll
    for (int kg = 0; kg < 8; ++kg)
      a += bf2f(Vpart[((((size_t)(kg * 32 + b)) * 4 + h) * 64 + tid) * 8 + l]);
    Vsm[h][tid] = a;
  }
  if (tid < 4) {
    int lh = tid * 8 + l;
    float s = 0.f;
    #pragma unroll
    for (int k = 0; k < 15; ++k) s += Sp[((size_t)b * 32 + lh) * 15 + k];
    Sinv[tid] = 1.f / s;
  }
  __syncthreads();
  if (tid < 48) {
    int h = tid / 12, p = tid % 12;
    const float* woOut = ws + OFF_WOOUT;
    const float* WVO = ws + OFF_WVO;
    float acc = 0.f;
    for (int dd = 0; dd < 64; ++dd)
      acc = fmaf(Vsm[h][dd], woOut[(h * 64 + dd) * 12 + p], acc);
    for (int j = 0; j < 256; ++j)
      acc = fmaf(Us[h][j], WVO[((size_t)h * 256 + j) * 12 + p], acc);
    part[h][p] = acc * Sinv[h];
  }
  __syncthreads();
  if (tid < 12)
    out[(size_t)bl * 12 + tid] =
        b_out[tid] + part[0][tid] + part[1][tid] + part[2][tid] + part[3][tid];
}

// ---------------------------------------------------------------------------
extern "C" void kernel_launch(void* const* d_in, const int* in_sizes, int n_in,
                              void* d_out, int out_size, void* d_ws, size_t ws_size,
                              hipStream_t stream) {
  const int*   grid_in = (const int*)d_in[0];
  const int*   anchor  = (const int*)d_in[1];
  const float* embed   = (const float*)d_in[2];
  const float* pos_emb = (const float*)d_in[3];
  const float* wq      = (const float*)d_in[4];
  const float* wk      = (const float*)d_in[5];
  const float* wv      = (const float*)d_in[6];
  const float* wo      = (const float*)d_in[7];
  const float* step_q  = (const float*)d_in[8];
  const float* w_out   = (const float*)d_in[9];
  const float* b_out   = (const float*)d_in[10];
  float* out = (float*)d_out;
  float* ws  = (float*)d_ws;
  short* wsS = (short*)(ws + OFF_F32_END);

  k_pre<<<dim3(262), dim3(256), 0, stream>>>(pos_emb, embed, wq, wk, wv, wo,
                                             step_q, w_out, ws);
  k_kvp<<<dim3(549), dim3(256), 0, stream>>>(grid_in, ws,
                                             wsS + SOFF_KB, wsS + SOFF_VT);
  k_attn<<<dim3(1024), dim3(256), 0, stream>>>(grid_in, ws, wsS + SOFF_KB,
                                               wsS + SOFF_VT, wsS + SOFF_ATTN);
  short* E  = wsS + SOFF_E;
  float* Sp = (float*)(wsS + SOFF_WOKVT);
  k_crossA<<<dim3(15, 32), dim3(256), 0, stream>>>(grid_in, ws, wsS + SOFF_ATTN, E, Sp);
  k_crossP<<<dim3(8, 32), dim3(256), 0, stream>>>(wsS + SOFF_ATTN, E, wsS + SOFF_VT,
                                                  wsS + SOFF_UPART, wsS + SOFF_VPART);
  k_tail<<<dim3(288), dim3(64), 0, stream>>>(ws, b_out, wsS + SOFF_UPART,
                                             wsS + SOFF_VPART, Sp, grid_in, anchor, out);
}